// Round 1
// baseline (2332.685 us; speedup 1.0000x reference)
//
#include <hip/hip_runtime.h>
#include <math.h>

namespace {

constexpr int NQ  = 6000;   // fluid particles (queries)
constexpr int NB  = 3000;   // box particles
constexpr int K   = 80;     // neighbor cap
constexpr float RAD = 0.1125f;
constexpr float R2  = RAD * RAD;
constexpr float EPSF = 1e-12f;

__device__ __forceinline__ float sgn(float x) {
    return (x > 0.f) ? 1.f : ((x < 0.f) ? -1.f : 0.f);
}

// ---------------- neighbor search: one wave (64 lanes) per query -------------
__global__ __launch_bounds__(256) void nn_kernel(
    const float* __restrict__ qpos, int nq,
    const float* __restrict__ ipos, int ni, int self_ig,
    int* __restrict__ cnt, int* __restrict__ idxs, float* __restrict__ d2s)
{
    int wid  = (blockIdx.x * blockDim.x + threadIdx.x) >> 6;
    int lane = threadIdx.x & 63;
    if (wid >= nq) return;
    float qx = qpos[wid*3+0], qy = qpos[wid*3+1], qz = qpos[wid*3+2];
    int base = wid * K;
    int c = 0;
    for (int j0 = 0; j0 < ni; j0 += 64) {
        int j = j0 + lane;
        float d2 = 1e30f;
        if (j < ni) {
            float dx = ipos[j*3+0]-qx, dy = ipos[j*3+1]-qy, dz = ipos[j*3+2]-qz;
            d2 = dx*dx + dy*dy + dz*dz;
            if (self_ig && j == wid) d2 = 1e30f;
        }
        bool hit = d2 <= R2;
        unsigned long long m = __ballot(hit);
        int pc = __popcll(m);
        if (pc == 0) continue;
        if (c + pc <= K) {
            if (hit) {
                int pos = c + __popcll(m & ((1ull << lane) - 1ull));
                idxs[base + pos] = j;
                d2s [base + pos] = d2;
            }
            c += pc;
        } else {
            // rare overflow path: keep the K nearest (top_k semantics)
            while (m) {
                int l = __ffsll((unsigned long long)m) - 1;
                m &= m - 1ull;
                float dd = __shfl(d2, l);
                int jj = j0 + l;
                if (c < K) {
                    idxs[base + c] = jj;   // all lanes store identical value
                    d2s [base + c] = dd;
                    c++;
                } else {
                    float mx = -1.f; int am = 0;
                    for (int s = 0; s < K; ++s) {
                        float v = d2s[base + s];
                        if (v > mx) { mx = v; am = s; }
                    }
                    if (dd < mx) {
                        idxs[base + am] = jj;
                        d2s [base + am] = dd;
                    }
                }
            }
        }
    }
    if (lane == 0) cnt[wid] = c;
}

// ------------- per-neighbor geometry: ball->cube + trilinear coefs -----------
__global__ __launch_bounds__(256) void coef_kernel(
    const float* __restrict__ qpos, const float* __restrict__ ipos,
    const int* __restrict__ cnt, const int* __restrict__ idxs,
    int* __restrict__ cells, float* __restrict__ coefs, int nq)
{
    int t = blockIdx.x * blockDim.x + threadIdx.x;
    int q = t / K, k = t - q * K;
    if (q >= nq) return;
    if (k >= cnt[q]) return;
    int j = idxs[q*K + k];
    float rx = (ipos[j*3+0] - qpos[q*3+0]) / RAD;
    float ry = (ipos[j*3+1] - qpos[q*3+1]) / RAD;
    float rz = (ipos[j*3+2] - qpos[q*3+2]) / RAD;
    float r2 = rx*rx + ry*ry + rz*rz;
    float w1 = 1.f - r2;
    float win = (w1 > 0.f) ? w1*w1*w1 : 0.f;   // clip((1-r2)^3, 0, 1)
    // ball -> cylinder (volume preserving)
    float sq = r2;
    float norm = sqrtf(sq);
    float rxy2 = rx*rx + ry*ry;
    float xc, yc, zc;
    if (sq < 1e-12f) {
        xc = yc = zc = 0.f;
    } else if (1.25f * rz * rz > rxy2) {
        float s = sqrtf(3.0f * norm / (norm + fabsf(rz) + EPSF));
        xc = s * rx; yc = s * ry; zc = sgn(rz) * norm;
    } else {
        float s = norm / sqrtf(rxy2 + EPSF);
        xc = s * rx; yc = s * ry; zc = 1.5f * rz * s;
    }
    // cylinder -> cube (disc -> square)
    float rxy = sqrtf(xc*xc + yc*yc);
    const float FP = (float)(4.0 / M_PI);
    float u, v;
    if (rxy < EPSF) {
        u = 0.f; v = 0.f;
    } else if (fabsf(xc) >= fabsf(yc)) {
        float sx = (fabsf(xc) < EPSF) ? EPSF : xc;
        u = sgn(xc) * rxy;
        v = u * FP * atanf(yc / sx);
    } else {
        float sy = (fabsf(yc) < EPSF) ? EPSF : yc;
        v = sgn(yc) * rxy;
        u = v * FP * atanf(xc / sy);
    }
    float gx = fminf(fmaxf((u  + 1.f) * 0.5f * 3.f, 0.f), 3.f);
    float gy = fminf(fmaxf((v  + 1.f) * 0.5f * 3.f, 0.f), 3.f);
    float gz = fminf(fmaxf((zc + 1.f) * 0.5f * 3.f, 0.f), 3.f);
    int ix = min((int)floorf(gx), 2);
    int iy = min((int)floorf(gy), 2);
    int iz = min((int)floorf(gz), 2);
    float tx = gx - (float)ix, ty = gy - (float)iy, tz = gz - (float)iz;
    cells[q*K + k] = iz*16 + iy*4 + ix;
    float wx[2] = {1.f - tx, tx}, wy[2] = {1.f - ty, ty}, wz[2] = {1.f - tz, tz};
    float* cf = coefs + (size_t)(q*K + k) * 8;
#pragma unroll
    for (int c = 0; c < 8; ++c)   // c = dx*4 + dy*2 + dz (python loop order)
        cf[c] = wx[c >> 2] * wy[(c >> 1) & 1] * wz[c & 1] * win;
}

// ---------------- fused continuous conv: one block per query point ----------
// scatter coef*feat into LDS S[64][F], then contract with W[64,F,O];
// optional dense skip (relu(feats[n]) @ dW + db), residual, scale.
template<int F, int O>
__global__ __launch_bounds__(256) void conv_kernel(
    const float* __restrict__ feats,
    const int* __restrict__ cnt, const int* __restrict__ nidx,
    const int* __restrict__ ncell, const float* __restrict__ ncoef,
    const float* __restrict__ W, const float* __restrict__ bias,
    const float* __restrict__ dW, const float* __restrict__ db,
    const float* __restrict__ resid,
    float* __restrict__ out, int ostride, int ooff,
    float scale, int relu, int nq)
{
    constexpr int OPAD = (O >= 64) ? 64 : (O >= 32) ? 32 : 4;
    constexpr int P  = 256 / OPAD;   // reduction parts
    constexpr int CP = 64 / P;       // cells per part
    __shared__ float S[64 * F];
    __shared__ float red[256];
    int n = blockIdx.x;
    if (n >= nq) return;
    int tid = threadIdx.x;
    for (int i = tid; i < 64 * F; i += 256) S[i] = 0.f;
    __syncthreads();
    int lane = tid & 63, wave = tid >> 6;
    int cn = cnt[n];
    for (int k = wave; k < cn; k += 4) {
        int j  = nidx[n*K + k];
        int cb = ncell[n*K + k];
        const float* cf8 = ncoef + (size_t)(n*K + k) * 8;
        float v0 = 0.f, v1 = 0.f;
        if (lane < F) {
            v0 = feats[j*F + lane];
            if (relu) v0 = fmaxf(v0, 0.f);
        }
        if (F > 64 && lane < F - 64) {
            v1 = feats[j*F + 64 + lane];
            if (relu) v1 = fmaxf(v1, 0.f);
        }
#pragma unroll
        for (int c = 0; c < 8; ++c) {
            float wgt = cf8[c];
            int cell = cb + (c & 1) * 16 + ((c >> 1) & 1) * 4 + (c >> 2);
            if (lane < F) atomicAdd(&S[cell*F + lane], wgt * v0);
            if (F > 64 && lane < F - 64) atomicAdd(&S[cell*F + 64 + lane], wgt * v1);
        }
    }
    __syncthreads();
    // dense contraction: thread (o = tid%OPAD, part = tid/OPAD)
    int o = tid % OPAD;
    int p = tid / OPAD;
    float acc = 0.f;
    if (o < O) {
        for (int cell = p * CP; cell < (p + 1) * CP; ++cell) {
            const float* Wc = W + (size_t)cell * F * O + o;
            const float* Sc = S + cell * F;
#pragma unroll 4
            for (int f = 0; f < F; ++f)
                acc += Sc[f] * Wc[(size_t)f * O];
        }
    }
    red[tid] = acc;
    __syncthreads();
    if (tid < O) {
        float r = 0.f;
#pragma unroll
        for (int pp = 0; pp < P; ++pp) r += red[pp * OPAD + tid];
        r += bias[tid];
        if (dW) {
            float dacc = db[tid];
            const float* hrow = feats + (size_t)n * F;
            for (int f = 0; f < F; ++f) {
                float h = hrow[f];
                if (relu) h = fmaxf(h, 0.f);
                dacc += h * dW[f*O + tid];
            }
            r += dacc;
        }
        if (resid) r += resid[n*O + tid];
        out[(size_t)n * ostride + ooff + tid] = r * scale;
    }
}

__global__ __launch_bounds__(256) void ff_kernel(const float* __restrict__ vel,
                                                 float* __restrict__ ff) {
    int t = blockIdx.x * blockDim.x + threadIdx.x;
    if (t >= NQ) return;
    ff[t*4+0] = 1.f;
    ff[t*4+1] = vel[t*3+0];
    ff[t*4+2] = vel[t*3+1];
    ff[t*4+3] = vel[t*3+2];
}

__global__ __launch_bounds__(256) void d0_kernel(const float* __restrict__ ff,
                                                 const float* __restrict__ w,
                                                 const float* __restrict__ b,
                                                 float* __restrict__ x1) {
    int t = blockIdx.x * blockDim.x + threadIdx.x;
    if (t >= NQ * 32) return;
    int n = t >> 5, o = t & 31;
    float acc = b[o];
#pragma unroll
    for (int f = 0; f < 4; ++f) acc += ff[n*4+f] * w[f*32+o];
    x1[n*96 + 64 + o] = acc;
}

} // namespace

extern "C" void kernel_launch(void* const* d_in, const int* in_sizes, int n_in,
                              void* d_out, int out_size, void* d_ws, size_t ws_size,
                              hipStream_t stream)
{
    const float* pos       = (const float*)d_in[0];
    const float* vel       = (const float*)d_in[1];
    const float* box       = (const float*)d_in[2];
    const float* box_feats = (const float*)d_in[3];
    const float* cf_w = (const float*)d_in[4];  const float* cf_b = (const float*)d_in[5];
    const float* co_w = (const float*)d_in[6];  const float* co_b = (const float*)d_in[7];
    const float* d0_w = (const float*)d_in[8];  const float* d0_b = (const float*)d_in[9];
    const float* c1_w = (const float*)d_in[10]; const float* c1_b = (const float*)d_in[11];
    const float* d1_w = (const float*)d_in[12]; const float* d1_b = (const float*)d_in[13];
    const float* c2_w = (const float*)d_in[14]; const float* c2_b = (const float*)d_in[15];
    const float* d2_w = (const float*)d_in[16]; const float* d2_b = (const float*)d_in[17];
    const float* c3_w = (const float*)d_in[18]; const float* c3_b = (const float*)d_in[19];
    const float* d3_w = (const float*)d_in[20]; const float* d3_b = (const float*)d_in[21];

    char* wsb = (char*)d_ws;
    size_t off = 0;
    auto alloc = [&](size_t bytes) {
        void* p = wsb + off;
        off = (off + bytes + 255) & ~(size_t)255;
        return p;
    };
    int*   f_cnt  = (int*)  alloc((size_t)NQ * 4);
    int*   f_idx  = (int*)  alloc((size_t)NQ * K * 4);
    float* f_d2   = (float*)alloc((size_t)NQ * K * 4);
    int*   f_cell = (int*)  alloc((size_t)NQ * K * 4);
    float* f_coef = (float*)alloc((size_t)NQ * K * 8 * 4);
    int*   b_cnt  = (int*)  alloc((size_t)NQ * 4);
    int*   b_idx  = (int*)  alloc((size_t)NQ * K * 4);
    float* b_d2   = (float*)alloc((size_t)NQ * K * 4);
    int*   b_cell = (int*)  alloc((size_t)NQ * K * 4);
    float* b_coef = (float*)alloc((size_t)NQ * K * 8 * 4);
    float* ff     = (float*)alloc((size_t)NQ * 4 * 4);
    float* x1     = (float*)alloc((size_t)NQ * 96 * 4);
    float* x2     = (float*)alloc((size_t)NQ * 64 * 4);
    float* x3     = (float*)alloc((size_t)NQ * 64 * 4);

    dim3 b256(256);
    // neighbor searches (one wave per query)
    nn_kernel<<<(NQ*64 + 255)/256, b256, 0, stream>>>(pos, NQ, pos, NQ, 1, f_cnt, f_idx, f_d2);
    nn_kernel<<<(NQ*64 + 255)/256, b256, 0, stream>>>(pos, NQ, box, NB, 0, b_cnt, b_idx, b_d2);
    // per-neighbor interpolation data
    coef_kernel<<<(NQ*K + 255)/256, b256, 0, stream>>>(pos, pos, f_cnt, f_idx, f_cell, f_coef, NQ);
    coef_kernel<<<(NQ*K + 255)/256, b256, 0, stream>>>(pos, box, b_cnt, b_idx, b_cell, b_coef, NQ);
    // ff = [1, vel]
    ff_kernel<<<(NQ + 255)/256, b256, 0, stream>>>(vel, ff);
    // layer 0: x1 = concat([a_co, a_cf, a_d0])
    conv_kernel<3,32><<<NQ, b256, 0, stream>>>(box_feats, b_cnt, b_idx, b_cell, b_coef,
        co_w, co_b, nullptr, nullptr, nullptr, x1, 96, 0, 1.f, 0, NQ);
    conv_kernel<4,32><<<NQ, b256, 0, stream>>>(ff, f_cnt, f_idx, f_cell, f_coef,
        cf_w, cf_b, nullptr, nullptr, nullptr, x1, 96, 32, 1.f, 0, NQ);
    d0_kernel<<<(NQ*32 + 255)/256, b256, 0, stream>>>(ff, d0_w, d0_b, x1);
    // layer 1: x2 = cconv(relu(x1)) + relu(x1)@d1 + b
    conv_kernel<96,64><<<NQ, b256, 0, stream>>>(x1, f_cnt, f_idx, f_cell, f_coef,
        c1_w, c1_b, d1_w, d1_b, nullptr, x2, 64, 0, 1.f, 1, NQ);
    // layer 2: x3 = [cconv(relu(x2)) + relu(x2)@d2 + b] + x2
    conv_kernel<64,64><<<NQ, b256, 0, stream>>>(x2, f_cnt, f_idx, f_cell, f_coef,
        c2_w, c2_b, d2_w, d2_b, x2, x3, 64, 0, 1.f, 1, NQ);
    // layer 3: out = [cconv(relu(x3)) + relu(x3)@d3 + b] / 128
    conv_kernel<64,3><<<NQ, b256, 0, stream>>>(x3, f_cnt, f_idx, f_cell, f_coef,
        c3_w, c3_b, d3_w, d3_b, nullptr, (float*)d_out, 3, 0, 1.f/128.f, 1, NQ);

    (void)in_sizes; (void)n_in; (void)out_size; (void)ws_size;
    (void)f_d2; (void)b_d2;
}

// Round 2
// 2234.034 us; speedup vs baseline: 1.0442x; 1.0442x over previous
//
#include <hip/hip_runtime.h>
#include <math.h>

namespace {

constexpr int NQ  = 6000;   // fluid particles (queries)
constexpr int NB  = 3000;   // box particles
constexpr int K   = 80;     // neighbor cap
constexpr float RAD = 0.1125f;
constexpr float R2  = RAD * RAD;
constexpr float EPSF = 1e-12f;

__device__ __forceinline__ float sgn(float x) {
    return (x > 0.f) ? 1.f : ((x < 0.f) ? -1.f : 0.f);
}

// ---------------- neighbor search: one wave (64 lanes) per query -------------
__global__ __launch_bounds__(256) void nn_kernel(
    const float* __restrict__ qpos, int nq,
    const float* __restrict__ ipos, int ni, int self_ig,
    int* __restrict__ cnt, int* __restrict__ idxs, float* __restrict__ d2s)
{
    int wid  = (blockIdx.x * blockDim.x + threadIdx.x) >> 6;
    int lane = threadIdx.x & 63;
    if (wid >= nq) return;
    float qx = qpos[wid*3+0], qy = qpos[wid*3+1], qz = qpos[wid*3+2];
    int base = wid * K;
    int c = 0;
    for (int j0 = 0; j0 < ni; j0 += 64) {
        int j = j0 + lane;
        float d2 = 1e30f;
        if (j < ni) {
            float dx = ipos[j*3+0]-qx, dy = ipos[j*3+1]-qy, dz = ipos[j*3+2]-qz;
            d2 = dx*dx + dy*dy + dz*dz;
            if (self_ig && j == wid) d2 = 1e30f;
        }
        bool hit = d2 <= R2;
        unsigned long long m = __ballot(hit);
        int pc = __popcll(m);
        if (pc == 0) continue;
        if (c + pc <= K) {
            if (hit) {
                int pos = c + __popcll(m & ((1ull << lane) - 1ull));
                idxs[base + pos] = j;
                d2s [base + pos] = d2;
            }
            c += pc;
        } else {
            // rare overflow path: keep the K nearest (top_k semantics)
            while (m) {
                int l = __ffsll((unsigned long long)m) - 1;
                m &= m - 1ull;
                float dd = __shfl(d2, l);
                int jj = j0 + l;
                if (c < K) {
                    idxs[base + c] = jj;
                    d2s [base + c] = dd;
                    c++;
                } else {
                    float mx = -1.f; int am = 0;
                    for (int s = 0; s < K; ++s) {
                        float v = d2s[base + s];
                        if (v > mx) { mx = v; am = s; }
                    }
                    if (dd < mx) {
                        idxs[base + am] = jj;
                        d2s [base + am] = dd;
                    }
                }
            }
        }
    }
    if (lane == 0) cnt[wid] = c;
}

// ------------- per-neighbor geometry: ball->cube + trilinear coefs -----------
__global__ __launch_bounds__(256) void coef_kernel(
    const float* __restrict__ qpos, const float* __restrict__ ipos,
    const int* __restrict__ cnt, const int* __restrict__ idxs,
    int* __restrict__ cells, float* __restrict__ coefs, int nq)
{
    int t = blockIdx.x * blockDim.x + threadIdx.x;
    int q = t / K, k = t - q * K;
    if (q >= nq) return;
    if (k >= cnt[q]) return;
    int j = idxs[q*K + k];
    float rx = (ipos[j*3+0] - qpos[q*3+0]) / RAD;
    float ry = (ipos[j*3+1] - qpos[q*3+1]) / RAD;
    float rz = (ipos[j*3+2] - qpos[q*3+2]) / RAD;
    float r2 = rx*rx + ry*ry + rz*rz;
    float w1 = 1.f - r2;
    float win = (w1 > 0.f) ? w1*w1*w1 : 0.f;   // clip((1-r2)^3, 0, 1)
    float sq = r2;
    float norm = sqrtf(sq);
    float rxy2 = rx*rx + ry*ry;
    float xc, yc, zc;
    if (sq < 1e-12f) {
        xc = yc = zc = 0.f;
    } else if (1.25f * rz * rz > rxy2) {
        float s = sqrtf(3.0f * norm / (norm + fabsf(rz) + EPSF));
        xc = s * rx; yc = s * ry; zc = sgn(rz) * norm;
    } else {
        float s = norm / sqrtf(rxy2 + EPSF);
        xc = s * rx; yc = s * ry; zc = 1.5f * rz * s;
    }
    float rxy = sqrtf(xc*xc + yc*yc);
    const float FP = (float)(4.0 / M_PI);
    float u, v;
    if (rxy < EPSF) {
        u = 0.f; v = 0.f;
    } else if (fabsf(xc) >= fabsf(yc)) {
        float sx = (fabsf(xc) < EPSF) ? EPSF : xc;
        u = sgn(xc) * rxy;
        v = u * FP * atanf(yc / sx);
    } else {
        float sy = (fabsf(yc) < EPSF) ? EPSF : yc;
        v = sgn(yc) * rxy;
        u = v * FP * atanf(xc / sy);
    }
    float gx = fminf(fmaxf((u  + 1.f) * 0.5f * 3.f, 0.f), 3.f);
    float gy = fminf(fmaxf((v  + 1.f) * 0.5f * 3.f, 0.f), 3.f);
    float gz = fminf(fmaxf((zc + 1.f) * 0.5f * 3.f, 0.f), 3.f);
    int ix = min((int)floorf(gx), 2);
    int iy = min((int)floorf(gy), 2);
    int iz = min((int)floorf(gz), 2);
    float tx = gx - (float)ix, ty = gy - (float)iy, tz = gz - (float)iz;
    cells[q*K + k] = iz*16 + iy*4 + ix;
    float wx[2] = {1.f - tx, tx}, wy[2] = {1.f - ty, ty}, wz[2] = {1.f - tz, tz};
    float* cf = coefs + (size_t)(q*K + k) * 8;
#pragma unroll
    for (int c = 0; c < 8; ++c)   // c = dx*4 + dy*2 + dz (python loop order)
        cf[c] = wx[c >> 2] * wy[(c >> 1) & 1] * wz[c & 1] * win;
}

// -------- scatter: build S[n, 64*F (+F ext)] rows in global workspace --------
// One block per query point. LDS scatter with ds atomics, coalesced write-out.
// EXT appends relu(feats[n]) so the dense skip rides the same GEMM.
template<int F, int RELU, int EXT>
__global__ __launch_bounds__(256) void scatter_kernel(
    const float* __restrict__ feats,
    const int* __restrict__ cnt, const int* __restrict__ nidx,
    const int* __restrict__ ncell, const float* __restrict__ ncoef,
    float* __restrict__ Sg)
{
    constexpr int KT = 64 * F + (EXT ? F : 0);
    __shared__ float S[64 * F];
    int n = blockIdx.x;
    int tid = threadIdx.x;
    for (int i = tid; i < 64 * F; i += 256) S[i] = 0.f;
    __syncthreads();
    int lane = tid & 63, wave = tid >> 6;
    int cn = cnt[n];
    for (int k = wave; k < cn; k += 4) {
        int j  = nidx[n*K + k];
        int cb = ncell[n*K + k];
        const float* cf8 = ncoef + (size_t)(n*K + k) * 8;
        float v0 = 0.f, v1 = 0.f;
        if (lane < F) {
            v0 = feats[(size_t)j*F + lane];
            if (RELU) v0 = fmaxf(v0, 0.f);
        }
        if (F > 64 && lane < F - 64) {
            v1 = feats[(size_t)j*F + 64 + lane];
            if (RELU) v1 = fmaxf(v1, 0.f);
        }
#pragma unroll
        for (int c = 0; c < 8; ++c) {
            float wgt = cf8[c];
            int cell = cb + (c & 1) * 16 + ((c >> 1) & 1) * 4 + (c >> 2);
            if (lane < F) atomicAdd(&S[cell*F + lane], wgt * v0);
            if (F > 64 && lane < F - 64) atomicAdd(&S[cell*F + 64 + lane], wgt * v1);
        }
    }
    __syncthreads();
    float* row = Sg + (size_t)n * KT;
#pragma unroll 4
    for (int i = tid; i < 64 * F / 4; i += 256)
        reinterpret_cast<float4*>(row)[i] = reinterpret_cast<const float4*>(S)[i];
    if (EXT) {
        for (int f = tid; f < F; f += 256) {
            float v = feats[(size_t)n*F + f];
            if (RELU) v = fmaxf(v, 0.f);
            row[64*F + f] = v;
        }
    }
}

// ----------------- tiled fp32 GEMM with interleaved split-K ------------------
// C_part[ky] = A[M,K] x B[K,O] over k-tiles t = ky, ky+KC, ... (deterministic).
// Partials are summed (plus bias/resid/scale) in a tiny epilogue kernel.
template<int O>
__global__ __launch_bounds__(256) void gemm_kernel(
    const float* __restrict__ A, int Kdim,
    const float* __restrict__ B,
    float* __restrict__ P,   // [gridDim.y][M][O]
    int M)
{
    constexpr int TX   = O / 4;        // threads along O (16 or 8)
    constexpr int TY   = 256 / TX;     // threads along M (16 or 32)
    constexpr int MT   = TY * 4;       // 64 or 128
    constexpr int ASTR = MT + 4;       // pad: keeps 16B align + no conflicts
    __shared__ float As[16][ASTR];     // k-major
    __shared__ float Bs[16 * O];
    int tid = threadIdx.x;
    int tx = tid % TX, ty = tid / TX;
    int m0 = blockIdx.x * MT;
    int ntiles = Kdim >> 4;
    float acc[4][4] = {};
    for (int t = blockIdx.y; t < ntiles; t += gridDim.y) {
        int k0 = t << 4;
        __syncthreads();
        // A tile: MT x 16, stored k-major into As
#pragma unroll
        for (int l = 0; l < MT / 64; ++l) {
            int idx = tid + l * 256;
            int mm = idx >> 2, k4 = idx & 3;
            int gm = m0 + mm; if (gm >= M) gm = M - 1;
            float4 av = *reinterpret_cast<const float4*>(A + (size_t)gm * Kdim + k0 + k4 * 4);
            As[k4*4+0][mm] = av.x; As[k4*4+1][mm] = av.y;
            As[k4*4+2][mm] = av.z; As[k4*4+3][mm] = av.w;
        }
        // B tile: 16 x O, contiguous in global
        constexpr int NB4 = 16 * O / 4;
        if (NB4 == 256 || tid < NB4)
            *reinterpret_cast<float4*>(&Bs[tid*4]) =
                *reinterpret_cast<const float4*>(B + (size_t)k0 * O + tid * 4);
        __syncthreads();
#pragma unroll
        for (int kk = 0; kk < 16; ++kk) {
            float4 av = *reinterpret_cast<const float4*>(&As[kk][ty*4]);
            float4 bv = *reinterpret_cast<const float4*>(&Bs[kk*O + tx*4]);
            float aa[4] = {av.x, av.y, av.z, av.w};
            float bb[4] = {bv.x, bv.y, bv.z, bv.w};
#pragma unroll
            for (int i = 0; i < 4; ++i)
#pragma unroll
                for (int j = 0; j < 4; ++j)
                    acc[i][j] += aa[i] * bb[j];
        }
    }
    float* Pb = P + (size_t)blockIdx.y * M * O;
#pragma unroll
    for (int i = 0; i < 4; ++i) {
        int gm = m0 + ty*4 + i;
        if (gm < M)
#pragma unroll
            for (int j = 0; j < 4; ++j)
                Pb[(size_t)gm * O + tx*4 + j] = acc[i][j];
    }
}

// ----- small-O GEMM for the final layer (O padded to 4), epilogue fused -----
__global__ __launch_bounds__(256) void gemm_small_kernel(
    const float* __restrict__ A, int Kdim, const float* __restrict__ B4,
    const float* __restrict__ cb, const float* __restrict__ db,
    float* __restrict__ out, int M, float scale)
{
    int w = (blockIdx.x * blockDim.x + threadIdx.x) >> 6;
    int lane = threadIdx.x & 63;
    if (w >= M) return;
    const float* Ar = A + (size_t)w * Kdim;
    float a0 = 0.f, a1 = 0.f, a2 = 0.f;
    for (int k = lane; k < Kdim; k += 64) {
        float a = Ar[k];
        float4 b = *reinterpret_cast<const float4*>(B4 + (size_t)k * 4);
        a0 += a * b.x; a1 += a * b.y; a2 += a * b.z;
    }
#pragma unroll
    for (int s = 32; s > 0; s >>= 1) {
        a0 += __shfl_down(a0, s);
        a1 += __shfl_down(a1, s);
        a2 += __shfl_down(a2, s);
    }
    if (lane == 0) {
        out[w*3+0] = (a0 + cb[0] + db[0]) * scale;
        out[w*3+1] = (a1 + cb[1] + db[1]) * scale;
        out[w*3+2] = (a2 + cb[2] + db[2]) * scale;
    }
}

// build padded [K,4] filter for the last layer: rows = [c3_w ; d3_w], col3 = 0
__global__ __launch_bounds__(256) void b3pad_kernel(
    const float* __restrict__ c3w, const float* __restrict__ d3w,
    float* __restrict__ B4, int Kc /*=4096*/, int Kt /*=4160*/)
{
    int k = blockIdx.x * blockDim.x + threadIdx.x;
    if (k >= Kt) return;
    const float* src = (k < Kc) ? (c3w + (size_t)k * 3) : (d3w + (size_t)(k - Kc) * 3);
    B4[k*4+0] = src[0]; B4[k*4+1] = src[1]; B4[k*4+2] = src[2]; B4[k*4+3] = 0.f;
}

__global__ __launch_bounds__(256) void ff_kernel(const float* __restrict__ vel,
                                                 float* __restrict__ ff) {
    int t = blockIdx.x * blockDim.x + threadIdx.x;
    if (t >= NQ) return;
    ff[t*4+0] = 1.f;
    ff[t*4+1] = vel[t*3+0];
    ff[t*4+2] = vel[t*3+1];
    ff[t*4+3] = vel[t*3+2];
}

__global__ __launch_bounds__(256) void d0_kernel(const float* __restrict__ ff,
                                                 const float* __restrict__ w,
                                                 const float* __restrict__ b,
                                                 float* __restrict__ x1) {
    int t = blockIdx.x * blockDim.x + threadIdx.x;
    if (t >= NQ * 32) return;
    int n = t >> 5, o = t & 31;
    float acc = b[o];
#pragma unroll
    for (int f = 0; f < 4; ++f) acc += ff[n*4+f] * w[f*32+o];
    x1[n*96 + 64 + o] = acc;
}

// epilogue for layer 0: x1[:,0:32] = sum(Pco)+co_b ; x1[:,32:64] = sum(Pcf)+cf_b
__global__ __launch_bounds__(256) void e0_kernel(
    const float* __restrict__ Pco, const float* __restrict__ Pcf, int KC,
    const float* __restrict__ cob, const float* __restrict__ cfb,
    float* __restrict__ x1)
{
    int t = blockIdx.x * blockDim.x + threadIdx.x;
    if (t >= NQ * 64) return;
    int n = t >> 6, c = t & 63;
    float v;
    if (c < 32) {
        v = cob[c];
        for (int ky = 0; ky < KC; ++ky) v += Pco[(size_t)ky * NQ * 32 + n*32 + c];
    } else {
        int cc = c - 32;
        v = cfb[cc];
        for (int ky = 0; ky < KC; ++ky) v += Pcf[(size_t)ky * NQ * 32 + n*32 + cc];
    }
    x1[n*96 + c] = v;
}

// epilogue for layers 1/2: xo = sum_ky(P) + cb + db (+ resid)
__global__ __launch_bounds__(256) void e_kernel(
    const float* __restrict__ P, int KC,
    const float* __restrict__ cb, const float* __restrict__ db,
    const float* __restrict__ resid, float* __restrict__ xo)
{
    int t = blockIdx.x * blockDim.x + threadIdx.x;
    if (t >= NQ * 64) return;
    int o = t & 63;
    float v = cb[o] + db[o];
    for (int ky = 0; ky < KC; ++ky) v += P[(size_t)ky * NQ * 64 + t];
    if (resid) v += resid[t];
    xo[t] = v;
}

} // namespace

extern "C" void kernel_launch(void* const* d_in, const int* in_sizes, int n_in,
                              void* d_out, int out_size, void* d_ws, size_t ws_size,
                              hipStream_t stream)
{
    const float* pos       = (const float*)d_in[0];
    const float* vel       = (const float*)d_in[1];
    const float* box       = (const float*)d_in[2];
    const float* box_feats = (const float*)d_in[3];
    const float* cf_w = (const float*)d_in[4];  const float* cf_b = (const float*)d_in[5];
    const float* co_w = (const float*)d_in[6];  const float* co_b = (const float*)d_in[7];
    const float* d0_w = (const float*)d_in[8];  const float* d0_b = (const float*)d_in[9];
    const float* c1_w = (const float*)d_in[10]; const float* c1_b = (const float*)d_in[11];
    const float* d1_w = (const float*)d_in[12]; const float* d1_b = (const float*)d_in[13];
    const float* c2_w = (const float*)d_in[14]; const float* c2_b = (const float*)d_in[15];
    const float* d2_w = (const float*)d_in[16]; const float* d2_b = (const float*)d_in[17];
    const float* c3_w = (const float*)d_in[18]; const float* c3_b = (const float*)d_in[19];
    const float* d3_w = (const float*)d_in[20]; const float* d3_b = (const float*)d_in[21];

    char* wsb = (char*)d_ws;
    size_t off = 0;
    auto alloc = [&](size_t bytes) {
        void* p = wsb + off;
        off = (off + bytes + 255) & ~(size_t)255;
        return p;
    };
    constexpr int K1 = 64*96 + 96;   // 6240
    constexpr int K2 = 64*64 + 64;   // 4160
    constexpr int KC  = 8;           // split-K chunks, big GEMMs
    constexpr int KCS = 2;           // split-K chunks, small layer-0 GEMMs

    int*   f_cnt  = (int*)  alloc((size_t)NQ * 4);
    int*   f_idx  = (int*)  alloc((size_t)NQ * K * 4);
    float* f_d2   = (float*)alloc((size_t)NQ * K * 4);
    int*   f_cell = (int*)  alloc((size_t)NQ * K * 4);
    float* f_coef = (float*)alloc((size_t)NQ * K * 8 * 4);
    int*   b_cnt  = (int*)  alloc((size_t)NQ * 4);
    int*   b_idx  = (int*)  alloc((size_t)NQ * K * 4);
    float* b_d2   = (float*)alloc((size_t)NQ * K * 4);
    int*   b_cell = (int*)  alloc((size_t)NQ * K * 4);
    float* b_coef = (float*)alloc((size_t)NQ * K * 8 * 4);
    float* ff     = (float*)alloc((size_t)NQ * 4 * 4);
    float* x1     = (float*)alloc((size_t)NQ * 96 * 4);
    float* x2     = (float*)alloc((size_t)NQ * 64 * 4);
    float* x3     = (float*)alloc((size_t)NQ * 64 * 4);
    float* B1     = (float*)alloc((size_t)K1 * 64 * 4);
    float* B2     = (float*)alloc((size_t)K2 * 64 * 4);
    float* B3     = (float*)alloc((size_t)K2 * 4 * 4);
    float* P      = (float*)alloc((size_t)KC * NQ * 64 * 4);    // big-GEMM partials
    float* Pco    = (float*)alloc((size_t)KCS * NQ * 32 * 4);
    float* Pcf    = (float*)alloc((size_t)KCS * NQ * 32 * 4);
    float* SB     = (float*)alloc((size_t)NQ * K1 * 4);         // reused S buffer
    float* S_cf   = SB;                         // [NQ,256]
    float* S_co   = SB + (size_t)NQ * 256;      // [NQ,192]

    dim3 b256(256);
    // neighbor searches + geometry
    nn_kernel<<<(NQ*64 + 255)/256, b256, 0, stream>>>(pos, NQ, pos, NQ, 1, f_cnt, f_idx, f_d2);
    nn_kernel<<<(NQ*64 + 255)/256, b256, 0, stream>>>(pos, NQ, box, NB, 0, b_cnt, b_idx, b_d2);
    coef_kernel<<<(NQ*K + 255)/256, b256, 0, stream>>>(pos, pos, f_cnt, f_idx, f_cell, f_coef, NQ);
    coef_kernel<<<(NQ*K + 255)/256, b256, 0, stream>>>(pos, box, b_cnt, b_idx, b_cell, b_coef, NQ);
    ff_kernel<<<(NQ + 255)/256, b256, 0, stream>>>(vel, ff);
    // concat filter matrices: B1 = [c1_w ; d1_w], B2 = [c2_w ; d2_w], B3 padded
    hipMemcpyAsync(B1,           c1_w, (size_t)64*96*64*4, hipMemcpyDeviceToDevice, stream);
    hipMemcpyAsync(B1 + 6144*64, d1_w, (size_t)96*64*4,    hipMemcpyDeviceToDevice, stream);
    hipMemcpyAsync(B2,           c2_w, (size_t)64*64*64*4, hipMemcpyDeviceToDevice, stream);
    hipMemcpyAsync(B2 + 4096*64, d2_w, (size_t)64*64*4,    hipMemcpyDeviceToDevice, stream);
    b3pad_kernel<<<(K2 + 255)/256, b256, 0, stream>>>(c3_w, d3_w, B3, 4096, K2);

    // ---- layer 0 ----
    scatter_kernel<4,0,0><<<NQ, b256, 0, stream>>>(ff, f_cnt, f_idx, f_cell, f_coef, S_cf);
    scatter_kernel<3,0,0><<<NQ, b256, 0, stream>>>(box_feats, b_cnt, b_idx, b_cell, b_coef, S_co);
    gemm_kernel<32><<<dim3((NQ+127)/128, KCS), b256, 0, stream>>>(S_co, 192, co_w, Pco, NQ);
    gemm_kernel<32><<<dim3((NQ+127)/128, KCS), b256, 0, stream>>>(S_cf, 256, cf_w, Pcf, NQ);
    d0_kernel<<<(NQ*32 + 255)/256, b256, 0, stream>>>(ff, d0_w, d0_b, x1);
    e0_kernel<<<(NQ*64 + 255)/256, b256, 0, stream>>>(Pco, Pcf, KCS, co_b, cf_b, x1);
    // ---- layer 1: x2 = cconv(relu(x1)) + relu(x1)@d1 + biases ----
    scatter_kernel<96,1,1><<<NQ, b256, 0, stream>>>(x1, f_cnt, f_idx, f_cell, f_coef, SB);
    gemm_kernel<64><<<dim3((NQ+63)/64, KC), b256, 0, stream>>>(SB, K1, B1, P, NQ);
    e_kernel<<<(NQ*64 + 255)/256, b256, 0, stream>>>(P, KC, c1_b, d1_b, nullptr, x2);
    // ---- layer 2: x3 = [cconv(relu(x2)) + relu(x2)@d2 + biases] + x2 ----
    scatter_kernel<64,1,1><<<NQ, b256, 0, stream>>>(x2, f_cnt, f_idx, f_cell, f_coef, SB);
    gemm_kernel<64><<<dim3((NQ+63)/64, KC), b256, 0, stream>>>(SB, K2, B2, P, NQ);
    e_kernel<<<(NQ*64 + 255)/256, b256, 0, stream>>>(P, KC, c2_b, d2_b, x2, x3);
    // ---- layer 3: out = [cconv(relu(x3)) + relu(x3)@d3 + biases] / 128 ----
    scatter_kernel<64,1,1><<<NQ, b256, 0, stream>>>(x3, f_cnt, f_idx, f_cell, f_coef, SB);
    gemm_small_kernel<<<(NQ*64 + 255)/256, b256, 0, stream>>>(SB, K2, B3, c3_b, d3_b,
                                                              (float*)d_out, NQ, 1.f/128.f);

    (void)in_sizes; (void)n_in; (void)out_size; (void)ws_size;
    (void)f_d2; (void)b_d2;
}

// Round 4
// 570.692 us; speedup vs baseline: 4.0875x; 3.9146x over previous
//
#include <hip/hip_runtime.h>
#include <math.h>

namespace {

constexpr int NQ  = 6000;   // fluid particles (queries)
constexpr int NB  = 3000;   // box particles
constexpr int K   = 80;     // neighbor cap
constexpr float RAD = 0.1125f;
constexpr float R2  = RAD * RAD;
constexpr float EPSF = 1e-12f;

__device__ __forceinline__ float sgn(float x) {
    return (x > 0.f) ? 1.f : ((x < 0.f) ? -1.f : 0.f);
}

// ---------------- neighbor search: one wave (64 lanes) per query -------------
__global__ __launch_bounds__(256) void nn_kernel(
    const float* __restrict__ qpos, int nq,
    const float* __restrict__ ipos, int ni, int self_ig,
    int* __restrict__ cnt, int* __restrict__ idxs, float* __restrict__ d2s)
{
    int wid  = (blockIdx.x * blockDim.x + threadIdx.x) >> 6;
    int lane = threadIdx.x & 63;
    if (wid >= nq) return;
    float qx = qpos[wid*3+0], qy = qpos[wid*3+1], qz = qpos[wid*3+2];
    int base = wid * K;
    int c = 0;
    for (int j0 = 0; j0 < ni; j0 += 64) {
        int j = j0 + lane;
        float d2 = 1e30f;
        if (j < ni) {
            float dx = ipos[j*3+0]-qx, dy = ipos[j*3+1]-qy, dz = ipos[j*3+2]-qz;
            d2 = dx*dx + dy*dy + dz*dz;
            if (self_ig && j == wid) d2 = 1e30f;
        }
        bool hit = d2 <= R2;
        unsigned long long m = __ballot(hit);
        int pc = __popcll(m);
        if (pc == 0) continue;
        if (c + pc <= K) {
            if (hit) {
                int pos = c + __popcll(m & ((1ull << lane) - 1ull));
                idxs[base + pos] = j;
                d2s [base + pos] = d2;
            }
            c += pc;
        } else {
            // rare overflow path: keep the K nearest (top_k semantics)
            while (m) {
                int l = __ffsll((unsigned long long)m) - 1;
                m &= m - 1ull;
                float dd = __shfl(d2, l);
                int jj = j0 + l;
                if (c < K) {
                    idxs[base + c] = jj;
                    d2s [base + c] = dd;
                    c++;
                } else {
                    float mx = -1.f; int am = 0;
                    for (int s = 0; s < K; ++s) {
                        float v = d2s[base + s];
                        if (v > mx) { mx = v; am = s; }
                    }
                    if (dd < mx) {
                        idxs[base + am] = jj;
                        d2s [base + am] = dd;
                    }
                }
            }
        }
    }
    if (lane == 0) cnt[wid] = c;
}

// ------------- per-neighbor geometry: ball->cube + trilinear coefs -----------
__global__ __launch_bounds__(256) void coef_kernel(
    const float* __restrict__ qpos, const float* __restrict__ ipos,
    const int* __restrict__ cnt, const int* __restrict__ idxs,
    int* __restrict__ cells, float* __restrict__ coefs, int nq)
{
    int t = blockIdx.x * blockDim.x + threadIdx.x;
    int q = t / K, k = t - q * K;
    if (q >= nq) return;
    if (k >= cnt[q]) return;
    int j = idxs[q*K + k];
    float rx = (ipos[j*3+0] - qpos[q*3+0]) / RAD;
    float ry = (ipos[j*3+1] - qpos[q*3+1]) / RAD;
    float rz = (ipos[j*3+2] - qpos[q*3+2]) / RAD;
    float r2 = rx*rx + ry*ry + rz*rz;
    float w1 = 1.f - r2;
    float win = (w1 > 0.f) ? w1*w1*w1 : 0.f;   // clip((1-r2)^3, 0, 1)
    float sq = r2;
    float norm = sqrtf(sq);
    float rxy2 = rx*rx + ry*ry;
    float xc, yc, zc;
    if (sq < 1e-12f) {
        xc = yc = zc = 0.f;
    } else if (1.25f * rz * rz > rxy2) {
        float s = sqrtf(3.0f * norm / (norm + fabsf(rz) + EPSF));
        xc = s * rx; yc = s * ry; zc = sgn(rz) * norm;
    } else {
        float s = norm / sqrtf(rxy2 + EPSF);
        xc = s * rx; yc = s * ry; zc = 1.5f * rz * s;
    }
    float rxy = sqrtf(xc*xc + yc*yc);
    const float FP = (float)(4.0 / M_PI);
    float u, v;
    if (rxy < EPSF) {
        u = 0.f; v = 0.f;
    } else if (fabsf(xc) >= fabsf(yc)) {
        float sx = (fabsf(xc) < EPSF) ? EPSF : xc;
        u = sgn(xc) * rxy;
        v = u * FP * atanf(yc / sx);
    } else {
        float sy = (fabsf(yc) < EPSF) ? EPSF : yc;
        v = sgn(yc) * rxy;
        u = v * FP * atanf(xc / sy);
    }
    float gx = fminf(fmaxf((u  + 1.f) * 0.5f * 3.f, 0.f), 3.f);
    float gy = fminf(fmaxf((v  + 1.f) * 0.5f * 3.f, 0.f), 3.f);
    float gz = fminf(fmaxf((zc + 1.f) * 0.5f * 3.f, 0.f), 3.f);
    int ix = min((int)floorf(gx), 2);
    int iy = min((int)floorf(gy), 2);
    int iz = min((int)floorf(gz), 2);
    float tx = gx - (float)ix, ty = gy - (float)iy, tz = gz - (float)iz;
    cells[q*K + k] = iz*16 + iy*4 + ix;
    float wx[2] = {1.f - tx, tx}, wy[2] = {1.f - ty, ty}, wz[2] = {1.f - tz, tz};
    float* cf = coefs + (size_t)(q*K + k) * 8;
#pragma unroll
    for (int c = 0; c < 8; ++c)   // c = dx*4 + dy*2 + dz (python loop order)
        cf[c] = wx[c >> 2] * wy[(c >> 1) & 1] * wz[c & 1] * win;
}

// -------- scatter: build S[n, 64*F (+F ext)] rows in global workspace --------
// One block per query point; wave w exclusively owns z-slab w (cells 16w..16w+15),
// so accumulation is plain LDS read-modify-write — NO atomics (LDS float atomics
// measured ~3.5 cyc/lane-op in r2: the 805us pathology).
// EXT appends relu(feats[n]) so the dense skip rides the same GEMM.
template<int F, int RELU, int EXT>
__global__ __launch_bounds__(256) void scatter_kernel(
    const float* __restrict__ feats,
    const int* __restrict__ cnt, const int* __restrict__ nidx,
    const int* __restrict__ ncell, const float* __restrict__ ncoef,
    float* __restrict__ Sg)
{
    constexpr int KT = 64 * F + (EXT ? F : 0);
    __shared__ float S[64 * F];
    int n = blockIdx.x;
    int tid = threadIdx.x;
    int lane = tid & 63, w = tid >> 6;
    // zero own slab only (no cross-wave writes before the final barrier)
    float* Sw = S + w * 16 * F;
    for (int i = lane; i < 16 * F; i += 64) Sw[i] = 0.f;
    int cn = cnt[n];
    for (int k = 0; k < cn; ++k) {
        int cb = ncell[n*K + k];
        int iz0 = cb >> 4;
        int dz = w - iz0;              // wave-uniform; no lane divergence
        if ((unsigned)dz <= 1u) {
            int j = nidx[n*K + k];
            const float* cf8 = ncoef + (size_t)(n*K + k) * 8;
            float4 cA = *reinterpret_cast<const float4*>(cf8);      // c = 0..3
            float4 cB = *reinterpret_cast<const float4*>(cf8 + 4);  // c = 4..7
            float v0 = 0.f, v1 = 0.f;
            if (lane < F) {
                v0 = feats[(size_t)j*F + lane];
                if (RELU) v0 = fmaxf(v0, 0.f);
            }
            if (F > 64 && lane < F - 64) {
                v1 = feats[(size_t)j*F + 64 + lane];
                if (RELU) v1 = fmaxf(v1, 0.f);
            }
            // coef index c = dx*4 + dy*2 + dz ; cell = cb + dz*16 + dy*4 + dx
            int base = cb + dz * 16;
            float w00 = dz ? cA.y : cA.x;   // dx=0,dy=0
            float w01 = dz ? cA.w : cA.z;   // dx=0,dy=1
            float w10 = dz ? cB.y : cB.x;   // dx=1,dy=0
            float w11 = dz ? cB.w : cB.z;   // dx=1,dy=1
            float wq[4] = {w00, w01, w10, w11};   // ordered by dx*2+dy
#pragma unroll
            for (int q = 0; q < 4; ++q) {
                // q = dx*2+dy: dx = q>>1, dy = q&1
                int cell = base + (q & 1) * 4 + (q >> 1);   // + dy*4 + dx
                float wgt = wq[q];   // r3 BUG was wq[dx+2*dy] (transposed w01/w10)
                if (lane < F)                S[cell*F + lane]      += wgt * v0;
                if (F > 64 && lane < F - 64) S[cell*F + 64 + lane] += wgt * v1;
            }
        }
    }
    __syncthreads();
    float* row = Sg + (size_t)n * KT;
#pragma unroll 4
    for (int i = tid; i < 64 * F / 4; i += 256)
        reinterpret_cast<float4*>(row)[i] = reinterpret_cast<const float4*>(S)[i];
    if (EXT) {
        for (int f = tid; f < F; f += 256) {
            float v = feats[(size_t)n*F + f];
            if (RELU) v = fmaxf(v, 0.f);
            row[64*F + f] = v;
        }
    }
}

// ----------------- tiled fp32 GEMM with interleaved split-K ------------------
// C_part[ky] = A[M,K] x B[K,O] over k-tiles t = ky, ky+KC, ... (deterministic).
// Partials are summed (plus bias/resid/scale) in a tiny epilogue kernel.
template<int O>
__global__ __launch_bounds__(256) void gemm_kernel(
    const float* __restrict__ A, int Kdim,
    const float* __restrict__ B,
    float* __restrict__ P,   // [gridDim.y][M][O]
    int M)
{
    constexpr int TX   = O / 4;        // threads along O (16 or 8)
    constexpr int TY   = 256 / TX;     // threads along M (16 or 32)
    constexpr int MT   = TY * 4;       // 64 or 128
    constexpr int ASTR = MT + 4;       // pad: keeps 16B align + no conflicts
    __shared__ float As[16][ASTR];     // k-major
    __shared__ float Bs[16 * O];
    int tid = threadIdx.x;
    int tx = tid % TX, ty = tid / TX;
    int m0 = blockIdx.x * MT;
    int ntiles = Kdim >> 4;
    float acc[4][4] = {};
    for (int t = blockIdx.y; t < ntiles; t += gridDim.y) {
        int k0 = t << 4;
        __syncthreads();
        // A tile: MT x 16, stored k-major into As
#pragma unroll
        for (int l = 0; l < MT / 64; ++l) {
            int idx = tid + l * 256;
            int mm = idx >> 2, k4 = idx & 3;
            int gm = m0 + mm; if (gm >= M) gm = M - 1;
            float4 av = *reinterpret_cast<const float4*>(A + (size_t)gm * Kdim + k0 + k4 * 4);
            As[k4*4+0][mm] = av.x; As[k4*4+1][mm] = av.y;
            As[k4*4+2][mm] = av.z; As[k4*4+3][mm] = av.w;
        }
        // B tile: 16 x O, contiguous in global
        constexpr int NB4 = 16 * O / 4;
        if (NB4 == 256 || tid < NB4)
            *reinterpret_cast<float4*>(&Bs[tid*4]) =
                *reinterpret_cast<const float4*>(B + (size_t)k0 * O + tid * 4);
        __syncthreads();
#pragma unroll
        for (int kk = 0; kk < 16; ++kk) {
            float4 av = *reinterpret_cast<const float4*>(&As[kk][ty*4]);
            float4 bv = *reinterpret_cast<const float4*>(&Bs[kk*O + tx*4]);
            float aa[4] = {av.x, av.y, av.z, av.w};
            float bb[4] = {bv.x, bv.y, bv.z, bv.w};
#pragma unroll
            for (int i = 0; i < 4; ++i)
#pragma unroll
                for (int j = 0; j < 4; ++j)
                    acc[i][j] += aa[i] * bb[j];
        }
    }
    float* Pb = P + (size_t)blockIdx.y * M * O;
#pragma unroll
    for (int i = 0; i < 4; ++i) {
        int gm = m0 + ty*4 + i;
        if (gm < M)
#pragma unroll
            for (int j = 0; j < 4; ++j)
                Pb[(size_t)gm * O + tx*4 + j] = acc[i][j];
    }
}

// ----- small-O GEMM for the final layer (O padded to 4), epilogue fused -----
__global__ __launch_bounds__(256) void gemm_small_kernel(
    const float* __restrict__ A, int Kdim, const float* __restrict__ B4,
    const float* __restrict__ cb, const float* __restrict__ db,
    float* __restrict__ out, int M, float scale)
{
    int w = (blockIdx.x * blockDim.x + threadIdx.x) >> 6;
    int lane = threadIdx.x & 63;
    if (w >= M) return;
    const float* Ar = A + (size_t)w * Kdim;
    float a0 = 0.f, a1 = 0.f, a2 = 0.f;
    for (int k = lane; k < Kdim; k += 64) {
        float a = Ar[k];
        float4 b = *reinterpret_cast<const float4*>(B4 + (size_t)k * 4);
        a0 += a * b.x; a1 += a * b.y; a2 += a * b.z;
    }
#pragma unroll
    for (int s = 32; s > 0; s >>= 1) {
        a0 += __shfl_down(a0, s);
        a1 += __shfl_down(a1, s);
        a2 += __shfl_down(a2, s);
    }
    if (lane == 0) {
        out[w*3+0] = (a0 + cb[0] + db[0]) * scale;
        out[w*3+1] = (a1 + cb[1] + db[1]) * scale;
        out[w*3+2] = (a2 + cb[2] + db[2]) * scale;
    }
}

// build padded [K,4] filter for the last layer: rows = [c3_w ; d3_w], col3 = 0
__global__ __launch_bounds__(256) void b3pad_kernel(
    const float* __restrict__ c3w, const float* __restrict__ d3w,
    float* __restrict__ B4, int Kc /*=4096*/, int Kt /*=4160*/)
{
    int k = blockIdx.x * blockDim.x + threadIdx.x;
    if (k >= Kt) return;
    const float* src = (k < Kc) ? (c3w + (size_t)k * 3) : (d3w + (size_t)(k - Kc) * 3);
    B4[k*4+0] = src[0]; B4[k*4+1] = src[1]; B4[k*4+2] = src[2]; B4[k*4+3] = 0.f;
}

__global__ __launch_bounds__(256) void ff_kernel(const float* __restrict__ vel,
                                                 float* __restrict__ ff) {
    int t = blockIdx.x * blockDim.x + threadIdx.x;
    if (t >= NQ) return;
    ff[t*4+0] = 1.f;
    ff[t*4+1] = vel[t*3+0];
    ff[t*4+2] = vel[t*3+1];
    ff[t*4+3] = vel[t*3+2];
}

__global__ __launch_bounds__(256) void d0_kernel(const float* __restrict__ ff,
                                                 const float* __restrict__ w,
                                                 const float* __restrict__ b,
                                                 float* __restrict__ x1) {
    int t = blockIdx.x * blockDim.x + threadIdx.x;
    if (t >= NQ * 32) return;
    int n = t >> 5, o = t & 31;
    float acc = b[o];
#pragma unroll
    for (int f = 0; f < 4; ++f) acc += ff[n*4+f] * w[f*32+o];
    x1[n*96 + 64 + o] = acc;
}

// epilogue for layer 0: x1[:,0:32] = sum(Pco)+co_b ; x1[:,32:64] = sum(Pcf)+cf_b
__global__ __launch_bounds__(256) void e0_kernel(
    const float* __restrict__ Pco, const float* __restrict__ Pcf, int KC,
    const float* __restrict__ cob, const float* __restrict__ cfb,
    float* __restrict__ x1)
{
    int t = blockIdx.x * blockDim.x + threadIdx.x;
    if (t >= NQ * 64) return;
    int n = t >> 6, c = t & 63;
    float v;
    if (c < 32) {
        v = cob[c];
        for (int ky = 0; ky < KC; ++ky) v += Pco[(size_t)ky * NQ * 32 + n*32 + c];
    } else {
        int cc = c - 32;
        v = cfb[cc];
        for (int ky = 0; ky < KC; ++ky) v += Pcf[(size_t)ky * NQ * 32 + n*32 + cc];
    }
    x1[n*96 + c] = v;
}

// epilogue for layers 1/2: xo = sum_ky(P) + cb + db (+ resid)
__global__ __launch_bounds__(256) void e_kernel(
    const float* __restrict__ P, int KC,
    const float* __restrict__ cb, const float* __restrict__ db,
    const float* __restrict__ resid, float* __restrict__ xo)
{
    int t = blockIdx.x * blockDim.x + threadIdx.x;
    if (t >= NQ * 64) return;
    int o = t & 63;
    float v = cb[o] + db[o];
    for (int ky = 0; ky < KC; ++ky) v += P[(size_t)ky * NQ * 64 + t];
    if (resid) v += resid[t];
    xo[t] = v;
}

} // namespace

extern "C" void kernel_launch(void* const* d_in, const int* in_sizes, int n_in,
                              void* d_out, int out_size, void* d_ws, size_t ws_size,
                              hipStream_t stream)
{
    const float* pos       = (const float*)d_in[0];
    const float* vel       = (const float*)d_in[1];
    const float* box       = (const float*)d_in[2];
    const float* box_feats = (const float*)d_in[3];
    const float* cf_w = (const float*)d_in[4];  const float* cf_b = (const float*)d_in[5];
    const float* co_w = (const float*)d_in[6];  const float* co_b = (const float*)d_in[7];
    const float* d0_w = (const float*)d_in[8];  const float* d0_b = (const float*)d_in[9];
    const float* c1_w = (const float*)d_in[10]; const float* c1_b = (const float*)d_in[11];
    const float* d1_w = (const float*)d_in[12]; const float* d1_b = (const float*)d_in[13];
    const float* c2_w = (const float*)d_in[14]; const float* c2_b = (const float*)d_in[15];
    const float* d2_w = (const float*)d_in[16]; const float* d2_b = (const float*)d_in[17];
    const float* c3_w = (const float*)d_in[18]; const float* c3_b = (const float*)d_in[19];
    const float* d3_w = (const float*)d_in[20]; const float* d3_b = (const float*)d_in[21];

    char* wsb = (char*)d_ws;
    size_t off = 0;
    auto alloc = [&](size_t bytes) {
        void* p = wsb + off;
        off = (off + bytes + 255) & ~(size_t)255;
        return p;
    };
    constexpr int K1 = 64*96 + 96;   // 6240
    constexpr int K2 = 64*64 + 64;   // 4160
    constexpr int KC  = 8;           // split-K chunks, big GEMMs
    constexpr int KCS = 2;           // split-K chunks, small layer-0 GEMMs

    int*   f_cnt  = (int*)  alloc((size_t)NQ * 4);
    int*   f_idx  = (int*)  alloc((size_t)NQ * K * 4);
    float* f_d2   = (float*)alloc((size_t)NQ * K * 4);
    int*   f_cell = (int*)  alloc((size_t)NQ * K * 4);
    float* f_coef = (float*)alloc((size_t)NQ * K * 8 * 4);
    int*   b_cnt  = (int*)  alloc((size_t)NQ * 4);
    int*   b_idx  = (int*)  alloc((size_t)NQ * K * 4);
    float* b_d2   = (float*)alloc((size_t)NQ * K * 4);
    int*   b_cell = (int*)  alloc((size_t)NQ * K * 4);
    float* b_coef = (float*)alloc((size_t)NQ * K * 8 * 4);
    float* ff     = (float*)alloc((size_t)NQ * 4 * 4);
    float* x1     = (float*)alloc((size_t)NQ * 96 * 4);
    float* x2     = (float*)alloc((size_t)NQ * 64 * 4);
    float* x3     = (float*)alloc((size_t)NQ * 64 * 4);
    float* B1     = (float*)alloc((size_t)K1 * 64 * 4);
    float* B2     = (float*)alloc((size_t)K2 * 64 * 4);
    float* B3     = (float*)alloc((size_t)K2 * 4 * 4);
    float* P      = (float*)alloc((size_t)KC * NQ * 64 * 4);    // big-GEMM partials
    float* Pco    = (float*)alloc((size_t)KCS * NQ * 32 * 4);
    float* Pcf    = (float*)alloc((size_t)KCS * NQ * 32 * 4);
    float* SB     = (float*)alloc((size_t)NQ * K1 * 4);         // reused S buffer
    float* S_cf   = SB;                         // [NQ,256]
    float* S_co   = SB + (size_t)NQ * 256;      // [NQ,192]

    dim3 b256(256);
    // neighbor searches + geometry
    nn_kernel<<<(NQ*64 + 255)/256, b256, 0, stream>>>(pos, NQ, pos, NQ, 1, f_cnt, f_idx, f_d2);
    nn_kernel<<<(NQ*64 + 255)/256, b256, 0, stream>>>(pos, NQ, box, NB, 0, b_cnt, b_idx, b_d2);
    coef_kernel<<<(NQ*K + 255)/256, b256, 0, stream>>>(pos, pos, f_cnt, f_idx, f_cell, f_coef, NQ);
    coef_kernel<<<(NQ*K + 255)/256, b256, 0, stream>>>(pos, box, b_cnt, b_idx, b_cell, b_coef, NQ);
    ff_kernel<<<(NQ + 255)/256, b256, 0, stream>>>(vel, ff);
    // concat filter matrices: B1 = [c1_w ; d1_w], B2 = [c2_w ; d2_w], B3 padded
    hipMemcpyAsync(B1,           c1_w, (size_t)64*96*64*4, hipMemcpyDeviceToDevice, stream);
    hipMemcpyAsync(B1 + 6144*64, d1_w, (size_t)96*64*4,    hipMemcpyDeviceToDevice, stream);
    hipMemcpyAsync(B2,           c2_w, (size_t)64*64*64*4, hipMemcpyDeviceToDevice, stream);
    hipMemcpyAsync(B2 + 4096*64, d2_w, (size_t)64*64*4,    hipMemcpyDeviceToDevice, stream);
    b3pad_kernel<<<(K2 + 255)/256, b256, 0, stream>>>(c3_w, d3_w, B3, 4096, K2);

    // ---- layer 0 ----
    scatter_kernel<4,0,0><<<NQ, b256, 0, stream>>>(ff, f_cnt, f_idx, f_cell, f_coef, S_cf);
    scatter_kernel<3,0,0><<<NQ, b256, 0, stream>>>(box_feats, b_cnt, b_idx, b_cell, b_coef, S_co);
    gemm_kernel<32><<<dim3((NQ+127)/128, KCS), b256, 0, stream>>>(S_co, 192, co_w, Pco, NQ);
    gemm_kernel<32><<<dim3((NQ+127)/128, KCS), b256, 0, stream>>>(S_cf, 256, cf_w, Pcf, NQ);
    d0_kernel<<<(NQ*32 + 255)/256, b256, 0, stream>>>(ff, d0_w, d0_b, x1);
    e0_kernel<<<(NQ*64 + 255)/256, b256, 0, stream>>>(Pco, Pcf, KCS, co_b, cf_b, x1);
    // ---- layer 1: x2 = cconv(relu(x1)) + relu(x1)@d1 + biases ----
    scatter_kernel<96,1,1><<<NQ, b256, 0, stream>>>(x1, f_cnt, f_idx, f_cell, f_coef, SB);
    gemm_kernel<64><<<dim3((NQ+63)/64, KC), b256, 0, stream>>>(SB, K1, B1, P, NQ);
    e_kernel<<<(NQ*64 + 255)/256, b256, 0, stream>>>(P, KC, c1_b, d1_b, nullptr, x2);
    // ---- layer 2: x3 = [cconv(relu(x2)) + relu(x2)@d2 + biases] + x2 ----
    scatter_kernel<64,1,1><<<NQ, b256, 0, stream>>>(x2, f_cnt, f_idx, f_cell, f_coef, SB);
    gemm_kernel<64><<<dim3((NQ+63)/64, KC), b256, 0, stream>>>(SB, K2, B2, P, NQ);
    e_kernel<<<(NQ*64 + 255)/256, b256, 0, stream>>>(P, KC, c2_b, d2_b, x2, x3);
    // ---- layer 3: out = [cconv(relu(x3)) + relu(x3)@d3 + biases] / 128 ----
    scatter_kernel<64,1,1><<<NQ, b256, 0, stream>>>(x3, f_cnt, f_idx, f_cell, f_coef, SB);
    gemm_small_kernel<<<(NQ*64 + 255)/256, b256, 0, stream>>>(SB, K2, B3, c3_b, d3_b,
                                                              (float*)d_out, NQ, 1.f/128.f);

    (void)in_sizes; (void)n_in; (void)out_size; (void)ws_size;
    (void)f_d2; (void)b_d2;
}

// Round 5
// 504.979 us; speedup vs baseline: 4.6194x; 1.1301x over previous
//
#include <hip/hip_runtime.h>
#include <math.h>

namespace {

constexpr int NQ  = 6000;   // fluid particles (queries)
constexpr int NB  = 3000;   // box particles
constexpr int K   = 80;     // neighbor cap
constexpr float RAD = 0.1125f;
constexpr float R2  = RAD * RAD;
constexpr float EPSF = 1e-12f;

constexpr int K1  = 64*96 + 96;  // 6240
constexpr int K2  = 64*64 + 64;  // 4160
constexpr int KC  = 12;          // split-K chunks, big GEMMs
constexpr int KCS = 4;           // split-K chunks, layer-0 GEMMs

__device__ __forceinline__ float sgn(float x) {
    return (x > 0.f) ? 1.f : ((x < 0.f) ? -1.f : 0.f);
}

// ---------------- neighbor search: one wave (64 lanes) per query -------------
__device__ void nn_search(const float* __restrict__ qpos, int wid,
                          const float* __restrict__ ipos, int ni, int self_ig,
                          int* __restrict__ cnt, int* __restrict__ idxs,
                          float* __restrict__ d2s, int lane)
{
    float qx = qpos[wid*3+0], qy = qpos[wid*3+1], qz = qpos[wid*3+2];
    int base = wid * K;
    int c = 0;
    for (int j0 = 0; j0 < ni; j0 += 64) {
        int j = j0 + lane;
        float d2 = 1e30f;
        if (j < ni) {
            float dx = ipos[j*3+0]-qx, dy = ipos[j*3+1]-qy, dz = ipos[j*3+2]-qz;
            d2 = dx*dx + dy*dy + dz*dz;
            if (self_ig && j == wid) d2 = 1e30f;
        }
        bool hit = d2 <= R2;
        unsigned long long m = __ballot(hit);
        int pc = __popcll(m);
        if (pc == 0) continue;
        if (c + pc <= K) {
            if (hit) {
                int pos = c + __popcll(m & ((1ull << lane) - 1ull));
                idxs[base + pos] = j;
                d2s [base + pos] = d2;
            }
            c += pc;
        } else {
            // rare overflow path: keep the K nearest (top_k semantics)
            while (m) {
                int l = __ffsll((unsigned long long)m) - 1;
                m &= m - 1ull;
                float dd = __shfl(d2, l);
                int jj = j0 + l;
                if (c < K) {
                    idxs[base + c] = jj;
                    d2s [base + c] = dd;
                    c++;
                } else {
                    float mx = -1.f; int am = 0;
                    for (int s = 0; s < K; ++s) {
                        float v = d2s[base + s];
                        if (v > mx) { mx = v; am = s; }
                    }
                    if (dd < mx) {
                        idxs[base + am] = jj;
                        d2s [base + am] = dd;
                    }
                }
            }
        }
    }
    if (lane == 0) cnt[wid] = c;
}

// merged: waves [0,NQ) = fluid self-search, [NQ,2NQ) = box search
__global__ __launch_bounds__(256) void nn2_kernel(
    const float* __restrict__ pos, const float* __restrict__ box,
    int* __restrict__ f_cnt, int* __restrict__ f_idx, float* __restrict__ f_d2,
    int* __restrict__ b_cnt, int* __restrict__ b_idx, float* __restrict__ b_d2)
{
    int gw = (blockIdx.x * blockDim.x + threadIdx.x) >> 6;
    int lane = threadIdx.x & 63;
    if (gw < NQ)
        nn_search(pos, gw, pos, NQ, 1, f_cnt, f_idx, f_d2, lane);
    else
        nn_search(pos, gw - NQ, box, NB, 0, b_cnt, b_idx, b_d2, lane);
}

// ------------- per-neighbor geometry: ball->cube + trilinear coefs -----------
__device__ void coef_one(const float* __restrict__ qpos, const float* __restrict__ ipos,
                         const int* __restrict__ cnt, const int* __restrict__ idxs,
                         int* __restrict__ cells, float* __restrict__ coefs,
                         int q, int k)
{
    if (k >= cnt[q]) return;
    int j = idxs[q*K + k];
    float rx = (ipos[j*3+0] - qpos[q*3+0]) / RAD;
    float ry = (ipos[j*3+1] - qpos[q*3+1]) / RAD;
    float rz = (ipos[j*3+2] - qpos[q*3+2]) / RAD;
    float r2 = rx*rx + ry*ry + rz*rz;
    float w1 = 1.f - r2;
    float win = (w1 > 0.f) ? w1*w1*w1 : 0.f;   // clip((1-r2)^3, 0, 1)
    float norm = sqrtf(r2);
    float rxy2 = rx*rx + ry*ry;
    float xc, yc, zc;
    if (r2 < 1e-12f) {
        xc = yc = zc = 0.f;
    } else if (1.25f * rz * rz > rxy2) {
        float s = sqrtf(3.0f * norm / (norm + fabsf(rz) + EPSF));
        xc = s * rx; yc = s * ry; zc = sgn(rz) * norm;
    } else {
        float s = norm / sqrtf(rxy2 + EPSF);
        xc = s * rx; yc = s * ry; zc = 1.5f * rz * s;
    }
    float rxy = sqrtf(xc*xc + yc*yc);
    const float FP = (float)(4.0 / M_PI);
    float u, v;
    if (rxy < EPSF) {
        u = 0.f; v = 0.f;
    } else if (fabsf(xc) >= fabsf(yc)) {
        float sx = (fabsf(xc) < EPSF) ? EPSF : xc;
        u = sgn(xc) * rxy;
        v = u * FP * atanf(yc / sx);
    } else {
        float sy = (fabsf(yc) < EPSF) ? EPSF : yc;
        v = sgn(yc) * rxy;
        u = v * FP * atanf(xc / sy);
    }
    float gx = fminf(fmaxf((u  + 1.f) * 0.5f * 3.f, 0.f), 3.f);
    float gy = fminf(fmaxf((v  + 1.f) * 0.5f * 3.f, 0.f), 3.f);
    float gz = fminf(fmaxf((zc + 1.f) * 0.5f * 3.f, 0.f), 3.f);
    int ix = min((int)floorf(gx), 2);
    int iy = min((int)floorf(gy), 2);
    int iz = min((int)floorf(gz), 2);
    float tx = gx - (float)ix, ty = gy - (float)iy, tz = gz - (float)iz;
    cells[q*K + k] = iz*16 + iy*4 + ix;
    float wx[2] = {1.f - tx, tx}, wy[2] = {1.f - ty, ty}, wz[2] = {1.f - tz, tz};
    float* cf = coefs + (size_t)(q*K + k) * 8;
#pragma unroll
    for (int c = 0; c < 8; ++c)   // c = dx*4 + dy*2 + dz (python loop order)
        cf[c] = wx[c >> 2] * wy[(c >> 1) & 1] * wz[c & 1] * win;
}

__global__ __launch_bounds__(256) void coef2_kernel(
    const float* __restrict__ pos, const float* __restrict__ box,
    const int* __restrict__ f_cnt, const int* __restrict__ f_idx,
    int* __restrict__ f_cell, float* __restrict__ f_coef,
    const int* __restrict__ b_cnt, const int* __restrict__ b_idx,
    int* __restrict__ b_cell, float* __restrict__ b_coef)
{
    int t = blockIdx.x * blockDim.x + threadIdx.x;
    if (t < NQ * K)
        coef_one(pos, pos, f_cnt, f_idx, f_cell, f_coef, t / K, t % K);
    else if (t < 2 * NQ * K) {
        int t2 = t - NQ * K;
        coef_one(pos, box, b_cnt, b_idx, b_cell, b_coef, t2 / K, t2 % K);
    }
}

// -------- big scatter (F in {64,96}): build S[n, 64F(+F)] rows ---------------
// Wave w owns z-slab w (cells 16w..16w+15): plain LDS RMW, no atomics.
// Activity precomputed as ballot masks; cb/j via __shfl; coefs staged in LDS;
// 1-deep pipeline prefetches next active neighbor's feature row.
template<int F, int RELU, int EXT>
__global__ __launch_bounds__(256) void scatter_kernel(
    const float* __restrict__ feats,
    const int* __restrict__ cnt, const int* __restrict__ nidx,
    const int* __restrict__ ncell, const float* __restrict__ ncoef,
    float* __restrict__ Sg)
{
    constexpr int KT = 64 * F + (EXT ? F : 0);
    __shared__ __align__(16) float S[64 * F];
    __shared__ __align__(16) float coefL[K * 8];
    int n = blockIdx.x;
    int tid = threadIdx.x, lane = tid & 63, w = tid >> 6;
    int cn = cnt[n];
    // stage coefs as float4 (global row is 32B-aligned per neighbor)
    {
        const float4* src = (const float4*)(ncoef + (size_t)n * K * 8);
        for (int i = tid; i < cn * 2; i += 256) ((float4*)coefL)[i] = src[i];
    }
    // zero own slab
    float* Sw = S + w * 16 * F;
    for (int i = lane; i < 16 * F; i += 64) Sw[i] = 0.f;
    // per-lane neighbor meta (k = lane and k = 64+lane)
    int kk2 = 64 + lane;
    int cb1 = (lane < cn) ? ncell[n*K + lane] : 0;
    int j1  = (lane < cn) ? nidx [n*K + lane] : 0;
    int cb2 = (kk2 < cn) ? ncell[n*K + kk2] : 0;
    int j2  = (kk2 < cn) ? nidx [n*K + kk2] : 0;
    int dzl1 = w - (cb1 >> 4);
    int dzl2 = w - (cb2 >> 4);
    bool a1 = (lane < cn) && ((unsigned)dzl1 <= 1u);
    bool a2 = (kk2 < cn) && ((unsigned)dzl2 <= 1u);
    unsigned long long act0 = __ballot(a1), act1 = __ballot(a2);
    unsigned long long dzm0 = __ballot(dzl1 == 1), dzm1 = __ballot(dzl2 == 1);
    __syncthreads();   // coefL ready

#define POP(K_, DZ_, J_, CB_) do { \
    if (act0) { int b_ = __builtin_ctzll(act0); act0 &= act0 - 1ull; \
        K_ = b_; DZ_ = (int)((dzm0 >> b_) & 1ull); \
        J_ = __shfl(j1, b_); CB_ = __shfl(cb1, b_); } \
    else if (act1) { int b_ = __builtin_ctzll(act1); act1 &= act1 - 1ull; \
        K_ = 64 + b_; DZ_ = (int)((dzm1 >> b_) & 1ull); \
        J_ = __shfl(j2, b_); CB_ = __shfl(cb2, b_); } \
    else K_ = -1; } while (0)

    int k = -1, dz = 0, j = 0, cb = 0;
    POP(k, dz, j, cb);
    float v0 = 0.f, v1 = 0.f;
    if (k >= 0) {
        v0 = feats[(size_t)j * F + lane];
        if (RELU) v0 = fmaxf(v0, 0.f);
        if (F > 64 && lane < F - 64) {
            v1 = feats[(size_t)j * F + 64 + lane];
            if (RELU) v1 = fmaxf(v1, 0.f);
        }
    }
    while (k >= 0) {
        int kN = -1, dzN = 0, jN = 0, cbN = 0;
        POP(kN, dzN, jN, cbN);
        float n0 = 0.f, n1 = 0.f;
        if (kN >= 0) {                       // prefetch next row (overlaps RMW)
            n0 = feats[(size_t)jN * F + lane];
            if (RELU) n0 = fmaxf(n0, 0.f);
            if (F > 64 && lane < F - 64) {
                n1 = feats[(size_t)jN * F + 64 + lane];
                if (RELU) n1 = fmaxf(n1, 0.f);
            }
        }
        float4 cA = ((const float4*)coefL)[k*2];      // c = 0..3  (dx=0)
        float4 cB = ((const float4*)coefL)[k*2 + 1];  // c = 4..7  (dx=1)
        int base = cb + dz * 16;
        float w00 = dz ? cA.y : cA.x;   // (dx0,dy0)
        float w01 = dz ? cA.w : cA.z;   // (dx0,dy1)
        float w10 = dz ? cB.y : cB.x;   // (dx1,dy0)
        float w11 = dz ? cB.w : cB.z;   // (dx1,dy1)
        int c00 = base, c01 = base + 4, c10 = base + 1, c11 = base + 5;
        S[c00*F + lane] += w00 * v0;
        S[c01*F + lane] += w01 * v0;
        S[c10*F + lane] += w10 * v0;
        S[c11*F + lane] += w11 * v0;
        if (F > 64 && lane < F - 64) {
            S[c00*F + 64 + lane] += w00 * v1;
            S[c01*F + 64 + lane] += w01 * v1;
            S[c10*F + 64 + lane] += w10 * v1;
            S[c11*F + 64 + lane] += w11 * v1;
        }
        k = kN; dz = dzN; cb = cbN; v0 = n0; v1 = n1;
    }
#undef POP
    __syncthreads();
    float* row = Sg + (size_t)n * KT;
    for (int i = tid; i < 64 * F / 4; i += 256)
        reinterpret_cast<float4*>(row)[i] = reinterpret_cast<const float4*>(S)[i];
    if (EXT) {
        for (int f = tid; f < F; f += 256) {
            float v = feats[(size_t)n * F + f];
            if (RELU) v = fmaxf(v, 0.f);
            row[64 * F + f] = v;
        }
    }
}

// ------- small scatter (F in {3,4}): one WAVE per point, lane=(corner,feat) --
// One LDS RMW covers all 8 corners of a neighbor (no slab split needed: the
// wave owns the whole 64xF table; intra-wave lanes hit distinct addresses).
template<int F>
__global__ __launch_bounds__(256) void scatter_small_kernel(
    const float* __restrict__ feats,
    const int* __restrict__ cnt, const int* __restrict__ nidx,
    const int* __restrict__ ncell, const float* __restrict__ ncoef,
    float* __restrict__ Sg, int nq)
{
    __shared__ __align__(16) float S4[4][64 * F];
    int tid = threadIdx.x, lane = tid & 63, w = tid >> 6;
    int n = blockIdx.x * 4 + w;
    if (n >= nq) return;
    float* Sw = S4[w];
    for (int i = lane; i < 64 * F; i += 64) Sw[i] = 0.f;
    int cn = cnt[n];
    int kk2 = 64 + lane;
    int cb1 = (lane < cn) ? ncell[n*K + lane] : 0;
    int j1  = (lane < cn) ? nidx [n*K + lane] : 0;
    int cb2 = (kk2 < cn) ? ncell[n*K + kk2] : 0;
    int j2  = (kk2 < cn) ? nidx [n*K + kk2] : 0;
    int c = lane & 7, f = lane >> 3;
    bool fok = f < F;                         // F=4: 32 lanes, F=3: 24 lanes
    const float* coefG = ncoef + (size_t)n * K * 8;

    float wgt = 0.f, v = 0.f; int cb = 0;
    if (cn > 0) {
        int j = __shfl(j1, 0); cb = __shfl(cb1, 0);
        if (fok) { wgt = coefG[c]; v = feats[(size_t)j * F + f]; }
    }
    for (int kk = 0; kk < cn; ++kk) {
        float wn = 0.f, vn = 0.f; int cbn = 0;
        int k1n = kk + 1;
        if (k1n < cn) {                        // prefetch next neighbor
            int jn = (k1n < 64) ? __shfl(j1, k1n) : __shfl(j2, k1n - 64);
            cbn    = (k1n < 64) ? __shfl(cb1, k1n) : __shfl(cb2, k1n - 64);
            if (fok) { wn = coefG[k1n*8 + c]; vn = feats[(size_t)jn * F + f]; }
        }
        if (fok) {
            int cell = cb + (c & 1)*16 + ((c >> 1) & 1)*4 + (c >> 2);
            Sw[cell*F + f] += wgt * v;
        }
        wgt = wn; v = vn; cb = cbn;
    }
    float* row = Sg + (size_t)n * (64 * F);
    for (int i = lane; i < 16 * F; i += 64)
        ((float4*)row)[i] = ((const float4*)Sw)[i];
}

// ----------------- layer-0 GEMM (4x4 blocking), interleaved split-K ----------
template<int O>
__global__ __launch_bounds__(256) void gemm_kernel(
    const float* __restrict__ A, int Kdim,
    const float* __restrict__ B,
    float* __restrict__ P, int M)
{
    constexpr int TX   = O / 4;
    constexpr int TY   = 256 / TX;
    constexpr int MT   = TY * 4;
    constexpr int ASTR = MT + 4;
    __shared__ float As[16][ASTR];
    __shared__ float Bs[16 * O];
    int tid = threadIdx.x;
    int tx = tid % TX, ty = tid / TX;
    int m0 = blockIdx.x * MT;
    int ntiles = Kdim >> 4;
    float acc[4][4] = {};
    for (int t = blockIdx.y; t < ntiles; t += gridDim.y) {
        int k0 = t << 4;
        __syncthreads();
#pragma unroll
        for (int l = 0; l < MT / 64; ++l) {
            int idx = tid + l * 256;
            int mm = idx >> 2, k4 = idx & 3;
            int gm = m0 + mm; if (gm >= M) gm = M - 1;
            float4 av = *reinterpret_cast<const float4*>(A + (size_t)gm * Kdim + k0 + k4 * 4);
            As[k4*4+0][mm] = av.x; As[k4*4+1][mm] = av.y;
            As[k4*4+2][mm] = av.z; As[k4*4+3][mm] = av.w;
        }
        constexpr int NB4 = 16 * O / 4;
        if (NB4 == 256 || tid < NB4)
            *reinterpret_cast<float4*>(&Bs[tid*4]) =
                *reinterpret_cast<const float4*>(B + (size_t)k0 * O + tid * 4);
        __syncthreads();
#pragma unroll
        for (int kk = 0; kk < 16; ++kk) {
            float4 av = *reinterpret_cast<const float4*>(&As[kk][ty*4]);
            float4 bv = *reinterpret_cast<const float4*>(&Bs[kk*O + tx*4]);
            float aa[4] = {av.x, av.y, av.z, av.w};
            float bb[4] = {bv.x, bv.y, bv.z, bv.w};
#pragma unroll
            for (int i = 0; i < 4; ++i)
#pragma unroll
                for (int jj = 0; jj < 4; ++jj)
                    acc[i][jj] += aa[i] * bb[jj];
        }
    }
    float* Pb = P + (size_t)blockIdx.y * M * O;
#pragma unroll
    for (int i = 0; i < 4; ++i) {
        int gm = m0 + ty*4 + i;
        if (gm < M)
#pragma unroll
            for (int jj = 0; jj < 4; ++jj)
                Pb[(size_t)gm * O + tx*4 + jj] = acc[i][jj];
    }
}

// ----------------- O=64 GEMM: 128x64 tile, 8x4 per thread --------------------
__global__ __launch_bounds__(256) void gemm64_kernel(
    const float* __restrict__ A, int Kdim,
    const float* __restrict__ B,
    float* __restrict__ P, int M)
{
    constexpr int MT = 128, ASTR = MT + 4;
    __shared__ float As[16][ASTR];          // k-major
    __shared__ float Bs[16 * 64];
    int tid = threadIdx.x;
    int tx = tid & 15, ty = tid >> 4;       // tx: o-group of 4, ty: m-group of 8
    int m0 = blockIdx.x * MT;
    int ntiles = Kdim >> 4;
    float acc[8][4] = {};
    for (int t = blockIdx.y; t < ntiles; t += gridDim.y) {
        int k0 = t << 4;
        __syncthreads();
#pragma unroll
        for (int l = 0; l < 2; ++l) {       // A: 128x16 = 512 float4
            int idx = tid + l * 256;
            int mm = idx >> 2, k4 = idx & 3;
            int gm = m0 + mm; if (gm >= M) gm = M - 1;
            float4 av = *reinterpret_cast<const float4*>(A + (size_t)gm * Kdim + k0 + k4 * 4);
            As[k4*4+0][mm] = av.x; As[k4*4+1][mm] = av.y;
            As[k4*4+2][mm] = av.z; As[k4*4+3][mm] = av.w;
        }
        *reinterpret_cast<float4*>(&Bs[tid*4]) =
            *reinterpret_cast<const float4*>(B + (size_t)k0 * 64 + tid * 4);
        __syncthreads();
#pragma unroll
        for (int kk = 0; kk < 16; ++kk) {
            float4 a0 = *reinterpret_cast<const float4*>(&As[kk][ty*8]);
            float4 a1 = *reinterpret_cast<const float4*>(&As[kk][ty*8+4]);
            float4 bv = *reinterpret_cast<const float4*>(&Bs[kk*64 + tx*4]);
            float aa[8] = {a0.x,a0.y,a0.z,a0.w,a1.x,a1.y,a1.z,a1.w};
            float bb[4] = {bv.x,bv.y,bv.z,bv.w};
#pragma unroll
            for (int i = 0; i < 8; ++i)
#pragma unroll
                for (int jj = 0; jj < 4; ++jj)
                    acc[i][jj] += aa[i] * bb[jj];
        }
    }
    float* Pb = P + (size_t)blockIdx.y * M * 64;
#pragma unroll
    for (int i = 0; i < 8; ++i) {
        int gm = m0 + ty*8 + i;
        if (gm < M) {
            float4 o = {acc[i][0], acc[i][1], acc[i][2], acc[i][3]};
            *reinterpret_cast<float4*>(&Pb[(size_t)gm * 64 + tx*4]) = o;
        }
    }
}

// ----------- prep: B1=[c1;d1], B2=[c2;d2], W3p, ff, dense-0 into x1 ----------
__global__ __launch_bounds__(256) void prep_kernel(
    const float* __restrict__ c1w, const float* __restrict__ d1w,
    const float* __restrict__ c2w, const float* __restrict__ d2w,
    const float* __restrict__ c3w, const float* __restrict__ d3w,
    const float* __restrict__ vel,
    const float* __restrict__ d0w, const float* __restrict__ d0b,
    float* __restrict__ B1, float* __restrict__ B2, float* __restrict__ W3p,
    float* __restrict__ ff, float* __restrict__ x1)
{
    int stride = gridDim.x * blockDim.x;
    int gid = blockIdx.x * blockDim.x + threadIdx.x;
    for (int i = gid; i < 64*96*64 + 96*64; i += stride)
        B1[i] = (i < 64*96*64) ? c1w[i] : d1w[i - 64*96*64];
    for (int i = gid; i < 64*64*64 + 64*64; i += stride)
        B2[i] = (i < 64*64*64) ? c2w[i] : d2w[i - 64*64*64];
    for (int i = gid; i < 64 * 195; i += stride) {   // W3p[f][c*3+o]
        int f = i / 195, r = i % 195, c = r / 3, o = r % 3;
        W3p[i] = (c < 64) ? c3w[(c*64 + f)*3 + o] : d3w[f*3 + o];
    }
    for (int i = gid; i < NQ; i += stride) {
        ff[i*4+0] = 1.f;
        ff[i*4+1] = vel[i*3+0];
        ff[i*4+2] = vel[i*3+1];
        ff[i*4+3] = vel[i*3+2];
    }
    for (int i = gid; i < NQ * 32; i += stride) {    // dense-0 skip -> x1[:,64:96]
        int n = i >> 5, o = i & 31;
        float acc = d0b[o] + d0w[o]
                  + vel[n*3+0] * d0w[32 + o]
                  + vel[n*3+1] * d0w[64 + o]
                  + vel[n*3+2] * d0w[96 + o];
        x1[n*96 + 64 + o] = acc;
    }
}

// epilogue for layer 0: x1[:,0:32] = sum(Pco)+co_b ; x1[:,32:64] = sum(Pcf)+cf_b
__global__ __launch_bounds__(256) void e0_kernel(
    const float* __restrict__ Pco, const float* __restrict__ Pcf, int kc,
    const float* __restrict__ cob, const float* __restrict__ cfb,
    float* __restrict__ x1)
{
    int t = blockIdx.x * blockDim.x + threadIdx.x;
    if (t >= NQ * 64) return;
    int n = t >> 6, c = t & 63;
    float v;
    if (c < 32) {
        v = cob[c];
        for (int ky = 0; ky < kc; ++ky) v += Pco[(size_t)ky * NQ * 32 + n*32 + c];
    } else {
        int cc = c - 32;
        v = cfb[cc];
        for (int ky = 0; ky < kc; ++ky) v += Pcf[(size_t)ky * NQ * 32 + n*32 + cc];
    }
    x1[n*96 + c] = v;
}

// epilogue for layers 1/2: xo = sum_ky(P) + cb + db (+ resid)
__global__ __launch_bounds__(256) void e_kernel(
    const float* __restrict__ P, int kc,
    const float* __restrict__ cb, const float* __restrict__ db,
    const float* __restrict__ resid, float* __restrict__ xo)
{
    int t = blockIdx.x * blockDim.x + threadIdx.x;
    if (t >= NQ * 64) return;
    int o = t & 63;
    float v = cb[o] + db[o];
    for (int ky = 0; ky < kc; ++ky) v += P[(size_t)ky * NQ * 64 + t];
    if (resid) v += resid[t];
    xo[t] = v;
}

// ---- final layer via transform+gather: Y[j, c<=64, 3] = relu(x3[j])*W3' -----
__global__ __launch_bounds__(256) void y3t_kernel(
    const float* __restrict__ x3, const float* __restrict__ W3p,
    float* __restrict__ Y)
{
    __shared__ float xr[64];
    int n = blockIdx.x, tid = threadIdx.x;
    if (tid < 64) xr[tid] = fmaxf(x3[n*64 + tid], 0.f);
    __syncthreads();
    if (tid < 195) {
        float acc = 0.f;
#pragma unroll 8
        for (int f = 0; f < 64; ++f) acc += xr[f] * W3p[f*195 + tid];
        Y[(size_t)n * 195 + tid] = acc;
    }
}

__global__ __launch_bounds__(256) void gather3_kernel(
    const int* __restrict__ cnt, const int* __restrict__ nidx,
    const int* __restrict__ ncell, const float* __restrict__ ncoef,
    const float* __restrict__ Y,
    const float* __restrict__ cb3, const float* __restrict__ db3,
    float* __restrict__ out)
{
    int gw = (blockIdx.x * blockDim.x + threadIdx.x) >> 6;
    int lane = threadIdx.x & 63;
    if (gw >= NQ) return;
    int n = gw;
    int cn = cnt[n];
    float a0 = 0.f, a1 = 0.f, a2 = 0.f;
#pragma unroll
    for (int seg = 0; seg < 2; ++seg) {
        int kidx = seg * 64 + lane;
        if (kidx < cn) {
            int j  = nidx [n*K + kidx];
            int cb = ncell[n*K + kidx];
            const float* cf = ncoef + (size_t)(n*K + kidx) * 8;
            const float* Yj = Y + (size_t)j * 195;
#pragma unroll
            for (int c = 0; c < 8; ++c) {
                int cell = cb + (c & 1)*16 + ((c >> 1) & 1)*4 + (c >> 2);
                float wgt = cf[c];
                const float* Tp = Yj + cell*3;
                a0 += wgt * Tp[0];
                a1 += wgt * Tp[1];
                a2 += wgt * Tp[2];
            }
        }
    }
#pragma unroll
    for (int s = 32; s > 0; s >>= 1) {
        a0 += __shfl_down(a0, s);
        a1 += __shfl_down(a1, s);
        a2 += __shfl_down(a2, s);
    }
    if (lane == 0) {
        const float* Yn = Y + (size_t)n * 195 + 192;   // dense skip (c=64)
        out[n*3+0] = (a0 + Yn[0] + cb3[0] + db3[0]) * (1.f/128.f);
        out[n*3+1] = (a1 + Yn[1] + cb3[1] + db3[1]) * (1.f/128.f);
        out[n*3+2] = (a2 + Yn[2] + cb3[2] + db3[2]) * (1.f/128.f);
    }
}

} // namespace

extern "C" void kernel_launch(void* const* d_in, const int* in_sizes, int n_in,
                              void* d_out, int out_size, void* d_ws, size_t ws_size,
                              hipStream_t stream)
{
    const float* pos       = (const float*)d_in[0];
    const float* vel       = (const float*)d_in[1];
    const float* box       = (const float*)d_in[2];
    const float* box_feats = (const float*)d_in[3];
    const float* cf_w = (const float*)d_in[4];  const float* cf_b = (const float*)d_in[5];
    const float* co_w = (const float*)d_in[6];  const float* co_b = (const float*)d_in[7];
    const float* d0_w = (const float*)d_in[8];  const float* d0_b = (const float*)d_in[9];
    const float* c1_w = (const float*)d_in[10]; const float* c1_b = (const float*)d_in[11];
    const float* d1_w = (const float*)d_in[12]; const float* d1_b = (const float*)d_in[13];
    const float* c2_w = (const float*)d_in[14]; const float* c2_b = (const float*)d_in[15];
    const float* d2_w = (const float*)d_in[16]; const float* d2_b = (const float*)d_in[17];
    const float* c3_w = (const float*)d_in[18]; const float* c3_b = (const float*)d_in[19];
    const float* d3_w = (const float*)d_in[20]; const float* d3_b = (const float*)d_in[21];

    char* wsb = (char*)d_ws;
    size_t off = 0;
    auto alloc = [&](size_t bytes) {
        void* p = wsb + off;
        off = (off + bytes + 255) & ~(size_t)255;
        return p;
    };
    // SB region (150 MB) is time-shared: {f_d2,b_d2} during nn -> {S_cf,S_co}
    // during layer 0 -> full S for layers 1/2.
    float* SB   = (float*)alloc((size_t)NQ * K1 * 4);
    float* f_d2 = SB;
    float* b_d2 = SB + (size_t)NQ * K;
    float* S_cf = SB;                        // [NQ,256]
    float* S_co = SB + (size_t)NQ * 256;     // [NQ,192]
    int*   f_cnt  = (int*)  alloc((size_t)NQ * 4);
    int*   f_idx  = (int*)  alloc((size_t)NQ * K * 4);
    int*   f_cell = (int*)  alloc((size_t)NQ * K * 4);
    float* f_coef = (float*)alloc((size_t)NQ * K * 8 * 4);
    int*   b_cnt  = (int*)  alloc((size_t)NQ * 4);
    int*   b_idx  = (int*)  alloc((size_t)NQ * K * 4);
    int*   b_cell = (int*)  alloc((size_t)NQ * K * 4);
    float* b_coef = (float*)alloc((size_t)NQ * K * 8 * 4);
    float* ff     = (float*)alloc((size_t)NQ * 4 * 4);
    float* x1     = (float*)alloc((size_t)NQ * 96 * 4);
    float* x2     = (float*)alloc((size_t)NQ * 64 * 4);
    float* x3     = (float*)alloc((size_t)NQ * 64 * 4);
    float* B1     = (float*)alloc((size_t)K1 * 64 * 4);
    float* B2     = (float*)alloc((size_t)K2 * 64 * 4);
    float* W3p    = (float*)alloc((size_t)64 * 195 * 4);
    float* P      = (float*)alloc((size_t)KC * NQ * 64 * 4);
    // P region time-shared: {Pco,Pcf} (layer 0) -> P (layers 1/2) -> Y (layer 3)
    float* Pco    = P;
    float* Pcf    = P + (size_t)KCS * NQ * 32;
    float* Y      = P;

    dim3 b256(256);
    prep_kernel<<<512, b256, 0, stream>>>(c1_w, d1_w, c2_w, d2_w, c3_w, d3_w,
                                          vel, d0_w, d0_b, B1, B2, W3p, ff, x1);
    nn2_kernel<<<2*NQ/4, b256, 0, stream>>>(pos, box, f_cnt, f_idx, f_d2,
                                            b_cnt, b_idx, b_d2);
    coef2_kernel<<<(2*NQ*K + 255)/256, b256, 0, stream>>>(
        pos, box, f_cnt, f_idx, f_cell, f_coef, b_cnt, b_idx, b_cell, b_coef);
    // ---- layer 0 ----
    scatter_small_kernel<4><<<(NQ+3)/4, b256, 0, stream>>>(ff, f_cnt, f_idx,
        f_cell, f_coef, S_cf, NQ);
    scatter_small_kernel<3><<<(NQ+3)/4, b256, 0, stream>>>(box_feats, b_cnt, b_idx,
        b_cell, b_coef, S_co, NQ);
    gemm_kernel<32><<<dim3((NQ+127)/128, KCS), b256, 0, stream>>>(S_co, 192, co_w, Pco, NQ);
    gemm_kernel<32><<<dim3((NQ+127)/128, KCS), b256, 0, stream>>>(S_cf, 256, cf_w, Pcf, NQ);
    e0_kernel<<<(NQ*64 + 255)/256, b256, 0, stream>>>(Pco, Pcf, KCS, co_b, cf_b, x1);
    // ---- layer 1: x2 = cconv(relu(x1)) + relu(x1)@d1 + biases ----
    scatter_kernel<96,1,1><<<NQ, b256, 0, stream>>>(x1, f_cnt, f_idx, f_cell, f_coef, SB);
    gemm64_kernel<<<dim3((NQ+127)/128, KC), b256, 0, stream>>>(SB, K1, B1, P, NQ);
    e_kernel<<<(NQ*64 + 255)/256, b256, 0, stream>>>(P, KC, c1_b, d1_b, nullptr, x2);
    // ---- layer 2: x3 = [cconv(relu(x2)) + relu(x2)@d2 + biases] + x2 ----
    scatter_kernel<64,1,1><<<NQ, b256, 0, stream>>>(x2, f_cnt, f_idx, f_cell, f_coef, SB);
    gemm64_kernel<<<dim3((NQ+127)/128, KC), b256, 0, stream>>>(SB, K2, B2, P, NQ);
    e_kernel<<<(NQ*64 + 255)/256, b256, 0, stream>>>(P, KC, c2_b, d2_b, x2, x3);
    // ---- layer 3 (O=3): transform Y = relu(x3)*[c3;d3], then gather ----
    y3t_kernel<<<NQ, b256, 0, stream>>>(x3, W3p, Y);
    gather3_kernel<<<(NQ+3)/4, b256, 0, stream>>>(f_cnt, f_idx, f_cell, f_coef,
        Y, c3_b, d3_b, (float*)d_out);

    (void)in_sizes; (void)n_in; (void)out_size; (void)ws_size;
}

// Round 6
// 474.201 us; speedup vs baseline: 4.9192x; 1.0649x over previous
//
#include <hip/hip_runtime.h>
#include <math.h>

namespace {

constexpr int NQ  = 6000;   // fluid particles (queries)
constexpr int NB  = 3000;   // box particles
constexpr int K   = 80;     // neighbor cap
constexpr float RAD = 0.1125f;
constexpr float R2  = RAD * RAD;
constexpr float EPSF = 1e-12f;

constexpr int K1  = 64*96 + 96;  // 6240
constexpr int K2  = 64*64 + 64;  // 4160
constexpr int KC  = 26;          // split-K chunks, big GEMMs (390=26*15, 260=26*10)
constexpr int KCS = 4;           // split-K chunks, layer-0 GEMMs

__device__ __forceinline__ float sgn(float x) {
    return (x > 0.f) ? 1.f : ((x < 0.f) ? -1.f : 0.f);
}

__device__ __forceinline__ unsigned int bf16rne(float f) {
    unsigned int u = __float_as_uint(f);
    return (u + 0x7fffu + ((u >> 16) & 1u)) >> 16;   // round-to-nearest-even
}

// ---------------- neighbor search: one wave (64 lanes) per query -------------
__device__ void nn_search(const float* __restrict__ qpos, int wid,
                          const float* __restrict__ ipos, int ni, int self_ig,
                          int* __restrict__ cnt, int* __restrict__ idxs,
                          float* __restrict__ d2s, int lane)
{
    float qx = qpos[wid*3+0], qy = qpos[wid*3+1], qz = qpos[wid*3+2];
    int base = wid * K;
    int c = 0;
    for (int j0 = 0; j0 < ni; j0 += 64) {
        int j = j0 + lane;
        float d2 = 1e30f;
        if (j < ni) {
            float dx = ipos[j*3+0]-qx, dy = ipos[j*3+1]-qy, dz = ipos[j*3+2]-qz;
            d2 = dx*dx + dy*dy + dz*dz;
            if (self_ig && j == wid) d2 = 1e30f;
        }
        bool hit = d2 <= R2;
        unsigned long long m = __ballot(hit);
        int pc = __popcll(m);
        if (pc == 0) continue;
        if (c + pc <= K) {
            if (hit) {
                int pos = c + __popcll(m & ((1ull << lane) - 1ull));
                idxs[base + pos] = j;
                d2s [base + pos] = d2;
            }
            c += pc;
        } else {
            // rare overflow path: keep the K nearest (top_k semantics)
            while (m) {
                int l = __ffsll((unsigned long long)m) - 1;
                m &= m - 1ull;
                float dd = __shfl(d2, l);
                int jj = j0 + l;
                if (c < K) {
                    idxs[base + c] = jj;
                    d2s [base + c] = dd;
                    c++;
                } else {
                    float mx = -1.f; int am = 0;
                    for (int s = 0; s < K; ++s) {
                        float v = d2s[base + s];
                        if (v > mx) { mx = v; am = s; }
                    }
                    if (dd < mx) {
                        idxs[base + am] = jj;
                        d2s [base + am] = dd;
                    }
                }
            }
        }
    }
    if (lane == 0) cnt[wid] = c;
}

// merged: waves [0,NQ) = fluid self-search, [NQ,2NQ) = box search
__global__ __launch_bounds__(256) void nn2_kernel(
    const float* __restrict__ pos, const float* __restrict__ box,
    int* __restrict__ f_cnt, int* __restrict__ f_idx, float* __restrict__ f_d2,
    int* __restrict__ b_cnt, int* __restrict__ b_idx, float* __restrict__ b_d2)
{
    int gw = (blockIdx.x * blockDim.x + threadIdx.x) >> 6;
    int lane = threadIdx.x & 63;
    if (gw < NQ)
        nn_search(pos, gw, pos, NQ, 1, f_cnt, f_idx, f_d2, lane);
    else
        nn_search(pos, gw - NQ, box, NB, 0, b_cnt, b_idx, b_d2, lane);
}

// ------------- per-neighbor geometry: ball->cube + trilinear coefs -----------
__device__ void coef_one(const float* __restrict__ qpos, const float* __restrict__ ipos,
                         const int* __restrict__ cnt, const int* __restrict__ idxs,
                         int* __restrict__ cells, float* __restrict__ coefs,
                         int q, int k)
{
    if (k >= cnt[q]) return;
    int j = idxs[q*K + k];
    float rx = (ipos[j*3+0] - qpos[q*3+0]) / RAD;
    float ry = (ipos[j*3+1] - qpos[q*3+1]) / RAD;
    float rz = (ipos[j*3+2] - qpos[q*3+2]) / RAD;
    float r2 = rx*rx + ry*ry + rz*rz;
    float w1 = 1.f - r2;
    float win = (w1 > 0.f) ? w1*w1*w1 : 0.f;   // clip((1-r2)^3, 0, 1)
    float norm = sqrtf(r2);
    float rxy2 = rx*rx + ry*ry;
    float xc, yc, zc;
    if (r2 < 1e-12f) {
        xc = yc = zc = 0.f;
    } else if (1.25f * rz * rz > rxy2) {
        float s = sqrtf(3.0f * norm / (norm + fabsf(rz) + EPSF));
        xc = s * rx; yc = s * ry; zc = sgn(rz) * norm;
    } else {
        float s = norm / sqrtf(rxy2 + EPSF);
        xc = s * rx; yc = s * ry; zc = 1.5f * rz * s;
    }
    float rxy = sqrtf(xc*xc + yc*yc);
    const float FP = (float)(4.0 / M_PI);
    float u, v;
    if (rxy < EPSF) {
        u = 0.f; v = 0.f;
    } else if (fabsf(xc) >= fabsf(yc)) {
        float sx = (fabsf(xc) < EPSF) ? EPSF : xc;
        u = sgn(xc) * rxy;
        v = u * FP * atanf(yc / sx);
    } else {
        float sy = (fabsf(yc) < EPSF) ? EPSF : yc;
        v = sgn(yc) * rxy;
        u = v * FP * atanf(xc / sy);
    }
    float gx = fminf(fmaxf((u  + 1.f) * 0.5f * 3.f, 0.f), 3.f);
    float gy = fminf(fmaxf((v  + 1.f) * 0.5f * 3.f, 0.f), 3.f);
    float gz = fminf(fmaxf((zc + 1.f) * 0.5f * 3.f, 0.f), 3.f);
    int ix = min((int)floorf(gx), 2);
    int iy = min((int)floorf(gy), 2);
    int iz = min((int)floorf(gz), 2);
    float tx = gx - (float)ix, ty = gy - (float)iy, tz = gz - (float)iz;
    cells[q*K + k] = iz*16 + iy*4 + ix;
    float wx[2] = {1.f - tx, tx}, wy[2] = {1.f - ty, ty}, wz[2] = {1.f - tz, tz};
    float* cf = coefs + (size_t)(q*K + k) * 8;
#pragma unroll
    for (int c = 0; c < 8; ++c)   // c = dx*4 + dy*2 + dz (python loop order)
        cf[c] = wx[c >> 2] * wy[(c >> 1) & 1] * wz[c & 1] * win;
}

__global__ __launch_bounds__(256) void coef2_kernel(
    const float* __restrict__ pos, const float* __restrict__ box,
    const int* __restrict__ f_cnt, const int* __restrict__ f_idx,
    int* __restrict__ f_cell, float* __restrict__ f_coef,
    const int* __restrict__ b_cnt, const int* __restrict__ b_idx,
    int* __restrict__ b_cell, float* __restrict__ b_coef)
{
    int t = blockIdx.x * blockDim.x + threadIdx.x;
    if (t < NQ * K)
        coef_one(pos, pos, f_cnt, f_idx, f_cell, f_coef, t / K, t % K);
    else if (t < 2 * NQ * K) {
        int t2 = t - NQ * K;
        coef_one(pos, box, b_cnt, b_idx, b_cell, b_coef, t2 / K, t2 % K);
    }
}

// -------- big scatter (F in {64,96}): build S[n, 64F(+F)] rows (bf16 out) ----
// Wave w owns z-slab w (cells 16w..16w+15): plain LDS RMW, no atomics.
// Activity via ballot masks; cb/j via __shfl; coefs staged in LDS; 1-deep
// pipeline prefetches next active neighbor's feature row. S is written to
// global as bf16 (halves WRITE traffic; fp32 accumulate stays in LDS).
template<int F, int RELU, int EXT>
__global__ __launch_bounds__(256) void scatter_kernel(
    const float* __restrict__ feats,
    const int* __restrict__ cnt, const int* __restrict__ nidx,
    const int* __restrict__ ncell, const float* __restrict__ ncoef,
    unsigned short* __restrict__ Sg)
{
    constexpr int KT = 64 * F + (EXT ? F : 0);   // ushorts per row
    __shared__ __align__(16) float S[64 * F];
    __shared__ __align__(16) float coefL[K * 8];
    int n = blockIdx.x;
    int tid = threadIdx.x, lane = tid & 63, w = tid >> 6;
    int cn = cnt[n];
    {
        const float4* src = (const float4*)(ncoef + (size_t)n * K * 8);
        for (int i = tid; i < cn * 2; i += 256) ((float4*)coefL)[i] = src[i];
    }
    float* Sw = S + w * 16 * F;
    for (int i = lane; i < 16 * F; i += 64) Sw[i] = 0.f;
    int kk2 = 64 + lane;
    int cb1 = (lane < cn) ? ncell[n*K + lane] : 0;
    int j1  = (lane < cn) ? nidx [n*K + lane] : 0;
    int cb2 = (kk2 < cn) ? ncell[n*K + kk2] : 0;
    int j2  = (kk2 < cn) ? nidx [n*K + kk2] : 0;
    int dzl1 = w - (cb1 >> 4);
    int dzl2 = w - (cb2 >> 4);
    bool a1 = (lane < cn) && ((unsigned)dzl1 <= 1u);
    bool a2 = (kk2 < cn) && ((unsigned)dzl2 <= 1u);
    unsigned long long act0 = __ballot(a1), act1 = __ballot(a2);
    unsigned long long dzm0 = __ballot(dzl1 == 1), dzm1 = __ballot(dzl2 == 1);
    __syncthreads();   // coefL ready

#define POP(K_, DZ_, J_, CB_) do { \
    if (act0) { int b_ = __builtin_ctzll(act0); act0 &= act0 - 1ull; \
        K_ = b_; DZ_ = (int)((dzm0 >> b_) & 1ull); \
        J_ = __shfl(j1, b_); CB_ = __shfl(cb1, b_); } \
    else if (act1) { int b_ = __builtin_ctzll(act1); act1 &= act1 - 1ull; \
        K_ = 64 + b_; DZ_ = (int)((dzm1 >> b_) & 1ull); \
        J_ = __shfl(j2, b_); CB_ = __shfl(cb2, b_); } \
    else K_ = -1; } while (0)

    int k = -1, dz = 0, j = 0, cb = 0;
    POP(k, dz, j, cb);
    float v0 = 0.f, v1 = 0.f;
    if (k >= 0) {
        v0 = feats[(size_t)j * F + lane];
        if (RELU) v0 = fmaxf(v0, 0.f);
        if (F > 64 && lane < F - 64) {
            v1 = feats[(size_t)j * F + 64 + lane];
            if (RELU) v1 = fmaxf(v1, 0.f);
        }
    }
    while (k >= 0) {
        int kN = -1, dzN = 0, jN = 0, cbN = 0;
        POP(kN, dzN, jN, cbN);
        float n0 = 0.f, n1 = 0.f;
        if (kN >= 0) {                       // prefetch next row (overlaps RMW)
            n0 = feats[(size_t)jN * F + lane];
            if (RELU) n0 = fmaxf(n0, 0.f);
            if (F > 64 && lane < F - 64) {
                n1 = feats[(size_t)jN * F + 64 + lane];
                if (RELU) n1 = fmaxf(n1, 0.f);
            }
        }
        float4 cA = ((const float4*)coefL)[k*2];      // c = 0..3  (dx=0)
        float4 cB = ((const float4*)coefL)[k*2 + 1];  // c = 4..7  (dx=1)
        int base = cb + dz * 16;
        float w00 = dz ? cA.y : cA.x;   // (dx0,dy0)
        float w01 = dz ? cA.w : cA.z;   // (dx0,dy1)
        float w10 = dz ? cB.y : cB.x;   // (dx1,dy0)
        float w11 = dz ? cB.w : cB.z;   // (dx1,dy1)
        int c00 = base, c01 = base + 4, c10 = base + 1, c11 = base + 5;
        S[c00*F + lane] += w00 * v0;
        S[c01*F + lane] += w01 * v0;
        S[c10*F + lane] += w10 * v0;
        S[c11*F + lane] += w11 * v0;
        if (F > 64 && lane < F - 64) {
            S[c00*F + 64 + lane] += w00 * v1;
            S[c01*F + 64 + lane] += w01 * v1;
            S[c10*F + 64 + lane] += w10 * v1;
            S[c11*F + 64 + lane] += w11 * v1;
        }
        k = kN; dz = dzN; cb = cbN; v0 = n0; v1 = n1;
    }
#undef POP
    __syncthreads();
    unsigned short* row = Sg + (size_t)n * KT;
    for (int i = tid; i < 64 * F / 8; i += 256) {
        const float* s8 = S + i * 8;
        uint4 o;
        o.x = bf16rne(s8[0]) | (bf16rne(s8[1]) << 16);
        o.y = bf16rne(s8[2]) | (bf16rne(s8[3]) << 16);
        o.z = bf16rne(s8[4]) | (bf16rne(s8[5]) << 16);
        o.w = bf16rne(s8[6]) | (bf16rne(s8[7]) << 16);
        reinterpret_cast<uint4*>(row)[i] = o;
    }
    if (EXT) {
        for (int f = tid; f < F; f += 256) {
            float v = feats[(size_t)n * F + f];
            if (RELU) v = fmaxf(v, 0.f);
            row[64 * F + f] = (unsigned short)bf16rne(v);
        }
    }
}

// ------- small scatter (F in {3,4}): one WAVE per point, lane=(corner,feat) --
template<int F>
__global__ __launch_bounds__(256) void scatter_small_kernel(
    const float* __restrict__ feats,
    const int* __restrict__ cnt, const int* __restrict__ nidx,
    const int* __restrict__ ncell, const float* __restrict__ ncoef,
    float* __restrict__ Sg, int nq)
{
    __shared__ __align__(16) float S4[4][64 * F];
    int tid = threadIdx.x, lane = tid & 63, w = tid >> 6;
    int n = blockIdx.x * 4 + w;
    if (n >= nq) return;
    float* Sw = S4[w];
    for (int i = lane; i < 64 * F; i += 64) Sw[i] = 0.f;
    int cn = cnt[n];
    int kk2 = 64 + lane;
    int cb1 = (lane < cn) ? ncell[n*K + lane] : 0;
    int j1  = (lane < cn) ? nidx [n*K + lane] : 0;
    int cb2 = (kk2 < cn) ? ncell[n*K + kk2] : 0;
    int j2  = (kk2 < cn) ? nidx [n*K + kk2] : 0;
    int c = lane & 7, f = lane >> 3;
    bool fok = f < F;
    const float* coefG = ncoef + (size_t)n * K * 8;

    float wgt = 0.f, v = 0.f; int cb = 0;
    if (cn > 0) {
        int j = __shfl(j1, 0); cb = __shfl(cb1, 0);
        if (fok) { wgt = coefG[c]; v = feats[(size_t)j * F + f]; }
    }
    for (int kk = 0; kk < cn; ++kk) {
        float wn = 0.f, vn = 0.f; int cbn = 0;
        int k1n = kk + 1;
        if (k1n < cn) {
            int jn = (k1n < 64) ? __shfl(j1, k1n) : __shfl(j2, k1n - 64);
            cbn    = (k1n < 64) ? __shfl(cb1, k1n) : __shfl(cb2, k1n - 64);
            if (fok) { wn = coefG[k1n*8 + c]; vn = feats[(size_t)jn * F + f]; }
        }
        if (fok) {
            int cell = cb + (c & 1)*16 + ((c >> 1) & 1)*4 + (c >> 2);
            Sw[cell*F + f] += wgt * v;
        }
        wgt = wn; v = vn; cb = cbn;
    }
    float* row = Sg + (size_t)n * (64 * F);
    for (int i = lane; i < 16 * F; i += 64)
        ((float4*)row)[i] = ((const float4*)Sw)[i];
}

// ----------------- layer-0 GEMM (4x4 blocking, fp32 A), split-K --------------
template<int O>
__global__ __launch_bounds__(256) void gemm_kernel(
    const float* __restrict__ A, int Kdim,
    const float* __restrict__ B,
    float* __restrict__ P, int M)
{
    constexpr int TX   = O / 4;
    constexpr int TY   = 256 / TX;
    constexpr int MT   = TY * 4;
    constexpr int ASTR = MT + 4;
    __shared__ float As[16][ASTR];
    __shared__ float Bs[16 * O];
    int tid = threadIdx.x;
    int tx = tid % TX, ty = tid / TX;
    int m0 = blockIdx.x * MT;
    int ntiles = Kdim >> 4;
    float acc[4][4] = {};
    for (int t = blockIdx.y; t < ntiles; t += gridDim.y) {
        int k0 = t << 4;
        __syncthreads();
#pragma unroll
        for (int l = 0; l < MT / 64; ++l) {
            int idx = tid + l * 256;
            int mm = idx >> 2, k4 = idx & 3;
            int gm = m0 + mm; if (gm >= M) gm = M - 1;
            float4 av = *reinterpret_cast<const float4*>(A + (size_t)gm * Kdim + k0 + k4 * 4);
            As[k4*4+0][mm] = av.x; As[k4*4+1][mm] = av.y;
            As[k4*4+2][mm] = av.z; As[k4*4+3][mm] = av.w;
        }
        constexpr int NB4 = 16 * O / 4;
        if (NB4 == 256 || tid < NB4)
            *reinterpret_cast<float4*>(&Bs[tid*4]) =
                *reinterpret_cast<const float4*>(B + (size_t)k0 * O + tid * 4);
        __syncthreads();
#pragma unroll
        for (int kk = 0; kk < 16; ++kk) {
            float4 av = *reinterpret_cast<const float4*>(&As[kk][ty*4]);
            float4 bv = *reinterpret_cast<const float4*>(&Bs[kk*O + tx*4]);
            float aa[4] = {av.x, av.y, av.z, av.w};
            float bb[4] = {bv.x, bv.y, bv.z, bv.w};
#pragma unroll
            for (int i = 0; i < 4; ++i)
#pragma unroll
                for (int jj = 0; jj < 4; ++jj)
                    acc[i][jj] += aa[i] * bb[jj];
        }
    }
    float* Pb = P + (size_t)blockIdx.y * M * O;
#pragma unroll
    for (int i = 0; i < 4; ++i) {
        int gm = m0 + ty*4 + i;
        if (gm < M)
#pragma unroll
            for (int jj = 0; jj < 4; ++jj)
                Pb[(size_t)gm * O + tx*4 + jj] = acc[i][jj];
    }
}

// ------ O=64 GEMM, bf16 A: 128x64 tile, 8x4/thread, reg double-buffer --------
__global__ __launch_bounds__(256) void gemm64b_kernel(
    const unsigned short* __restrict__ A, int Kdim,   // bf16 [M,Kdim]
    const float* __restrict__ B,
    float* __restrict__ P, int M)
{
    constexpr int MT = 128, ASTR = 132;
    __shared__ float As[16 * ASTR];          // k-major, fp32 (converted at stage)
    __shared__ float Bs[16 * 64];
    int tid = threadIdx.x;
    int tx = tid & 15, ty = tid >> 4;
    int m0 = blockIdx.x * MT;
    int ntiles = Kdim >> 4;
    int mm = tid >> 1, half = tid & 1;       // staging map: thread -> (row, k-half)
    int gms = m0 + mm; if (gms >= M) gms = M - 1;
    const unsigned short* Arow = A + (size_t)gms * Kdim + half * 8;
    float acc[8][4] = {};
    int t = blockIdx.y;
    uint4 av = {0,0,0,0}; float4 bv = {0.f,0.f,0.f,0.f};
    if (t < ntiles) {
        av = *reinterpret_cast<const uint4*>(Arow + (t << 4));
        bv = *reinterpret_cast<const float4*>(B + (size_t)(t << 4) * 64 + tid * 4);
    }
    for (; t < ntiles; t += gridDim.y) {
        int r0 = half * 8;
        As[(r0+0)*ASTR + mm] = __uint_as_float(av.x << 16);
        As[(r0+1)*ASTR + mm] = __uint_as_float(av.x & 0xffff0000u);
        As[(r0+2)*ASTR + mm] = __uint_as_float(av.y << 16);
        As[(r0+3)*ASTR + mm] = __uint_as_float(av.y & 0xffff0000u);
        As[(r0+4)*ASTR + mm] = __uint_as_float(av.z << 16);
        As[(r0+5)*ASTR + mm] = __uint_as_float(av.z & 0xffff0000u);
        As[(r0+6)*ASTR + mm] = __uint_as_float(av.w << 16);
        As[(r0+7)*ASTR + mm] = __uint_as_float(av.w & 0xffff0000u);
        *reinterpret_cast<float4*>(&Bs[tid*4]) = bv;
        __syncthreads();
        int tn = t + gridDim.y;
        if (tn < ntiles) {                   // prefetch next tile (overlaps FMA)
            av = *reinterpret_cast<const uint4*>(Arow + (tn << 4));
            bv = *reinterpret_cast<const float4*>(B + (size_t)(tn << 4) * 64 + tid * 4);
        }
#pragma unroll
        for (int kk = 0; kk < 16; ++kk) {
            float4 a0 = *reinterpret_cast<const float4*>(&As[kk*ASTR + ty*8]);
            float4 a1 = *reinterpret_cast<const float4*>(&As[kk*ASTR + ty*8 + 4]);
            float4 b4 = *reinterpret_cast<const float4*>(&Bs[kk*64 + tx*4]);
            float aa[8] = {a0.x,a0.y,a0.z,a0.w,a1.x,a1.y,a1.z,a1.w};
            float bb[4] = {b4.x,b4.y,b4.z,b4.w};
#pragma unroll
            for (int i = 0; i < 8; ++i)
#pragma unroll
                for (int jj = 0; jj < 4; ++jj)
                    acc[i][jj] += aa[i] * bb[jj];
        }
        __syncthreads();
    }
    float* Pb = P + (size_t)blockIdx.y * M * 64;
#pragma unroll
    for (int i = 0; i < 8; ++i) {
        int gm = m0 + ty*8 + i;
        if (gm < M) {
            float4 o = {acc[i][0], acc[i][1], acc[i][2], acc[i][3]};
            *reinterpret_cast<float4*>(&Pb[(size_t)gm * 64 + tx*4]) = o;
        }
    }
}

// ----------- prep: B1=[c1;d1], B2=[c2;d2], W3p, ff, dense-0 into x1 ----------
__global__ __launch_bounds__(256) void prep_kernel(
    const float* __restrict__ c1w, const float* __restrict__ d1w,
    const float* __restrict__ c2w, const float* __restrict__ d2w,
    const float* __restrict__ c3w, const float* __restrict__ d3w,
    const float* __restrict__ vel,
    const float* __restrict__ d0w, const float* __restrict__ d0b,
    float* __restrict__ B1, float* __restrict__ B2, float* __restrict__ W3p,
    float* __restrict__ ff, float* __restrict__ x1)
{
    int stride = gridDim.x * blockDim.x;
    int gid = blockIdx.x * blockDim.x + threadIdx.x;
    for (int i = gid; i < 64*96*64 + 96*64; i += stride)
        B1[i] = (i < 64*96*64) ? c1w[i] : d1w[i - 64*96*64];
    for (int i = gid; i < 64*64*64 + 64*64; i += stride)
        B2[i] = (i < 64*64*64) ? c2w[i] : d2w[i - 64*64*64];
    for (int i = gid; i < 64 * 195; i += stride) {   // W3p[f][c*3+o]
        int f = i / 195, r = i % 195, c = r / 3, o = r % 3;
        W3p[i] = (c < 64) ? c3w[(c*64 + f)*3 + o] : d3w[f*3 + o];
    }
    for (int i = gid; i < NQ; i += stride) {
        ff[i*4+0] = 1.f;
        ff[i*4+1] = vel[i*3+0];
        ff[i*4+2] = vel[i*3+1];
        ff[i*4+3] = vel[i*3+2];
    }
    for (int i = gid; i < NQ * 32; i += stride) {    // dense-0 skip -> x1[:,64:96]
        int n = i >> 5, o = i & 31;
        float acc = d0b[o] + d0w[o]
                  + vel[n*3+0] * d0w[32 + o]
                  + vel[n*3+1] * d0w[64 + o]
                  + vel[n*3+2] * d0w[96 + o];
        x1[n*96 + 64 + o] = acc;
    }
}

// epilogue for layer 0: x1[:,0:32] = sum(Pco)+co_b ; x1[:,32:64] = sum(Pcf)+cf_b
__global__ __launch_bounds__(256) void e0_kernel(
    const float* __restrict__ Pco, const float* __restrict__ Pcf, int kc,
    const float* __restrict__ cob, const float* __restrict__ cfb,
    float* __restrict__ x1)
{
    int t = blockIdx.x * blockDim.x + threadIdx.x;
    if (t >= NQ * 64) return;
    int n = t >> 6, c = t & 63;
    float v;
    if (c < 32) {
        v = cob[c];
        for (int ky = 0; ky < kc; ++ky) v += Pco[(size_t)ky * NQ * 32 + n*32 + c];
    } else {
        int cc = c - 32;
        v = cfb[cc];
        for (int ky = 0; ky < kc; ++ky) v += Pcf[(size_t)ky * NQ * 32 + n*32 + cc];
    }
    x1[n*96 + c] = v;
}

// epilogue for layers 1/2: xo = sum_ky(P) + cb + db (+ resid)
__global__ __launch_bounds__(256) void e_kernel(
    const float* __restrict__ P, int kc,
    const float* __restrict__ cb, const float* __restrict__ db,
    const float* __restrict__ resid, float* __restrict__ xo)
{
    int t = blockIdx.x * blockDim.x + threadIdx.x;
    if (t >= NQ * 64) return;
    int o = t & 63;
    float v = cb[o] + db[o];
    for (int ky = 0; ky < kc; ++ky) v += P[(size_t)ky * NQ * 64 + t];
    if (resid) v += resid[t];
    xo[t] = v;
}

// ---- final layer via transform+gather: Y[j, c<=64, 3] = relu(x3[j])*W3' -----
__global__ __launch_bounds__(256) void y3t_kernel(
    const float* __restrict__ x3, const float* __restrict__ W3p,
    float* __restrict__ Y)
{
    __shared__ float xr[64];
    int n = blockIdx.x, tid = threadIdx.x;
    if (tid < 64) xr[tid] = fmaxf(x3[n*64 + tid], 0.f);
    __syncthreads();
    if (tid < 195) {
        float acc = 0.f;
#pragma unroll 8
        for (int f = 0; f < 64; ++f) acc += xr[f] * W3p[f*195 + tid];
        Y[(size_t)n * 195 + tid] = acc;
    }
}

__global__ __launch_bounds__(256) void gather3_kernel(
    const int* __restrict__ cnt, const int* __restrict__ nidx,
    const int* __restrict__ ncell, const float* __restrict__ ncoef,
    const float* __restrict__ Y,
    const float* __restrict__ cb3, const float* __restrict__ db3,
    float* __restrict__ out)
{
    int gw = (blockIdx.x * blockDim.x + threadIdx.x) >> 6;
    int lane = threadIdx.x & 63;
    if (gw >= NQ) return;
    int n = gw;
    int cn = cnt[n];
    float a0 = 0.f, a1 = 0.f, a2 = 0.f;
#pragma unroll
    for (int seg = 0; seg < 2; ++seg) {
        int kidx = seg * 64 + lane;
        if (kidx < cn) {
            int j  = nidx [n*K + kidx];
            int cb = ncell[n*K + kidx];
            const float* cf = ncoef + (size_t)(n*K + kidx) * 8;
            const float* Yj = Y + (size_t)j * 195;
#pragma unroll
            for (int c = 0; c < 8; ++c) {
                int cell = cb + (c & 1)*16 + ((c >> 1) & 1)*4 + (c >> 2);
                float wgt = cf[c];
                const float* Tp = Yj + cell*3;
                a0 += wgt * Tp[0];
                a1 += wgt * Tp[1];
                a2 += wgt * Tp[2];
            }
        }
    }
#pragma unroll
    for (int s = 32; s > 0; s >>= 1) {
        a0 += __shfl_down(a0, s);
        a1 += __shfl_down(a1, s);
        a2 += __shfl_down(a2, s);
    }
    if (lane == 0) {
        const float* Yn = Y + (size_t)n * 195 + 192;   // dense skip (c=64)
        out[n*3+0] = (a0 + Yn[0] + cb3[0] + db3[0]) * (1.f/128.f);
        out[n*3+1] = (a1 + Yn[1] + cb3[1] + db3[1]) * (1.f/128.f);
        out[n*3+2] = (a2 + Yn[2] + cb3[2] + db3[2]) * (1.f/128.f);
    }
}

} // namespace

extern "C" void kernel_launch(void* const* d_in, const int* in_sizes, int n_in,
                              void* d_out, int out_size, void* d_ws, size_t ws_size,
                              hipStream_t stream)
{
    const float* pos       = (const float*)d_in[0];
    const float* vel       = (const float*)d_in[1];
    const float* box       = (const float*)d_in[2];
    const float* box_feats = (const float*)d_in[3];
    const float* cf_w = (const float*)d_in[4];  const float* cf_b = (const float*)d_in[5];
    const float* co_w = (const float*)d_in[6];  const float* co_b = (const float*)d_in[7];
    const float* d0_w = (const float*)d_in[8];  const float* d0_b = (const float*)d_in[9];
    const float* c1_w = (const float*)d_in[10]; const float* c1_b = (const float*)d_in[11];
    const float* d1_w = (const float*)d_in[12]; const float* d1_b = (const float*)d_in[13];
    const float* c2_w = (const float*)d_in[14]; const float* c2_b = (const float*)d_in[15];
    const float* d2_w = (const float*)d_in[16]; const float* d2_b = (const float*)d_in[17];
    const float* c3_w = (const float*)d_in[18]; const float* c3_b = (const float*)d_in[19];
    const float* d3_w = (const float*)d_in[20]; const float* d3_b = (const float*)d_in[21];

    char* wsb = (char*)d_ws;
    size_t off = 0;
    auto alloc = [&](size_t bytes) {
        void* p = wsb + off;
        off = (off + bytes + 255) & ~(size_t)255;
        return p;
    };
    // SB region time-shared: {f_d2,b_d2} during nn -> {S_cf,S_co} (fp32, layer 0)
    // -> bf16 S rows for layers 1/2.
    char*  SBraw = (char*)alloc((size_t)NQ * K1 * 4);
    unsigned short* SB = (unsigned short*)SBraw;
    float* f_d2 = (float*)SBraw;
    float* b_d2 = (float*)SBraw + (size_t)NQ * K;
    float* S_cf = (float*)SBraw;                      // [NQ,256] fp32
    float* S_co = (float*)SBraw + (size_t)NQ * 256;   // [NQ,192] fp32
    int*   f_cnt  = (int*)  alloc((size_t)NQ * 4);
    int*   f_idx  = (int*)  alloc((size_t)NQ * K * 4);
    int*   f_cell = (int*)  alloc((size_t)NQ * K * 4);
    float* f_coef = (float*)alloc((size_t)NQ * K * 8 * 4);
    int*   b_cnt  = (int*)  alloc((size_t)NQ * 4);
    int*   b_idx  = (int*)  alloc((size_t)NQ * K * 4);
    int*   b_cell = (int*)  alloc((size_t)NQ * K * 4);
    float* b_coef = (float*)alloc((size_t)NQ * K * 8 * 4);
    float* ff     = (float*)alloc((size_t)NQ * 4 * 4);
    float* x1     = (float*)alloc((size_t)NQ * 96 * 4);
    float* x2     = (float*)alloc((size_t)NQ * 64 * 4);
    float* x3     = (float*)alloc((size_t)NQ * 64 * 4);
    float* B1     = (float*)alloc((size_t)K1 * 64 * 4);
    float* B2     = (float*)alloc((size_t)K2 * 64 * 4);
    float* W3p    = (float*)alloc((size_t)64 * 195 * 4);
    float* P      = (float*)alloc((size_t)KC * NQ * 64 * 4);   // 40 MB
    // P region time-shared: {Pco,Pcf} (layer 0) -> P (layers 1/2) -> Y (layer 3)
    float* Pco    = P;
    float* Pcf    = P + (size_t)KCS * NQ * 32;
    float* Y      = P;

    dim3 b256(256);
    prep_kernel<<<512, b256, 0, stream>>>(c1_w, d1_w, c2_w, d2_w, c3_w, d3_w,
                                          vel, d0_w, d0_b, B1, B2, W3p, ff, x1);
    nn2_kernel<<<2*NQ/4, b256, 0, stream>>>(pos, box, f_cnt, f_idx, f_d2,
                                            b_cnt, b_idx, b_d2);
    coef2_kernel<<<(2*NQ*K + 255)/256, b256, 0, stream>>>(
        pos, box, f_cnt, f_idx, f_cell, f_coef, b_cnt, b_idx, b_cell, b_coef);
    // ---- layer 0 ----
    scatter_small_kernel<4><<<(NQ+3)/4, b256, 0, stream>>>(ff, f_cnt, f_idx,
        f_cell, f_coef, S_cf, NQ);
    scatter_small_kernel<3><<<(NQ+3)/4, b256, 0, stream>>>(box_feats, b_cnt, b_idx,
        b_cell, b_coef, S_co, NQ);
    gemm_kernel<32><<<dim3((NQ+127)/128, KCS), b256, 0, stream>>>(S_co, 192, co_w, Pco, NQ);
    gemm_kernel<32><<<dim3((NQ+127)/128, KCS), b256, 0, stream>>>(S_cf, 256, cf_w, Pcf, NQ);
    e0_kernel<<<(NQ*64 + 255)/256, b256, 0, stream>>>(Pco, Pcf, KCS, co_b, cf_b, x1);
    // ---- layer 1: x2 = cconv(relu(x1)) + relu(x1)@d1 + biases ----
    scatter_kernel<96,1,1><<<NQ, b256, 0, stream>>>(x1, f_cnt, f_idx, f_cell, f_coef, SB);
    gemm64b_kernel<<<dim3((NQ+127)/128, KC), b256, 0, stream>>>(SB, K1, B1, P, NQ);
    e_kernel<<<(NQ*64 + 255)/256, b256, 0, stream>>>(P, KC, c1_b, d1_b, nullptr, x2);
    // ---- layer 2: x3 = [cconv(relu(x2)) + relu(x2)@d2 + biases] + x2 ----
    scatter_kernel<64,1,1><<<NQ, b256, 0, stream>>>(x2, f_cnt, f_idx, f_cell, f_coef, SB);
    gemm64b_kernel<<<dim3((NQ+127)/128, KC), b256, 0, stream>>>(SB, K2, B2, P, NQ);
    e_kernel<<<(NQ*64 + 255)/256, b256, 0, stream>>>(P, KC, c2_b, d2_b, x2, x3);
    // ---- layer 3 (O=3): transform Y = relu(x3)*[c3;d3], then gather ----
    y3t_kernel<<<NQ, b256, 0, stream>>>(x3, W3p, Y);
    gather3_kernel<<<(NQ+3)/4, b256, 0, stream>>>(f_cnt, f_idx, f_cell, f_coef,
        Y, c3_b, d3_b, (float*)d_out);

    (void)in_sizes; (void)n_in; (void)out_size; (void)ws_size;
}

// Round 7
// 427.399 us; speedup vs baseline: 5.4579x; 1.1095x over previous
//
#include <hip/hip_runtime.h>
#include <math.h>

namespace {

constexpr int NQ  = 6000;   // fluid particles (queries)
constexpr int NB  = 3000;   // box particles
constexpr int K   = 80;     // neighbor cap
constexpr float RAD = 0.1125f;
constexpr float R2  = RAD * RAD;
constexpr float EPSF = 1e-12f;

constexpr int NO  = 65 * 64;     // G row: 64 cells + 1 dense-skip col, O=64
constexpr int KCS = 4;           // split-K chunks, layer-0 GEMMs

__device__ __forceinline__ float sgn(float x) {
    return (x > 0.f) ? 1.f : ((x < 0.f) ? -1.f : 0.f);
}

__device__ __forceinline__ unsigned int bf16rne(float f) {
    unsigned int u = __float_as_uint(f);
    return (u + 0x7fffu + ((u >> 16) & 1u)) >> 16;   // round-to-nearest-even
}
__device__ __forceinline__ float bf16f(unsigned short u) {
    return __uint_as_float(((unsigned int)u) << 16);
}

// ---------------- neighbor search: one wave (64 lanes) per query -------------
__device__ void nn_search(const float* __restrict__ qpos, int wid,
                          const float* __restrict__ ipos, int ni, int self_ig,
                          int* __restrict__ cnt, int* __restrict__ idxs,
                          float* __restrict__ d2s, int lane)
{
    float qx = qpos[wid*3+0], qy = qpos[wid*3+1], qz = qpos[wid*3+2];
    int base = wid * K;
    int c = 0;
    for (int j0 = 0; j0 < ni; j0 += 64) {
        int j = j0 + lane;
        float d2 = 1e30f;
        if (j < ni) {
            float dx = ipos[j*3+0]-qx, dy = ipos[j*3+1]-qy, dz = ipos[j*3+2]-qz;
            d2 = dx*dx + dy*dy + dz*dz;
            if (self_ig && j == wid) d2 = 1e30f;
        }
        bool hit = d2 <= R2;
        unsigned long long m = __ballot(hit);
        int pc = __popcll(m);
        if (pc == 0) continue;
        if (c + pc <= K) {
            if (hit) {
                int pos = c + __popcll(m & ((1ull << lane) - 1ull));
                idxs[base + pos] = j;
                d2s [base + pos] = d2;
            }
            c += pc;
        } else {
            // rare overflow path: keep the K nearest (top_k semantics)
            while (m) {
                int l = __ffsll((unsigned long long)m) - 1;
                m &= m - 1ull;
                float dd = __shfl(d2, l);
                int jj = j0 + l;
                if (c < K) {
                    idxs[base + c] = jj;
                    d2s [base + c] = dd;
                    c++;
                } else {
                    float mx = -1.f; int am = 0;
                    for (int s = 0; s < K; ++s) {
                        float v = d2s[base + s];
                        if (v > mx) { mx = v; am = s; }
                    }
                    if (dd < mx) {
                        idxs[base + am] = jj;
                        d2s [base + am] = dd;
                    }
                }
            }
        }
    }
    if (lane == 0) cnt[wid] = c;
}

// merged: waves [0,NQ) = fluid self-search, [NQ,2NQ) = box search
__global__ __launch_bounds__(256) void nn2_kernel(
    const float* __restrict__ pos, const float* __restrict__ box,
    int* __restrict__ f_cnt, int* __restrict__ f_idx, float* __restrict__ f_d2,
    int* __restrict__ b_cnt, int* __restrict__ b_idx, float* __restrict__ b_d2)
{
    int gw = (blockIdx.x * blockDim.x + threadIdx.x) >> 6;
    int lane = threadIdx.x & 63;
    if (gw < NQ)
        nn_search(pos, gw, pos, NQ, 1, f_cnt, f_idx, f_d2, lane);
    else
        nn_search(pos, gw - NQ, box, NB, 0, b_cnt, b_idx, b_d2, lane);
}

// ------------- per-neighbor geometry: ball->cube + trilinear coefs -----------
__device__ void coef_one(const float* __restrict__ qpos, const float* __restrict__ ipos,
                         const int* __restrict__ cnt, const int* __restrict__ idxs,
                         int* __restrict__ cells, float* __restrict__ coefs,
                         int q, int k)
{
    if (k >= cnt[q]) return;
    int j = idxs[q*K + k];
    float rx = (ipos[j*3+0] - qpos[q*3+0]) / RAD;
    float ry = (ipos[j*3+1] - qpos[q*3+1]) / RAD;
    float rz = (ipos[j*3+2] - qpos[q*3+2]) / RAD;
    float r2 = rx*rx + ry*ry + rz*rz;
    float w1 = 1.f - r2;
    float win = (w1 > 0.f) ? w1*w1*w1 : 0.f;   // clip((1-r2)^3, 0, 1)
    float norm = sqrtf(r2);
    float rxy2 = rx*rx + ry*ry;
    float xc, yc, zc;
    if (r2 < 1e-12f) {
        xc = yc = zc = 0.f;
    } else if (1.25f * rz * rz > rxy2) {
        float s = sqrtf(3.0f * norm / (norm + fabsf(rz) + EPSF));
        xc = s * rx; yc = s * ry; zc = sgn(rz) * norm;
    } else {
        float s = norm / sqrtf(rxy2 + EPSF);
        xc = s * rx; yc = s * ry; zc = 1.5f * rz * s;
    }
    float rxy = sqrtf(xc*xc + yc*yc);
    const float FP = (float)(4.0 / M_PI);
    float u, v;
    if (rxy < EPSF) {
        u = 0.f; v = 0.f;
    } else if (fabsf(xc) >= fabsf(yc)) {
        float sx = (fabsf(xc) < EPSF) ? EPSF : xc;
        u = sgn(xc) * rxy;
        v = u * FP * atanf(yc / sx);
    } else {
        float sy = (fabsf(yc) < EPSF) ? EPSF : yc;
        v = sgn(yc) * rxy;
        u = v * FP * atanf(xc / sy);
    }
    float gx = fminf(fmaxf((u  + 1.f) * 0.5f * 3.f, 0.f), 3.f);
    float gy = fminf(fmaxf((v  + 1.f) * 0.5f * 3.f, 0.f), 3.f);
    float gz = fminf(fmaxf((zc + 1.f) * 0.5f * 3.f, 0.f), 3.f);
    int ix = min((int)floorf(gx), 2);
    int iy = min((int)floorf(gy), 2);
    int iz = min((int)floorf(gz), 2);
    float tx = gx - (float)ix, ty = gy - (float)iy, tz = gz - (float)iz;
    cells[q*K + k] = iz*16 + iy*4 + ix;
    float wx[2] = {1.f - tx, tx}, wy[2] = {1.f - ty, ty}, wz[2] = {1.f - tz, tz};
    float* cf = coefs + (size_t)(q*K + k) * 8;
#pragma unroll
    for (int c = 0; c < 8; ++c)   // c = dx*4 + dy*2 + dz (python loop order)
        cf[c] = wx[c >> 2] * wy[(c >> 1) & 1] * wz[c & 1] * win;
}

__global__ __launch_bounds__(256) void coef2_kernel(
    const float* __restrict__ pos, const float* __restrict__ box,
    const int* __restrict__ f_cnt, const int* __restrict__ f_idx,
    int* __restrict__ f_cell, float* __restrict__ f_coef,
    const int* __restrict__ b_cnt, const int* __restrict__ b_idx,
    int* __restrict__ b_cell, float* __restrict__ b_coef)
{
    int t = blockIdx.x * blockDim.x + threadIdx.x;
    if (t < NQ * K)
        coef_one(pos, pos, f_cnt, f_idx, f_cell, f_coef, t / K, t % K);
    else if (t < 2 * NQ * K) {
        int t2 = t - NQ * K;
        coef_one(pos, box, b_cnt, b_idx, b_cell, b_coef, t2 / K, t2 % K);
    }
}

// ------- small scatter (F in {3,4}): one WAVE per point, lane=(corner,feat) --
template<int F>
__global__ __launch_bounds__(256) void scatter_small_kernel(
    const float* __restrict__ feats,
    const int* __restrict__ cnt, const int* __restrict__ nidx,
    const int* __restrict__ ncell, const float* __restrict__ ncoef,
    float* __restrict__ Sg, int nq)
{
    __shared__ __align__(16) float S4[4][64 * F];
    int tid = threadIdx.x, lane = tid & 63, w = tid >> 6;
    int n = blockIdx.x * 4 + w;
    if (n >= nq) return;
    float* Sw = S4[w];
    for (int i = lane; i < 64 * F; i += 64) Sw[i] = 0.f;
    int cn = cnt[n];
    int kk2 = 64 + lane;
    int cb1 = (lane < cn) ? ncell[n*K + lane] : 0;
    int j1  = (lane < cn) ? nidx [n*K + lane] : 0;
    int cb2 = (kk2 < cn) ? ncell[n*K + kk2] : 0;
    int j2  = (kk2 < cn) ? nidx [n*K + kk2] : 0;
    int c = lane & 7, f = lane >> 3;
    bool fok = f < F;
    const float* coefG = ncoef + (size_t)n * K * 8;

    float wgt = 0.f, v = 0.f; int cb = 0;
    if (cn > 0) {
        int j = __shfl(j1, 0); cb = __shfl(cb1, 0);
        if (fok) { wgt = coefG[c]; v = feats[(size_t)j * F + f]; }
    }
    for (int kk = 0; kk < cn; ++kk) {
        float wn = 0.f, vn = 0.f; int cbn = 0;
        int k1n = kk + 1;
        if (k1n < cn) {
            int jn = (k1n < 64) ? __shfl(j1, k1n) : __shfl(j2, k1n - 64);
            cbn    = (k1n < 64) ? __shfl(cb1, k1n) : __shfl(cb2, k1n - 64);
            if (fok) { wn = coefG[k1n*8 + c]; vn = feats[(size_t)jn * F + f]; }
        }
        if (fok) {
            int cell = cb + (c & 1)*16 + ((c >> 1) & 1)*4 + (c >> 2);
            Sw[cell*F + f] += wgt * v;
        }
        wgt = wn; v = vn; cb = cbn;
    }
    float* row = Sg + (size_t)n * (64 * F);
    for (int i = lane; i < 16 * F; i += 64)
        ((float4*)row)[i] = ((const float4*)Sw)[i];
}

// ----------------- layer-0 GEMM (4x4 blocking, fp32 A), split-K --------------
template<int O>
__global__ __launch_bounds__(256) void gemm_kernel(
    const float* __restrict__ A, int Kdim,
    const float* __restrict__ B,
    float* __restrict__ P, int M)
{
    constexpr int TX   = O / 4;
    constexpr int TY   = 256 / TX;
    constexpr int MT   = TY * 4;
    constexpr int ASTR = MT + 4;
    __shared__ float As[16][ASTR];
    __shared__ float Bs[16 * O];
    int tid = threadIdx.x;
    int tx = tid % TX, ty = tid / TX;
    int m0 = blockIdx.x * MT;
    int ntiles = Kdim >> 4;
    float acc[4][4] = {};
    for (int t = blockIdx.y; t < ntiles; t += gridDim.y) {
        int k0 = t << 4;
        __syncthreads();
#pragma unroll
        for (int l = 0; l < MT / 64; ++l) {
            int idx = tid + l * 256;
            int mm = idx >> 2, k4 = idx & 3;
            int gm = m0 + mm; if (gm >= M) gm = M - 1;
            float4 av = *reinterpret_cast<const float4*>(A + (size_t)gm * Kdim + k0 + k4 * 4);
            As[k4*4+0][mm] = av.x; As[k4*4+1][mm] = av.y;
            As[k4*4+2][mm] = av.z; As[k4*4+3][mm] = av.w;
        }
        constexpr int NB4 = 16 * O / 4;
        if (NB4 == 256 || tid < NB4)
            *reinterpret_cast<float4*>(&Bs[tid*4]) =
                *reinterpret_cast<const float4*>(B + (size_t)k0 * O + tid * 4);
        __syncthreads();
#pragma unroll
        for (int kk = 0; kk < 16; ++kk) {
            float4 av = *reinterpret_cast<const float4*>(&As[kk][ty*4]);
            float4 bv = *reinterpret_cast<const float4*>(&Bs[kk*O + tx*4]);
            float aa[4] = {av.x, av.y, av.z, av.w};
            float bb[4] = {bv.x, bv.y, bv.z, bv.w};
#pragma unroll
            for (int i = 0; i < 4; ++i)
#pragma unroll
                for (int jj = 0; jj < 4; ++jj)
                    acc[i][jj] += aa[i] * bb[jj];
        }
    }
    float* Pb = P + (size_t)blockIdx.y * M * O;
#pragma unroll
    for (int i = 0; i < 4; ++i) {
        int gm = m0 + ty*4 + i;
        if (gm < M)
#pragma unroll
            for (int jj = 0; jj < 4; ++jj)
                Pb[(size_t)gm * O + tx*4 + jj] = acc[i][jj];
    }
}

// ---- G-GEMM: G[j, c*64+o] = relu(feats[j,:]) . Bg[:, c*64+o], bf16 out ------
// K = F (<=96) staged once in LDS; 64x64 tile, 4x4 micro. No k-loop, no split-K.
template<int F>
__global__ __launch_bounds__(256) void gemmG_kernel(
    const float* __restrict__ feats,      // [M, F] fp32
    const float* __restrict__ Bg,         // [F, NO] fp32
    unsigned short* __restrict__ G,       // [M, NO] bf16
    int M)
{
    constexpr int ASTR = 68;
    __shared__ float As[F * ASTR];        // k-major [F][64+pad]
    __shared__ float Bs[F * 64];          // [F][64]
    int tid = threadIdx.x;
    int tx = tid & 15, ty = tid >> 4;
    int m0 = blockIdx.x * 64;
    int no0 = blockIdx.y * 64;
    // stage A (relu at load), transposed to k-major
#pragma unroll
    for (int l = 0; l < F * 16 / 256; ++l) {     // F*64/4 float4 loads
        int idx = tid + l * 256;
        int mm = idx / (F / 4), k4 = idx % (F / 4);
        int gm = m0 + mm; if (gm >= M) gm = M - 1;
        float4 av = *reinterpret_cast<const float4*>(feats + (size_t)gm * F + k4 * 4);
        As[(k4*4+0)*ASTR + mm] = fmaxf(av.x, 0.f);
        As[(k4*4+1)*ASTR + mm] = fmaxf(av.y, 0.f);
        As[(k4*4+2)*ASTR + mm] = fmaxf(av.z, 0.f);
        As[(k4*4+3)*ASTR + mm] = fmaxf(av.w, 0.f);
    }
    // stage B: rows f, 64 cols starting at no0
#pragma unroll
    for (int l = 0; l < F * 16 / 256; ++l) {
        int idx = tid + l * 256;
        int f = idx >> 4, o4 = idx & 15;
        *reinterpret_cast<float4*>(&Bs[f*64 + o4*4]) =
            *reinterpret_cast<const float4*>(Bg + (size_t)f * NO + no0 + o4*4);
    }
    __syncthreads();
    float acc[4][4] = {};
#pragma unroll 8
    for (int k = 0; k < F; ++k) {
        float4 av = *reinterpret_cast<const float4*>(&As[k*ASTR + ty*4]);
        float4 bv = *reinterpret_cast<const float4*>(&Bs[k*64 + tx*4]);
        float aa[4] = {av.x, av.y, av.z, av.w};
        float bb[4] = {bv.x, bv.y, bv.z, bv.w};
#pragma unroll
        for (int i = 0; i < 4; ++i)
#pragma unroll
            for (int jj = 0; jj < 4; ++jj)
                acc[i][jj] += aa[i] * bb[jj];
    }
#pragma unroll
    for (int i = 0; i < 4; ++i) {
        int gm = m0 + ty*4 + i;
        if (gm < M) {
            uint2 o;
            o.x = bf16rne(acc[i][0]) | (bf16rne(acc[i][1]) << 16);
            o.y = bf16rne(acc[i][2]) | (bf16rne(acc[i][3]) << 16);
            *reinterpret_cast<uint2*>(G + (size_t)gm * NO + no0 + tx*4) = o;
        }
    }
}

// ---- G-gather: out[n,o] = sum_k sum_c coef[n,k,c] G[j_k, c*64+o]
//                + G[n, 64*64+o] (dense skip) + cb[o] + db[o] (+ resid) -------
__global__ __launch_bounds__(256) void gatherG_kernel(
    const int* __restrict__ cnt, const int* __restrict__ nidx,
    const int* __restrict__ ncell, const float* __restrict__ ncoef,
    const unsigned short* __restrict__ G,
    const float* __restrict__ cb, const float* __restrict__ db,
    const float* __restrict__ resid, float* __restrict__ out)
{
    int n = (blockIdx.x * blockDim.x + threadIdx.x) >> 6;
    int lane = threadIdx.x & 63;
    if (n >= NQ) return;
    int cn = cnt[n];
    int kk2 = 64 + lane;
    int cb1 = (lane < cn) ? ncell[n*K + lane] : 0;
    int j1  = (lane < cn) ? nidx [n*K + lane] : 0;
    int cb2 = (kk2 < cn) ? ncell[n*K + kk2] : 0;
    int j2  = (kk2 < cn) ? nidx [n*K + kk2] : 0;
    float acc = cb[lane] + db[lane];
    const float* cfp = ncoef + (size_t)n * K * 8;
    for (int k = 0; k < cn; ++k) {
        int j    = (k < 64) ? __shfl(j1, k)  : __shfl(j2, k - 64);
        int cbse = (k < 64) ? __shfl(cb1, k) : __shfl(cb2, k - 64);
        float4 cA = *reinterpret_cast<const float4*>(cfp + k*8);      // c=0..3 (dx=0)
        float4 cB = *reinterpret_cast<const float4*>(cfp + k*8 + 4);  // c=4..7 (dx=1)
        const unsigned short* Gj = G + (size_t)j * NO + lane;
        // c = dx*4+dy*2+dz ; cell = cbse + dz*16 + dy*4 + dx
        acc += cA.x * bf16f(Gj[(cbse     ) * 64]);
        acc += cA.y * bf16f(Gj[(cbse + 16) * 64]);
        acc += cA.z * bf16f(Gj[(cbse +  4) * 64]);
        acc += cA.w * bf16f(Gj[(cbse + 20) * 64]);
        acc += cB.x * bf16f(Gj[(cbse +  1) * 64]);
        acc += cB.y * bf16f(Gj[(cbse + 17) * 64]);
        acc += cB.z * bf16f(Gj[(cbse +  5) * 64]);
        acc += cB.w * bf16f(Gj[(cbse + 21) * 64]);
    }
    acc += bf16f(G[(size_t)n * NO + 64*64 + lane]);   // dense skip
    if (resid) acc += resid[(size_t)n * 64 + lane];
    out[(size_t)n * 64 + lane] = acc;
}

// ----------- prep: B1g, B2g (G-GEMM layouts), W3p, ff, dense-0 into x1 -------
__global__ __launch_bounds__(256) void prep_kernel(
    const float* __restrict__ c1w, const float* __restrict__ d1w,
    const float* __restrict__ c2w, const float* __restrict__ d2w,
    const float* __restrict__ c3w, const float* __restrict__ d3w,
    const float* __restrict__ vel,
    const float* __restrict__ d0w, const float* __restrict__ d0b,
    float* __restrict__ B1g, float* __restrict__ B2g, float* __restrict__ W3p,
    float* __restrict__ ff, float* __restrict__ x1)
{
    int stride = gridDim.x * blockDim.x;
    int gid = blockIdx.x * blockDim.x + threadIdx.x;
    // B1g[f, c*64+o] = c1_w[c,f,o] (c<64) else d1_w[f,o]
    for (int i = gid; i < 96 * NO; i += stride) {
        int f = i / NO, r = i % NO, c = r >> 6, o = r & 63;
        B1g[i] = (c < 64) ? c1w[((size_t)c*96 + f)*64 + o] : d1w[f*64 + o];
    }
    for (int i = gid; i < 64 * NO; i += stride) {
        int f = i / NO, r = i % NO, c = r >> 6, o = r & 63;
        B2g[i] = (c < 64) ? c2w[((size_t)c*64 + f)*64 + o] : d2w[f*64 + o];
    }
    for (int i = gid; i < 64 * 195; i += stride) {   // W3p[f][c*3+o]
        int f = i / 195, r = i % 195, c = r / 3, o = r % 3;
        W3p[i] = (c < 64) ? c3w[(c*64 + f)*3 + o] : d3w[f*3 + o];
    }
    for (int i = gid; i < NQ; i += stride) {
        ff[i*4+0] = 1.f;
        ff[i*4+1] = vel[i*3+0];
        ff[i*4+2] = vel[i*3+1];
        ff[i*4+3] = vel[i*3+2];
    }
    for (int i = gid; i < NQ * 32; i += stride) {    // dense-0 skip -> x1[:,64:96]
        int n = i >> 5, o = i & 31;
        float acc = d0b[o] + d0w[o]
                  + vel[n*3+0] * d0w[32 + o]
                  + vel[n*3+1] * d0w[64 + o]
                  + vel[n*3+2] * d0w[96 + o];
        x1[n*96 + 64 + o] = acc;
    }
}

// epilogue for layer 0: x1[:,0:32] = sum(Pco)+co_b ; x1[:,32:64] = sum(Pcf)+cf_b
__global__ __launch_bounds__(256) void e0_kernel(
    const float* __restrict__ Pco, const float* __restrict__ Pcf, int kc,
    const float* __restrict__ cob, const float* __restrict__ cfb,
    float* __restrict__ x1)
{
    int t = blockIdx.x * blockDim.x + threadIdx.x;
    if (t >= NQ * 64) return;
    int n = t >> 6, c = t & 63;
    float v;
    if (c < 32) {
        v = cob[c];
        for (int ky = 0; ky < kc; ++ky) v += Pco[(size_t)ky * NQ * 32 + n*32 + c];
    } else {
        int cc = c - 32;
        v = cfb[cc];
        for (int ky = 0; ky < kc; ++ky) v += Pcf[(size_t)ky * NQ * 32 + n*32 + cc];
    }
    x1[n*96 + c] = v;
}

// ---- final layer via transform+gather: Y[j, c<=64, 3] = relu(x3[j])*W3' -----
__global__ __launch_bounds__(256) void y3t_kernel(
    const float* __restrict__ x3, const float* __restrict__ W3p,
    float* __restrict__ Y)
{
    __shared__ float xr[64];
    int n = blockIdx.x, tid = threadIdx.x;
    if (tid < 64) xr[tid] = fmaxf(x3[n*64 + tid], 0.f);
    __syncthreads();
    if (tid < 195) {
        float acc = 0.f;
#pragma unroll 8
        for (int f = 0; f < 64; ++f) acc += xr[f] * W3p[f*195 + tid];
        Y[(size_t)n * 195 + tid] = acc;
    }
}

__global__ __launch_bounds__(256) void gather3_kernel(
    const int* __restrict__ cnt, const int* __restrict__ nidx,
    const int* __restrict__ ncell, const float* __restrict__ ncoef,
    const float* __restrict__ Y,
    const float* __restrict__ cb3, const float* __restrict__ db3,
    float* __restrict__ out)
{
    int gw = (blockIdx.x * blockDim.x + threadIdx.x) >> 6;
    int lane = threadIdx.x & 63;
    if (gw >= NQ) return;
    int n = gw;
    int cn = cnt[n];
    float a0 = 0.f, a1 = 0.f, a2 = 0.f;
#pragma unroll
    for (int seg = 0; seg < 2; ++seg) {
        int kidx = seg * 64 + lane;
        if (kidx < cn) {
            int j  = nidx [n*K + kidx];
            int cb = ncell[n*K + kidx];
            const float* cf = ncoef + (size_t)(n*K + kidx) * 8;
            const float* Yj = Y + (size_t)j * 195;
#pragma unroll
            for (int c = 0; c < 8; ++c) {
                int cell = cb + (c & 1)*16 + ((c >> 1) & 1)*4 + (c >> 2);
                float wgt = cf[c];
                const float* Tp = Yj + cell*3;
                a0 += wgt * Tp[0];
                a1 += wgt * Tp[1];
                a2 += wgt * Tp[2];
            }
        }
    }
#pragma unroll
    for (int s = 32; s > 0; s >>= 1) {
        a0 += __shfl_down(a0, s);
        a1 += __shfl_down(a1, s);
        a2 += __shfl_down(a2, s);
    }
    if (lane == 0) {
        const float* Yn = Y + (size_t)n * 195 + 192;   // dense skip (c=64)
        out[n*3+0] = (a0 + Yn[0] + cb3[0] + db3[0]) * (1.f/128.f);
        out[n*3+1] = (a1 + Yn[1] + cb3[1] + db3[1]) * (1.f/128.f);
        out[n*3+2] = (a2 + Yn[2] + cb3[2] + db3[2]) * (1.f/128.f);
    }
}

} // namespace

extern "C" void kernel_launch(void* const* d_in, const int* in_sizes, int n_in,
                              void* d_out, int out_size, void* d_ws, size_t ws_size,
                              hipStream_t stream)
{
    const float* pos       = (const float*)d_in[0];
    const float* vel       = (const float*)d_in[1];
    const float* box       = (const float*)d_in[2];
    const float* box_feats = (const float*)d_in[3];
    const float* cf_w = (const float*)d_in[4];  const float* cf_b = (const float*)d_in[5];
    const float* co_w = (const float*)d_in[6];  const float* co_b = (const float*)d_in[7];
    const float* d0_w = (const float*)d_in[8];  const float* d0_b = (const float*)d_in[9];
    const float* c1_w = (const float*)d_in[10]; const float* c1_b = (const float*)d_in[11];
    const float* d1_w = (const float*)d_in[12]; const float* d1_b = (const float*)d_in[13];
    const float* c2_w = (const float*)d_in[14]; const float* c2_b = (const float*)d_in[15];
    const float* d2_w = (const float*)d_in[16]; const float* d2_b = (const float*)d_in[17];
    const float* c3_w = (const float*)d_in[18]; const float* c3_b = (const float*)d_in[19];
    const float* d3_w = (const float*)d_in[20]; const float* d3_b = (const float*)d_in[21];

    char* wsb = (char*)d_ws;
    size_t off = 0;
    auto alloc = [&](size_t bytes) {
        void* p = wsb + off;
        off = (off + bytes + 255) & ~(size_t)255;
        return p;
    };
    // Big region time-shared: {f_d2,b_d2} during nn -> {S_cf,S_co} (layer 0)
    // -> bf16 G rows for layers 1/2.
    char*  Graw = (char*)alloc((size_t)NQ * NO * 2 + 4096);   // 50 MB
    unsigned short* G = (unsigned short*)Graw;
    float* f_d2 = (float*)Graw;
    float* b_d2 = (float*)Graw + (size_t)NQ * K;
    float* S_cf = (float*)Graw;                      // [NQ,256] fp32
    float* S_co = (float*)Graw + (size_t)NQ * 256;   // [NQ,192] fp32
    int*   f_cnt  = (int*)  alloc((size_t)NQ * 4);
    int*   f_idx  = (int*)  alloc((size_t)NQ * K * 4);
    int*   f_cell = (int*)  alloc((size_t)NQ * K * 4);
    float* f_coef = (float*)alloc((size_t)NQ * K * 8 * 4);
    int*   b_cnt  = (int*)  alloc((size_t)NQ * 4);
    int*   b_idx  = (int*)  alloc((size_t)NQ * K * 4);
    int*   b_cell = (int*)  alloc((size_t)NQ * K * 4);
    float* b_coef = (float*)alloc((size_t)NQ * K * 8 * 4);
    float* ff     = (float*)alloc((size_t)NQ * 4 * 4);
    float* x1     = (float*)alloc((size_t)NQ * 96 * 4);
    float* x2     = (float*)alloc((size_t)NQ * 64 * 4);
    float* x3     = (float*)alloc((size_t)NQ * 64 * 4);
    float* B1g    = (float*)alloc((size_t)96 * NO * 4);   // 1.6 MB
    float* B2g    = (float*)alloc((size_t)64 * NO * 4);   // 1.1 MB
    float* W3p    = (float*)alloc((size_t)64 * 195 * 4);
    float* P      = (float*)alloc((size_t)KCS * NQ * 64 * 4);  // layer-0 partials / Y
    float* Pco    = P;
    float* Pcf    = P + (size_t)KCS * NQ * 32;
    float* Y      = P;

    dim3 b256(256);
    prep_kernel<<<512, b256, 0, stream>>>(c1_w, d1_w, c2_w, d2_w, c3_w, d3_w,
                                          vel, d0_w, d0_b, B1g, B2g, W3p, ff, x1);
    nn2_kernel<<<2*NQ/4, b256, 0, stream>>>(pos, box, f_cnt, f_idx, f_d2,
                                            b_cnt, b_idx, b_d2);
    coef2_kernel<<<(2*NQ*K + 255)/256, b256, 0, stream>>>(
        pos, box, f_cnt, f_idx, f_cell, f_coef, b_cnt, b_idx, b_cell, b_coef);
    // ---- layer 0 ----
    scatter_small_kernel<4><<<(NQ+3)/4, b256, 0, stream>>>(ff, f_cnt, f_idx,
        f_cell, f_coef, S_cf, NQ);
    scatter_small_kernel<3><<<(NQ+3)/4, b256, 0, stream>>>(box_feats, b_cnt, b_idx,
        b_cell, b_coef, S_co, NQ);
    gemm_kernel<32><<<dim3((NQ+127)/128, KCS), b256, 0, stream>>>(S_co, 192, co_w, Pco, NQ);
    gemm_kernel<32><<<dim3((NQ+127)/128, KCS), b256, 0, stream>>>(S_cf, 256, cf_w, Pcf, NQ);
    e0_kernel<<<(NQ*64 + 255)/256, b256, 0, stream>>>(Pco, Pcf, KCS, co_b, cf_b, x1);
    // ---- layer 1: G1 = relu(x1) x [c1;d1] ; x2 = gather(G1) + biases ----
    gemmG_kernel<96><<<dim3((NQ+63)/64, NO/64), b256, 0, stream>>>(x1, B1g, G, NQ);
    gatherG_kernel<<<(NQ+3)/4, b256, 0, stream>>>(f_cnt, f_idx, f_cell, f_coef,
        G, c1_b, d1_b, nullptr, x2);
    // ---- layer 2: G2 = relu(x2) x [c2;d2] ; x3 = gather(G2) + biases + x2 ----
    gemmG_kernel<64><<<dim3((NQ+63)/64, NO/64), b256, 0, stream>>>(x2, B2g, G, NQ);
    gatherG_kernel<<<(NQ+3)/4, b256, 0, stream>>>(f_cnt, f_idx, f_cell, f_coef,
        G, c2_b, d2_b, x2, x3);
    // ---- layer 3 (O=3): transform Y = relu(x3)*[c3;d3], then gather ----
    y3t_kernel<<<NQ, b256, 0, stream>>>(x3, W3p, Y);
    gather3_kernel<<<(NQ+3)/4, b256, 0, stream>>>(f_cnt, f_idx, f_cell, f_coef,
        Y, c3_b, d3_b, (float*)d_out);

    (void)in_sizes; (void)n_in; (void)out_size; (void)ws_size;
}

// Round 8
// 339.323 us; speedup vs baseline: 6.8745x; 1.2596x over previous
//
#include <hip/hip_runtime.h>
#include <math.h>

namespace {

constexpr int NQ  = 6000;   // fluid particles (queries)
constexpr int NB  = 3000;   // box particles
constexpr int K   = 80;     // neighbor cap
constexpr float RAD = 0.1125f;
constexpr float R2  = RAD * RAD;
constexpr float EPSF = 1e-12f;

constexpr int NO  = 65 * 64;     // G row: 64 cells + 1 dense-skip col, O=64
constexpr int KCS = 4;           // split-K chunks, layer-0 GEMMs

typedef __attribute__((ext_vector_type(8))) short bf16x8;
typedef __attribute__((ext_vector_type(4))) float f32x4;

__device__ __forceinline__ float sgn(float x) {
    return (x > 0.f) ? 1.f : ((x < 0.f) ? -1.f : 0.f);
}

__device__ __forceinline__ unsigned int bf16rne(float f) {
    unsigned int u = __float_as_uint(f);
    return (u + 0x7fffu + ((u >> 16) & 1u)) >> 16;   // round-to-nearest-even
}
__device__ __forceinline__ float bf16f(unsigned short u) {
    return __uint_as_float(((unsigned int)u) << 16);
}

// ---------------- neighbor search: one wave (64 lanes) per query -------------
__device__ void nn_search(const float* __restrict__ qpos, int wid,
                          const float* __restrict__ ipos, int ni, int self_ig,
                          int* __restrict__ cnt, int* __restrict__ idxs,
                          float* __restrict__ d2s, int lane)
{
    float qx = qpos[wid*3+0], qy = qpos[wid*3+1], qz = qpos[wid*3+2];
    int base = wid * K;
    int c = 0;
    for (int j0 = 0; j0 < ni; j0 += 64) {
        int j = j0 + lane;
        float d2 = 1e30f;
        if (j < ni) {
            float dx = ipos[j*3+0]-qx, dy = ipos[j*3+1]-qy, dz = ipos[j*3+2]-qz;
            d2 = dx*dx + dy*dy + dz*dz;
            if (self_ig && j == wid) d2 = 1e30f;
        }
        bool hit = d2 <= R2;
        unsigned long long m = __ballot(hit);
        int pc = __popcll(m);
        if (pc == 0) continue;
        if (c + pc <= K) {
            if (hit) {
                int pos = c + __popcll(m & ((1ull << lane) - 1ull));
                idxs[base + pos] = j;
                d2s [base + pos] = d2;
            }
            c += pc;
        } else {
            // rare overflow path: keep the K nearest (top_k semantics)
            while (m) {
                int l = __ffsll((unsigned long long)m) - 1;
                m &= m - 1ull;
                float dd = __shfl(d2, l);
                int jj = j0 + l;
                if (c < K) {
                    idxs[base + c] = jj;
                    d2s [base + c] = dd;
                    c++;
                } else {
                    float mx = -1.f; int am = 0;
                    for (int s = 0; s < K; ++s) {
                        float v = d2s[base + s];
                        if (v > mx) { mx = v; am = s; }
                    }
                    if (dd < mx) {
                        idxs[base + am] = jj;
                        d2s [base + am] = dd;
                    }
                }
            }
        }
    }
    if (lane == 0) cnt[wid] = c;
}

// merged: waves [0,NQ) = fluid self-search, [NQ,2NQ) = box search
__global__ __launch_bounds__(256) void nn2_kernel(
    const float* __restrict__ pos, const float* __restrict__ box,
    int* __restrict__ f_cnt, int* __restrict__ f_idx, float* __restrict__ f_d2,
    int* __restrict__ b_cnt, int* __restrict__ b_idx, float* __restrict__ b_d2)
{
    int gw = (blockIdx.x * blockDim.x + threadIdx.x) >> 6;
    int lane = threadIdx.x & 63;
    if (gw < NQ)
        nn_search(pos, gw, pos, NQ, 1, f_cnt, f_idx, f_d2, lane);
    else
        nn_search(pos, gw - NQ, box, NB, 0, b_cnt, b_idx, b_d2, lane);
}

// ------------- per-neighbor geometry: ball->cube + trilinear coefs -----------
__device__ void coef_one(const float* __restrict__ qpos, const float* __restrict__ ipos,
                         const int* __restrict__ cnt, const int* __restrict__ idxs,
                         int* __restrict__ cells, float* __restrict__ coefs,
                         int q, int k)
{
    if (k >= cnt[q]) return;
    int j = idxs[q*K + k];
    float rx = (ipos[j*3+0] - qpos[q*3+0]) / RAD;
    float ry = (ipos[j*3+1] - qpos[q*3+1]) / RAD;
    float rz = (ipos[j*3+2] - qpos[q*3+2]) / RAD;
    float r2 = rx*rx + ry*ry + rz*rz;
    float w1 = 1.f - r2;
    float win = (w1 > 0.f) ? w1*w1*w1 : 0.f;   // clip((1-r2)^3, 0, 1)
    float norm = sqrtf(r2);
    float rxy2 = rx*rx + ry*ry;
    float xc, yc, zc;
    if (r2 < 1e-12f) {
        xc = yc = zc = 0.f;
    } else if (1.25f * rz * rz > rxy2) {
        float s = sqrtf(3.0f * norm / (norm + fabsf(rz) + EPSF));
        xc = s * rx; yc = s * ry; zc = sgn(rz) * norm;
    } else {
        float s = norm / sqrtf(rxy2 + EPSF);
        xc = s * rx; yc = s * ry; zc = 1.5f * rz * s;
    }
    float rxy = sqrtf(xc*xc + yc*yc);
    const float FP = (float)(4.0 / M_PI);
    float u, v;
    if (rxy < EPSF) {
        u = 0.f; v = 0.f;
    } else if (fabsf(xc) >= fabsf(yc)) {
        float sx = (fabsf(xc) < EPSF) ? EPSF : xc;
        u = sgn(xc) * rxy;
        v = u * FP * atanf(yc / sx);
    } else {
        float sy = (fabsf(yc) < EPSF) ? EPSF : yc;
        v = sgn(yc) * rxy;
        u = v * FP * atanf(xc / sy);
    }
    float gx = fminf(fmaxf((u  + 1.f) * 0.5f * 3.f, 0.f), 3.f);
    float gy = fminf(fmaxf((v  + 1.f) * 0.5f * 3.f, 0.f), 3.f);
    float gz = fminf(fmaxf((zc + 1.f) * 0.5f * 3.f, 0.f), 3.f);
    int ix = min((int)floorf(gx), 2);
    int iy = min((int)floorf(gy), 2);
    int iz = min((int)floorf(gz), 2);
    float tx = gx - (float)ix, ty = gy - (float)iy, tz = gz - (float)iz;
    cells[q*K + k] = iz*16 + iy*4 + ix;
    float wx[2] = {1.f - tx, tx}, wy[2] = {1.f - ty, ty}, wz[2] = {1.f - tz, tz};
    float* cf = coefs + (size_t)(q*K + k) * 8;
#pragma unroll
    for (int c = 0; c < 8; ++c)   // c = dx*4 + dy*2 + dz (python loop order)
        cf[c] = wx[c >> 2] * wy[(c >> 1) & 1] * wz[c & 1] * win;
}

__global__ __launch_bounds__(256) void coef2_kernel(
    const float* __restrict__ pos, const float* __restrict__ box,
    const int* __restrict__ f_cnt, const int* __restrict__ f_idx,
    int* __restrict__ f_cell, float* __restrict__ f_coef,
    const int* __restrict__ b_cnt, const int* __restrict__ b_idx,
    int* __restrict__ b_cell, float* __restrict__ b_coef)
{
    int t = blockIdx.x * blockDim.x + threadIdx.x;
    if (t < NQ * K)
        coef_one(pos, pos, f_cnt, f_idx, f_cell, f_coef, t / K, t % K);
    else if (t < 2 * NQ * K) {
        int t2 = t - NQ * K;
        coef_one(pos, box, b_cnt, b_idx, b_cell, b_coef, t2 / K, t2 % K);
    }
}

// ------- small scatter (F in {3,4}): one WAVE per point, lane=(corner,feat) --
template<int F>
__global__ __launch_bounds__(256) void scatter_small_kernel(
    const float* __restrict__ feats,
    const int* __restrict__ cnt, const int* __restrict__ nidx,
    const int* __restrict__ ncell, const float* __restrict__ ncoef,
    float* __restrict__ Sg, int nq)
{
    __shared__ __align__(16) float S4[4][64 * F];
    int tid = threadIdx.x, lane = tid & 63, w = tid >> 6;
    int n = blockIdx.x * 4 + w;
    if (n >= nq) return;
    float* Sw = S4[w];
    for (int i = lane; i < 64 * F; i += 64) Sw[i] = 0.f;
    int cn = cnt[n];
    int kk2 = 64 + lane;
    int cb1 = (lane < cn) ? ncell[n*K + lane] : 0;
    int j1  = (lane < cn) ? nidx [n*K + lane] : 0;
    int cb2 = (kk2 < cn) ? ncell[n*K + kk2] : 0;
    int j2  = (kk2 < cn) ? nidx [n*K + kk2] : 0;
    int c = lane & 7, f = lane >> 3;
    bool fok = f < F;
    const float* coefG = ncoef + (size_t)n * K * 8;

    float wgt = 0.f, v = 0.f; int cb = 0;
    if (cn > 0) {
        int j = __shfl(j1, 0); cb = __shfl(cb1, 0);
        if (fok) { wgt = coefG[c]; v = feats[(size_t)j * F + f]; }
    }
    for (int kk = 0; kk < cn; ++kk) {
        float wn = 0.f, vn = 0.f; int cbn = 0;
        int k1n = kk + 1;
        if (k1n < cn) {
            int jn = (k1n < 64) ? __shfl(j1, k1n) : __shfl(j2, k1n - 64);
            cbn    = (k1n < 64) ? __shfl(cb1, k1n) : __shfl(cb2, k1n - 64);
            if (fok) { wn = coefG[k1n*8 + c]; vn = feats[(size_t)jn * F + f]; }
        }
        if (fok) {
            int cell = cb + (c & 1)*16 + ((c >> 1) & 1)*4 + (c >> 2);
            Sw[cell*F + f] += wgt * v;
        }
        wgt = wn; v = vn; cb = cbn;
    }
    float* row = Sg + (size_t)n * (64 * F);
    for (int i = lane; i < 16 * F; i += 64)
        ((float4*)row)[i] = ((const float4*)Sw)[i];
}

// ----------------- layer-0 GEMM (4x4 blocking, fp32 A), split-K --------------
template<int O>
__global__ __launch_bounds__(256) void gemm_kernel(
    const float* __restrict__ A, int Kdim,
    const float* __restrict__ B,
    float* __restrict__ P, int M)
{
    constexpr int TX   = O / 4;
    constexpr int TY   = 256 / TX;
    constexpr int MT   = TY * 4;
    constexpr int ASTR = MT + 4;
    __shared__ float As[16][ASTR];
    __shared__ float Bs[16 * O];
    int tid = threadIdx.x;
    int tx = tid % TX, ty = tid / TX;
    int m0 = blockIdx.x * MT;
    int ntiles = Kdim >> 4;
    float acc[4][4] = {};
    for (int t = blockIdx.y; t < ntiles; t += gridDim.y) {
        int k0 = t << 4;
        __syncthreads();
#pragma unroll
        for (int l = 0; l < MT / 64; ++l) {
            int idx = tid + l * 256;
            int mm = idx >> 2, k4 = idx & 3;
            int gm = m0 + mm; if (gm >= M) gm = M - 1;
            float4 av = *reinterpret_cast<const float4*>(A + (size_t)gm * Kdim + k0 + k4 * 4);
            As[k4*4+0][mm] = av.x; As[k4*4+1][mm] = av.y;
            As[k4*4+2][mm] = av.z; As[k4*4+3][mm] = av.w;
        }
        constexpr int NB4 = 16 * O / 4;
        if (NB4 == 256 || tid < NB4)
            *reinterpret_cast<float4*>(&Bs[tid*4]) =
                *reinterpret_cast<const float4*>(B + (size_t)k0 * O + tid * 4);
        __syncthreads();
#pragma unroll
        for (int kk = 0; kk < 16; ++kk) {
            float4 av = *reinterpret_cast<const float4*>(&As[kk][ty*4]);
            float4 bv = *reinterpret_cast<const float4*>(&Bs[kk*O + tx*4]);
            float aa[4] = {av.x, av.y, av.z, av.w};
            float bb[4] = {bv.x, bv.y, bv.z, bv.w};
#pragma unroll
            for (int i = 0; i < 4; ++i)
#pragma unroll
                for (int jj = 0; jj < 4; ++jj)
                    acc[i][jj] += aa[i] * bb[jj];
        }
    }
    float* Pb = P + (size_t)blockIdx.y * M * O;
#pragma unroll
    for (int i = 0; i < 4; ++i) {
        int gm = m0 + ty*4 + i;
        if (gm < M)
#pragma unroll
            for (int jj = 0; jj < 4; ++jj)
                Pb[(size_t)gm * O + tx*4 + jj] = acc[i][jj];
    }
}

// ---- MFMA G-GEMM: G[j, n] = relu(feats[j,:]) . Bt[n,:]  (bf16 in/out) -------
// 64x64 block tile, 4 waves x (16m x 64n), K=F resident in LDS, no k-barriers.
// As/Bs row stride F+8 ushorts: 16B-aligned frags, <=2-way bank aliasing.
template<int F>
__global__ __launch_bounds__(256) void gemmGm_kernel(
    const float* __restrict__ feats,            // [M,F] fp32
    const unsigned short* __restrict__ Bt,      // [NO,F] bf16 (n-major)
    unsigned short* __restrict__ G,             // [M,NO] bf16
    int M)
{
    constexpr int AST = F + 8;
    __shared__ unsigned short As[64 * AST];     // [m][k]
    __shared__ unsigned short Bs[64 * AST];     // [n][k]
    int tid = threadIdx.x, lane = tid & 63, wv = tid >> 6;
    int m0 = blockIdx.x * 64, no0 = blockIdx.y * 64;
    // stage A: fp32 -> relu -> bf16
    for (int i = tid; i < 64 * F / 4; i += 256) {
        int m = i / (F / 4), k4 = i % (F / 4);
        int gm = m0 + m; if (gm >= M) gm = M - 1;
        float4 av = *reinterpret_cast<const float4*>(feats + (size_t)gm * F + k4 * 4);
        uint2 o;
        o.x = bf16rne(fmaxf(av.x, 0.f)) | (bf16rne(fmaxf(av.y, 0.f)) << 16);
        o.y = bf16rne(fmaxf(av.z, 0.f)) | (bf16rne(fmaxf(av.w, 0.f)) << 16);
        *reinterpret_cast<uint2*>(As + m * AST + k4 * 4) = o;
    }
    // stage B-tile (rows no0..no0+63 of Bt, contiguous per row)
    for (int i = tid; i < 64 * F / 8; i += 256) {
        int n = i / (F / 8), k8 = i % (F / 8);
        *reinterpret_cast<uint4*>(Bs + n * AST + k8 * 8) =
            *reinterpret_cast<const uint4*>(Bt + (size_t)(no0 + n) * F + k8 * 8);
    }
    __syncthreads();
    int mr = lane & 15, quad = lane >> 4;
    f32x4 acc[4] = {{0.f,0.f,0.f,0.f},{0.f,0.f,0.f,0.f},
                    {0.f,0.f,0.f,0.f},{0.f,0.f,0.f,0.f}};
#pragma unroll
    for (int kc = 0; kc < F; kc += 32) {
        bf16x8 a = *reinterpret_cast<const bf16x8*>(As + (wv*16 + mr) * AST + kc + quad*8);
#pragma unroll
        for (int t = 0; t < 4; ++t) {
            bf16x8 b = *reinterpret_cast<const bf16x8*>(Bs + (t*16 + mr) * AST + kc + quad*8);
            acc[t] = __builtin_amdgcn_mfma_f32_16x16x32_bf16(a, b, acc[t], 0, 0, 0);
        }
    }
    // C layout: col = lane&15, row = quad*4 + reg
#pragma unroll
    for (int t = 0; t < 4; ++t) {
#pragma unroll
        for (int r = 0; r < 4; ++r) {
            int gm = m0 + wv*16 + quad*4 + r;
            if (gm < M)
                G[(size_t)gm * NO + no0 + t*16 + mr] = (unsigned short)bf16rne(acc[t][r]);
        }
    }
}

// ---- G-gather: out[n,o] = sum_k sum_c coef[n,k,c] G[j_k, c*64+o]
//                + G[n, 64*64+o] (dense skip) + cb[o] + db[o] (+ resid) -------
__global__ __launch_bounds__(256) void gatherG_kernel(
    const int* __restrict__ cnt, const int* __restrict__ nidx,
    const int* __restrict__ ncell, const float* __restrict__ ncoef,
    const unsigned short* __restrict__ G,
    const float* __restrict__ cb, const float* __restrict__ db,
    const float* __restrict__ resid, float* __restrict__ out)
{
    int n = (blockIdx.x * blockDim.x + threadIdx.x) >> 6;
    int lane = threadIdx.x & 63;
    if (n >= NQ) return;
    int cn = cnt[n];
    int kk2 = 64 + lane;
    int cb1 = (lane < cn) ? ncell[n*K + lane] : 0;
    int j1  = (lane < cn) ? nidx [n*K + lane] : 0;
    int cb2 = (kk2 < cn) ? ncell[n*K + kk2] : 0;
    int j2  = (kk2 < cn) ? nidx [n*K + kk2] : 0;
    float acc = cb[lane] + db[lane];
    const float* cfp = ncoef + (size_t)n * K * 8;
#pragma unroll 2
    for (int k = 0; k < cn; ++k) {
        int j    = (k < 64) ? __shfl(j1, k)  : __shfl(j2, k - 64);
        int cbse = (k < 64) ? __shfl(cb1, k) : __shfl(cb2, k - 64);
        float4 cA = *reinterpret_cast<const float4*>(cfp + k*8);      // c=0..3 (dx=0)
        float4 cB = *reinterpret_cast<const float4*>(cfp + k*8 + 4);  // c=4..7 (dx=1)
        const unsigned short* Gj = G + (size_t)j * NO + lane;
        // c = dx*4+dy*2+dz ; cell = cbse + dz*16 + dy*4 + dx
        acc += cA.x * bf16f(Gj[(cbse     ) * 64]);
        acc += cA.y * bf16f(Gj[(cbse + 16) * 64]);
        acc += cA.z * bf16f(Gj[(cbse +  4) * 64]);
        acc += cA.w * bf16f(Gj[(cbse + 20) * 64]);
        acc += cB.x * bf16f(Gj[(cbse +  1) * 64]);
        acc += cB.y * bf16f(Gj[(cbse + 17) * 64]);
        acc += cB.z * bf16f(Gj[(cbse +  5) * 64]);
        acc += cB.w * bf16f(Gj[(cbse + 21) * 64]);
    }
    acc += bf16f(G[(size_t)n * NO + 64*64 + lane]);   // dense skip
    if (resid) acc += resid[(size_t)n * 64 + lane];
    out[(size_t)n * 64 + lane] = acc;
}

// --- prep: Bt1/Bt2 (bf16, n-major G-GEMM filters), W3p, ff, dense-0 into x1 --
__global__ __launch_bounds__(256) void prep_kernel(
    const float* __restrict__ c1w, const float* __restrict__ d1w,
    const float* __restrict__ c2w, const float* __restrict__ d2w,
    const float* __restrict__ c3w, const float* __restrict__ d3w,
    const float* __restrict__ vel,
    const float* __restrict__ d0w, const float* __restrict__ d0b,
    unsigned short* __restrict__ Bt1, unsigned short* __restrict__ Bt2,
    float* __restrict__ W3p, float* __restrict__ ff, float* __restrict__ x1)
{
    int stride = gridDim.x * blockDim.x;
    int gid = blockIdx.x * blockDim.x + threadIdx.x;
    // Bt1[n, f] = c1_w[c,f,o] (c<64) else d1_w[f,o];  n = c*64+o
    for (int i = gid; i < NO * 96; i += stride) {
        int n = i / 96, f = i % 96, c = n >> 6, o = n & 63;
        float v = (c < 64) ? c1w[((size_t)c*96 + f)*64 + o] : d1w[f*64 + o];
        Bt1[i] = (unsigned short)bf16rne(v);
    }
    for (int i = gid; i < NO * 64; i += stride) {
        int n = i / 64, f = i % 64, c = n >> 6, o = n & 63;
        float v = (c < 64) ? c2w[((size_t)c*64 + f)*64 + o] : d2w[f*64 + o];
        Bt2[i] = (unsigned short)bf16rne(v);
    }
    for (int i = gid; i < 64 * 195; i += stride) {   // W3p[f][c*3+o]
        int f = i / 195, r = i % 195, c = r / 3, o = r % 3;
        W3p[i] = (c < 64) ? c3w[(c*64 + f)*3 + o] : d3w[f*3 + o];
    }
    for (int i = gid; i < NQ; i += stride) {
        ff[i*4+0] = 1.f;
        ff[i*4+1] = vel[i*3+0];
        ff[i*4+2] = vel[i*3+1];
        ff[i*4+3] = vel[i*3+2];
    }
    for (int i = gid; i < NQ * 32; i += stride) {    // dense-0 skip -> x1[:,64:96]
        int n = i >> 5, o = i & 31;
        float acc = d0b[o] + d0w[o]
                  + vel[n*3+0] * d0w[32 + o]
                  + vel[n*3+1] * d0w[64 + o]
                  + vel[n*3+2] * d0w[96 + o];
        x1[n*96 + 64 + o] = acc;
    }
}

// epilogue for layer 0: x1[:,0:32] = sum(Pco)+co_b ; x1[:,32:64] = sum(Pcf)+cf_b
__global__ __launch_bounds__(256) void e0_kernel(
    const float* __restrict__ Pco, const float* __restrict__ Pcf, int kc,
    const float* __restrict__ cob, const float* __restrict__ cfb,
    float* __restrict__ x1)
{
    int t = blockIdx.x * blockDim.x + threadIdx.x;
    if (t >= NQ * 64) return;
    int n = t >> 6, c = t & 63;
    float v;
    if (c < 32) {
        v = cob[c];
        for (int ky = 0; ky < kc; ++ky) v += Pco[(size_t)ky * NQ * 32 + n*32 + c];
    } else {
        int cc = c - 32;
        v = cfb[cc];
        for (int ky = 0; ky < kc; ++ky) v += Pcf[(size_t)ky * NQ * 32 + n*32 + cc];
    }
    x1[n*96 + c] = v;
}

// ---- final layer via transform+gather: Y[j, c<=64, 3] = relu(x3[j])*W3' -----
__global__ __launch_bounds__(256) void y3t_kernel(
    const float* __restrict__ x3, const float* __restrict__ W3p,
    float* __restrict__ Y)
{
    __shared__ float xr[64];
    int n = blockIdx.x, tid = threadIdx.x;
    if (tid < 64) xr[tid] = fmaxf(x3[n*64 + tid], 0.f);
    __syncthreads();
    if (tid < 195) {
        float acc = 0.f;
#pragma unroll 8
        for (int f = 0; f < 64; ++f) acc += xr[f] * W3p[f*195 + tid];
        Y[(size_t)n * 195 + tid] = acc;
    }
}

__global__ __launch_bounds__(256) void gather3_kernel(
    const int* __restrict__ cnt, const int* __restrict__ nidx,
    const int* __restrict__ ncell, const float* __restrict__ ncoef,
    const float* __restrict__ Y,
    const float* __restrict__ cb3, const float* __restrict__ db3,
    float* __restrict__ out)
{
    int gw = (blockIdx.x * blockDim.x + threadIdx.x) >> 6;
    int lane = threadIdx.x & 63;
    if (gw >= NQ) return;
    int n = gw;
    int cn = cnt[n];
    float a0 = 0.f, a1 = 0.f, a2 = 0.f;
#pragma unroll
    for (int seg = 0; seg < 2; ++seg) {
        int kidx = seg * 64 + lane;
        if (kidx < cn) {
            int j  = nidx [n*K + kidx];
            int cb = ncell[n*K + kidx];
            const float* cf = ncoef + (size_t)(n*K + kidx) * 8;
            const float* Yj = Y + (size_t)j * 195;
#pragma unroll
            for (int c = 0; c < 8; ++c) {
                int cell = cb + (c & 1)*16 + ((c >> 1) & 1)*4 + (c >> 2);
                float wgt = cf[c];
                const float* Tp = Yj + cell*3;
                a0 += wgt * Tp[0];
                a1 += wgt * Tp[1];
                a2 += wgt * Tp[2];
            }
        }
    }
#pragma unroll
    for (int s = 32; s > 0; s >>= 1) {
        a0 += __shfl_down(a0, s);
        a1 += __shfl_down(a1, s);
        a2 += __shfl_down(a2, s);
    }
    if (lane == 0) {
        const float* Yn = Y + (size_t)n * 195 + 192;   // dense skip (c=64)
        out[n*3+0] = (a0 + Yn[0] + cb3[0] + db3[0]) * (1.f/128.f);
        out[n*3+1] = (a1 + Yn[1] + cb3[1] + db3[1]) * (1.f/128.f);
        out[n*3+2] = (a2 + Yn[2] + cb3[2] + db3[2]) * (1.f/128.f);
    }
}

} // namespace

extern "C" void kernel_launch(void* const* d_in, const int* in_sizes, int n_in,
                              void* d_out, int out_size, void* d_ws, size_t ws_size,
                              hipStream_t stream)
{
    const float* pos       = (const float*)d_in[0];
    const float* vel       = (const float*)d_in[1];
    const float* box       = (const float*)d_in[2];
    const float* box_feats = (const float*)d_in[3];
    const float* cf_w = (const float*)d_in[4];  const float* cf_b = (const float*)d_in[5];
    const float* co_w = (const float*)d_in[6];  const float* co_b = (const float*)d_in[7];
    const float* d0_w = (const float*)d_in[8];  const float* d0_b = (const float*)d_in[9];
    const float* c1_w = (const float*)d_in[10]; const float* c1_b = (const float*)d_in[11];
    const float* d1_w = (const float*)d_in[12]; const float* d1_b = (const float*)d_in[13];
    const float* c2_w = (const float*)d_in[14]; const float* c2_b = (const float*)d_in[15];
    const float* d2_w = (const float*)d_in[16]; const float* d2_b = (const float*)d_in[17];
    const float* c3_w = (const float*)d_in[18]; const float* c3_b = (const float*)d_in[19];
    const float* d3_w = (const float*)d_in[20]; const float* d3_b = (const float*)d_in[21];

    char* wsb = (char*)d_ws;
    size_t off = 0;
    auto alloc = [&](size_t bytes) {
        void* p = wsb + off;
        off = (off + bytes + 255) & ~(size_t)255;
        return p;
    };
    // Big region time-shared: {f_d2,b_d2} during nn -> {S_cf,S_co} (layer 0)
    // -> bf16 G rows for layers 1/2.
    char*  Graw = (char*)alloc((size_t)NQ * NO * 2 + 4096);   // 50 MB
    unsigned short* G = (unsigned short*)Graw;
    float* f_d2 = (float*)Graw;
    float* b_d2 = (float*)Graw + (size_t)NQ * K;
    float* S_cf = (float*)Graw;                      // [NQ,256] fp32
    float* S_co = (float*)Graw + (size_t)NQ * 256;   // [NQ,192] fp32
    int*   f_cnt  = (int*)  alloc((size_t)NQ * 4);
    int*   f_idx  = (int*)  alloc((size_t)NQ * K * 4);
    int*   f_cell = (int*)  alloc((size_t)NQ * K * 4);
    float* f_coef = (float*)alloc((size_t)NQ * K * 8 * 4);
    int*   b_cnt  = (int*)  alloc((size_t)NQ * 4);
    int*   b_idx  = (int*)  alloc((size_t)NQ * K * 4);
    int*   b_cell = (int*)  alloc((size_t)NQ * K * 4);
    float* b_coef = (float*)alloc((size_t)NQ * K * 8 * 4);
    float* ff     = (float*)alloc((size_t)NQ * 4 * 4);
    float* x1     = (float*)alloc((size_t)NQ * 96 * 4);
    float* x2     = (float*)alloc((size_t)NQ * 64 * 4);
    float* x3     = (float*)alloc((size_t)NQ * 64 * 4);
    unsigned short* Bt1 = (unsigned short*)alloc((size_t)NO * 96 * 2);  // 0.8 MB
    unsigned short* Bt2 = (unsigned short*)alloc((size_t)NO * 64 * 2);  // 0.5 MB
    float* W3p    = (float*)alloc((size_t)64 * 195 * 4);
    float* P      = (float*)alloc((size_t)KCS * NQ * 64 * 4);  // layer-0 partials / Y
    float* Pco    = P;
    float* Pcf    = P + (size_t)KCS * NQ * 32;
    float* Y      = P;

    dim3 b256(256);
    prep_kernel<<<512, b256, 0, stream>>>(c1_w, d1_w, c2_w, d2_w, c3_w, d3_w,
                                          vel, d0_w, d0_b, Bt1, Bt2, W3p, ff, x1);
    nn2_kernel<<<2*NQ/4, b256, 0, stream>>>(pos, box, f_cnt, f_idx, f_d2,
                                            b_cnt, b_idx, b_d2);
    coef2_kernel<<<(2*NQ*K + 255)/256, b256, 0, stream>>>(
        pos, box, f_cnt, f_idx, f_cell, f_coef, b_cnt, b_idx, b_cell, b_coef);
    // ---- layer 0 ----
    scatter_small_kernel<4><<<(NQ+3)/4, b256, 0, stream>>>(ff, f_cnt, f_idx,
        f_cell, f_coef, S_cf, NQ);
    scatter_small_kernel<3><<<(NQ+3)/4, b256, 0, stream>>>(box_feats, b_cnt, b_idx,
        b_cell, b_coef, S_co, NQ);
    gemm_kernel<32><<<dim3((NQ+127)/128, KCS), b256, 0, stream>>>(S_co, 192, co_w, Pco, NQ);
    gemm_kernel<32><<<dim3((NQ+127)/128, KCS), b256, 0, stream>>>(S_cf, 256, cf_w, Pcf, NQ);
    e0_kernel<<<(NQ*64 + 255)/256, b256, 0, stream>>>(Pco, Pcf, KCS, co_b, cf_b, x1);
    // ---- layer 1: G1 = relu(x1) x [c1;d1] (MFMA) ; x2 = gather(G1) + biases --
    gemmGm_kernel<96><<<dim3((NQ+63)/64, NO/64), b256, 0, stream>>>(x1, Bt1, G, NQ);
    gatherG_kernel<<<(NQ+3)/4, b256, 0, stream>>>(f_cnt, f_idx, f_cell, f_coef,
        G, c1_b, d1_b, nullptr, x2);
    // ---- layer 2: G2 = relu(x2) x [c2;d2] (MFMA) ; x3 = gather + biases + x2 -
    gemmGm_kernel<64><<<dim3((NQ+63)/64, NO/64), b256, 0, stream>>>(x2, Bt2, G, NQ);
    gatherG_kernel<<<(NQ+3)/4, b256, 0, stream>>>(f_cnt, f_idx, f_cell, f_coef,
        G, c2_b, d2_b, x2, x3);
    // ---- layer 3 (O=3): transform Y = relu(x3)*[c3;d3], then gather ----
    y3t_kernel<<<NQ, b256, 0, stream>>>(x3, W3p, Y);
    gather3_kernel<<<(NQ+3)/4, b256, 0, stream>>>(f_cnt, f_idx, f_cell, f_coef,
        Y, c3_b, d3_b, (float*)d_out);

    (void)in_sizes; (void)n_in; (void)out_size; (void)ws_size;
}

// Round 9
// 320.698 us; speedup vs baseline: 7.2738x; 1.0581x over previous
//
#include <hip/hip_runtime.h>
#include <math.h>

namespace {

constexpr int NQ  = 6000;   // fluid particles (queries)
constexpr int NB  = 3000;   // box particles
constexpr int K   = 80;     // neighbor cap
constexpr float RAD = 0.1125f;
constexpr float R2  = RAD * RAD;
constexpr float EPSF = 1e-12f;

constexpr int GS  = 8;           // grid dim (cell 0.125 >= RADIUS)
constexpr int NC  = GS*GS*GS;    // 512 cells
constexpr int NO  = 65 * 64;     // G row: 64 cells + 1 dense-skip col, O=64
constexpr int KCS = 4;           // split-K chunks, layer-0 GEMMs

typedef __attribute__((ext_vector_type(8))) short bf16x8;
typedef __attribute__((ext_vector_type(4))) float f32x4;

__device__ __forceinline__ float sgn(float x) {
    return (x > 0.f) ? 1.f : ((x < 0.f) ? -1.f : 0.f);
}

__device__ __forceinline__ unsigned int bf16rne(float f) {
    unsigned int u = __float_as_uint(f);
    return (u + 0x7fffu + ((u >> 16) & 1u)) >> 16;   // round-to-nearest-even
}
__device__ __forceinline__ float bf16f(unsigned short u) {
    return __uint_as_float(((unsigned int)u) << 16);
}
__device__ __forceinline__ int cell_of(float x, float y, float z) {
    int cx = min(max((int)(x * (float)GS), 0), GS-1);
    int cy = min(max((int)(y * (float)GS), 0), GS-1);
    int cz = min(max((int)(z * (float)GS), 0), GS-1);
    return (cz*GS + cy)*GS + cx;
}

// ---------------- grid-accelerated neighbor search -------------------------
// exclusive scan of gcnt[0..511] (fluid) and gcnt[512..1023] (box)
__global__ __launch_bounds__(512) void scan_kernel(
    const int* __restrict__ gcnt,
    int* __restrict__ gs_f, int* __restrict__ gs_b,
    int* __restrict__ cur_f, int* __restrict__ cur_b)
{
    __shared__ int tmp[NC];
    int tid = threadIdx.x;
#pragma unroll
    for (int a = 0; a < 2; ++a) {
        int cntv = gcnt[a*NC + tid];
        tmp[tid] = cntv;
        __syncthreads();
        for (int off = 1; off < NC; off <<= 1) {
            int v = (tid >= off) ? tmp[tid - off] : 0;
            __syncthreads();
            tmp[tid] += v;
            __syncthreads();
        }
        int* gsd = a ? gs_b : gs_f;
        int* cur = a ? cur_b : cur_f;
        int excl = tmp[tid] - cntv;
        gsd[tid] = excl;
        cur[tid] = excl;
        if (tid == NC - 1) gsd[NC] = tmp[tid];
        __syncthreads();
    }
}

__global__ __launch_bounds__(256) void scatter_pts_kernel(
    const float* __restrict__ pos, const float* __restrict__ box,
    int* __restrict__ cur_f, int* __restrict__ cur_b,
    float* __restrict__ spf, int* __restrict__ sif,
    float* __restrict__ spb, int* __restrict__ sib)
{
    int t = blockIdx.x * blockDim.x + threadIdx.x;
    if (t < NQ) {
        float x = pos[t*3], y = pos[t*3+1], z = pos[t*3+2];
        int dst = atomicAdd(&cur_f[cell_of(x,y,z)], 1);
        spf[dst*3] = x; spf[dst*3+1] = y; spf[dst*3+2] = z;
        sif[dst] = t;
    } else if (t < NQ + NB) {
        int b = t - NQ;
        float x = box[b*3], y = box[b*3+1], z = box[b*3+2];
        int dst = atomicAdd(&cur_b[cell_of(x,y,z)], 1);
        spb[dst*3] = x; spb[dst*3+1] = y; spb[dst*3+2] = z;
        sib[dst] = b;
    }
}

// one wave per query; scan 3x3 (z,y) rows of 3 x-contiguous cells each
__global__ __launch_bounds__(256) void nn2g_kernel(
    const float* __restrict__ pos,
    const float* __restrict__ spf, const int* __restrict__ sif, const int* __restrict__ gsf,
    const float* __restrict__ spb, const int* __restrict__ sib, const int* __restrict__ gsb,
    int* __restrict__ f_cnt, int* __restrict__ f_idx, float* __restrict__ f_d2,
    int* __restrict__ b_cnt, int* __restrict__ b_idx, float* __restrict__ b_d2)
{
    int gw = (blockIdx.x * blockDim.x + threadIdx.x) >> 6;
    int lane = threadIdx.x & 63;
    if (gw >= 2 * NQ) return;
    bool isF = gw < NQ;
    int wid = isF ? gw : gw - NQ;
    const float* sp = isF ? spf : spb;
    const int*   si = isF ? sif : sib;
    const int*   gs = isF ? gsf : gsb;
    int*   cnt  = isF ? f_cnt : b_cnt;
    int*   idxs = isF ? f_idx : b_idx;
    float* d2s  = isF ? f_d2  : b_d2;
    float qx = pos[wid*3+0], qy = pos[wid*3+1], qz = pos[wid*3+2];
    int cx = min(max((int)(qx * (float)GS), 0), GS-1);
    int cy = min(max((int)(qy * (float)GS), 0), GS-1);
    int cz = min(max((int)(qz * (float)GS), 0), GS-1);
    int x0 = max(cx-1, 0), x1 = min(cx+1, GS-1);
    int base = wid * K;
    int c = 0;
    for (int dz = -1; dz <= 1; ++dz) {
        int z = cz + dz; if ((unsigned)z >= (unsigned)GS) continue;
        for (int dy = -1; dy <= 1; ++dy) {
            int y = cy + dy; if ((unsigned)y >= (unsigned)GS) continue;
            int row = (z*GS + y)*GS;
            int s0 = gs[row + x0], s1 = gs[row + x1 + 1];
            for (int j0 = s0; j0 < s1; j0 += 64) {
                int ii = j0 + lane;
                float d2 = 1e30f; int oj = 0;
                if (ii < s1) {
                    oj = si[ii];
                    float ddx = sp[ii*3+0]-qx, ddy = sp[ii*3+1]-qy, ddz = sp[ii*3+2]-qz;
                    d2 = ddx*ddx + ddy*ddy + ddz*ddz;
                    if (isF && oj == wid) d2 = 1e30f;
                }
                bool hit = d2 <= R2;
                unsigned long long m = __ballot(hit);
                int pc = __popcll(m);
                if (pc == 0) continue;
                if (c + pc <= K) {
                    if (hit) {
                        int p = c + __popcll(m & ((1ull << lane) - 1ull));
                        idxs[base + p] = oj;
                        d2s [base + p] = d2;
                    }
                    c += pc;
                } else {
                    // rare overflow: keep the K nearest (top_k semantics)
                    while (m) {
                        int l = __ffsll((unsigned long long)m) - 1;
                        m &= m - 1ull;
                        float dd = __shfl(d2, l);
                        int jv = __shfl(oj, l);
                        if (c < K) {
                            idxs[base + c] = jv;
                            d2s [base + c] = dd;
                            c++;
                        } else {
                            float mx = -1.f; int am = 0;
                            for (int s = 0; s < K; ++s) {
                                float v = d2s[base + s];
                                if (v > mx) { mx = v; am = s; }
                            }
                            if (dd < mx) {
                                idxs[base + am] = jv;
                                d2s [base + am] = dd;
                            }
                        }
                    }
                }
            }
        }
    }
    if (lane == 0) cnt[wid] = c;
}

// ------------- per-neighbor geometry: ball->cube + trilinear coefs -----------
__device__ void coef_one(const float* __restrict__ qpos, const float* __restrict__ ipos,
                         const int* __restrict__ cnt, const int* __restrict__ idxs,
                         int* __restrict__ cells, float* __restrict__ coefs,
                         int q, int k)
{
    if (k >= cnt[q]) return;
    int j = idxs[q*K + k];
    float rx = (ipos[j*3+0] - qpos[q*3+0]) / RAD;
    float ry = (ipos[j*3+1] - qpos[q*3+1]) / RAD;
    float rz = (ipos[j*3+2] - qpos[q*3+2]) / RAD;
    float r2 = rx*rx + ry*ry + rz*rz;
    float w1 = 1.f - r2;
    float win = (w1 > 0.f) ? w1*w1*w1 : 0.f;   // clip((1-r2)^3, 0, 1)
    float norm = sqrtf(r2);
    float rxy2 = rx*rx + ry*ry;
    float xc, yc, zc;
    if (r2 < 1e-12f) {
        xc = yc = zc = 0.f;
    } else if (1.25f * rz * rz > rxy2) {
        float s = sqrtf(3.0f * norm / (norm + fabsf(rz) + EPSF));
        xc = s * rx; yc = s * ry; zc = sgn(rz) * norm;
    } else {
        float s = norm / sqrtf(rxy2 + EPSF);
        xc = s * rx; yc = s * ry; zc = 1.5f * rz * s;
    }
    float rxy = sqrtf(xc*xc + yc*yc);
    const float FP = (float)(4.0 / M_PI);
    float u, v;
    if (rxy < EPSF) {
        u = 0.f; v = 0.f;
    } else if (fabsf(xc) >= fabsf(yc)) {
        float sx = (fabsf(xc) < EPSF) ? EPSF : xc;
        u = sgn(xc) * rxy;
        v = u * FP * atanf(yc / sx);
    } else {
        float sy = (fabsf(yc) < EPSF) ? EPSF : yc;
        v = sgn(yc) * rxy;
        u = v * FP * atanf(xc / sy);
    }
    float gx = fminf(fmaxf((u  + 1.f) * 0.5f * 3.f, 0.f), 3.f);
    float gy = fminf(fmaxf((v  + 1.f) * 0.5f * 3.f, 0.f), 3.f);
    float gz = fminf(fmaxf((zc + 1.f) * 0.5f * 3.f, 0.f), 3.f);
    int ix = min((int)floorf(gx), 2);
    int iy = min((int)floorf(gy), 2);
    int iz = min((int)floorf(gz), 2);
    float tx = gx - (float)ix, ty = gy - (float)iy, tz = gz - (float)iz;
    cells[q*K + k] = iz*16 + iy*4 + ix;
    float wx[2] = {1.f - tx, tx}, wy[2] = {1.f - ty, ty}, wz[2] = {1.f - tz, tz};
    float* cf = coefs + (size_t)(q*K + k) * 8;
#pragma unroll
    for (int c = 0; c < 8; ++c)   // c = dx*4 + dy*2 + dz (python loop order)
        cf[c] = wx[c >> 2] * wy[(c >> 1) & 1] * wz[c & 1] * win;
}

__global__ __launch_bounds__(256) void coef2_kernel(
    const float* __restrict__ pos, const float* __restrict__ box,
    const int* __restrict__ f_cnt, const int* __restrict__ f_idx,
    int* __restrict__ f_cell, float* __restrict__ f_coef,
    const int* __restrict__ b_cnt, const int* __restrict__ b_idx,
    int* __restrict__ b_cell, float* __restrict__ b_coef)
{
    int t = blockIdx.x * blockDim.x + threadIdx.x;
    if (t < NQ * K)
        coef_one(pos, pos, f_cnt, f_idx, f_cell, f_coef, t / K, t % K);
    else if (t < 2 * NQ * K) {
        int t2 = t - NQ * K;
        coef_one(pos, box, b_cnt, b_idx, b_cell, b_coef, t2 / K, t2 % K);
    }
}

// ------- small scatter (F in {3,4}): one WAVE per point, lane=(corner,feat) --
template<int F>
__global__ __launch_bounds__(256) void scatter_small_kernel(
    const float* __restrict__ feats,
    const int* __restrict__ cnt, const int* __restrict__ nidx,
    const int* __restrict__ ncell, const float* __restrict__ ncoef,
    float* __restrict__ Sg, int nq)
{
    __shared__ __align__(16) float S4[4][64 * F];
    int tid = threadIdx.x, lane = tid & 63, w = tid >> 6;
    int n = blockIdx.x * 4 + w;
    if (n >= nq) return;
    float* Sw = S4[w];
    for (int i = lane; i < 64 * F; i += 64) Sw[i] = 0.f;
    int cn = cnt[n];
    int kk2 = 64 + lane;
    int cb1 = (lane < cn) ? ncell[n*K + lane] : 0;
    int j1  = (lane < cn) ? nidx [n*K + lane] : 0;
    int cb2 = (kk2 < cn) ? ncell[n*K + kk2] : 0;
    int j2  = (kk2 < cn) ? nidx [n*K + kk2] : 0;
    int c = lane & 7, f = lane >> 3;
    bool fok = f < F;
    const float* coefG = ncoef + (size_t)n * K * 8;

    float wgt = 0.f, v = 0.f; int cb = 0;
    if (cn > 0) {
        int j = __shfl(j1, 0); cb = __shfl(cb1, 0);
        if (fok) { wgt = coefG[c]; v = feats[(size_t)j * F + f]; }
    }
    for (int kk = 0; kk < cn; ++kk) {
        float wn = 0.f, vn = 0.f; int cbn = 0;
        int k1n = kk + 1;
        if (k1n < cn) {
            int jn = (k1n < 64) ? __shfl(j1, k1n) : __shfl(j2, k1n - 64);
            cbn    = (k1n < 64) ? __shfl(cb1, k1n) : __shfl(cb2, k1n - 64);
            if (fok) { wn = coefG[k1n*8 + c]; vn = feats[(size_t)jn * F + f]; }
        }
        if (fok) {
            int cell = cb + (c & 1)*16 + ((c >> 1) & 1)*4 + (c >> 2);
            Sw[cell*F + f] += wgt * v;
        }
        wgt = wn; v = vn; cb = cbn;
    }
    float* row = Sg + (size_t)n * (64 * F);
    for (int i = lane; i < 16 * F; i += 64)
        ((float4*)row)[i] = ((const float4*)Sw)[i];
}

// ----------------- layer-0 GEMM (4x4 blocking, fp32 A), split-K --------------
template<int O>
__global__ __launch_bounds__(256) void gemm_kernel(
    const float* __restrict__ A, int Kdim,
    const float* __restrict__ B,
    float* __restrict__ P, int M)
{
    constexpr int TX   = O / 4;
    constexpr int TY   = 256 / TX;
    constexpr int MT   = TY * 4;
    constexpr int ASTR = MT + 4;
    __shared__ float As[16][ASTR];
    __shared__ float Bs[16 * O];
    int tid = threadIdx.x;
    int tx = tid % TX, ty = tid / TX;
    int m0 = blockIdx.x * MT;
    int ntiles = Kdim >> 4;
    float acc[4][4] = {};
    for (int t = blockIdx.y; t < ntiles; t += gridDim.y) {
        int k0 = t << 4;
        __syncthreads();
#pragma unroll
        for (int l = 0; l < MT / 64; ++l) {
            int idx = tid + l * 256;
            int mm = idx >> 2, k4 = idx & 3;
            int gm = m0 + mm; if (gm >= M) gm = M - 1;
            float4 av = *reinterpret_cast<const float4*>(A + (size_t)gm * Kdim + k0 + k4 * 4);
            As[k4*4+0][mm] = av.x; As[k4*4+1][mm] = av.y;
            As[k4*4+2][mm] = av.z; As[k4*4+3][mm] = av.w;
        }
        constexpr int NB4 = 16 * O / 4;
        if (NB4 == 256 || tid < NB4)
            *reinterpret_cast<float4*>(&Bs[tid*4]) =
                *reinterpret_cast<const float4*>(B + (size_t)k0 * O + tid * 4);
        __syncthreads();
#pragma unroll
        for (int kk = 0; kk < 16; ++kk) {
            float4 av = *reinterpret_cast<const float4*>(&As[kk][ty*4]);
            float4 bv = *reinterpret_cast<const float4*>(&Bs[kk*O + tx*4]);
            float aa[4] = {av.x, av.y, av.z, av.w};
            float bb[4] = {bv.x, bv.y, bv.z, bv.w};
#pragma unroll
            for (int i = 0; i < 4; ++i)
#pragma unroll
                for (int jj = 0; jj < 4; ++jj)
                    acc[i][jj] += aa[i] * bb[jj];
        }
    }
    float* Pb = P + (size_t)blockIdx.y * M * O;
#pragma unroll
    for (int i = 0; i < 4; ++i) {
        int gm = m0 + ty*4 + i;
        if (gm < M)
#pragma unroll
            for (int jj = 0; jj < 4; ++jj)
                Pb[(size_t)gm * O + tx*4 + jj] = acc[i][jj];
    }
}

// ---- MFMA G-GEMM: G[j, n] = relu(feats[j,:]) . Bt[n,:]  (bf16 in/out) -------
template<int F>
__global__ __launch_bounds__(256) void gemmGm_kernel(
    const float* __restrict__ feats,            // [M,F] fp32
    const unsigned short* __restrict__ Bt,      // [NO,F] bf16 (n-major)
    unsigned short* __restrict__ G,             // [M,NO] bf16
    int M)
{
    constexpr int AST = F + 8;
    __shared__ unsigned short As[64 * AST];     // [m][k]
    __shared__ unsigned short Bs[64 * AST];     // [n][k]
    int tid = threadIdx.x, lane = tid & 63, wv = tid >> 6;
    int m0 = blockIdx.x * 64, no0 = blockIdx.y * 64;
    for (int i = tid; i < 64 * F / 4; i += 256) {
        int m = i / (F / 4), k4 = i % (F / 4);
        int gm = m0 + m; if (gm >= M) gm = M - 1;
        float4 av = *reinterpret_cast<const float4*>(feats + (size_t)gm * F + k4 * 4);
        uint2 o;
        o.x = bf16rne(fmaxf(av.x, 0.f)) | (bf16rne(fmaxf(av.y, 0.f)) << 16);
        o.y = bf16rne(fmaxf(av.z, 0.f)) | (bf16rne(fmaxf(av.w, 0.f)) << 16);
        *reinterpret_cast<uint2*>(As + m * AST + k4 * 4) = o;
    }
    for (int i = tid; i < 64 * F / 8; i += 256) {
        int n = i / (F / 8), k8 = i % (F / 8);
        *reinterpret_cast<uint4*>(Bs + n * AST + k8 * 8) =
            *reinterpret_cast<const uint4*>(Bt + (size_t)(no0 + n) * F + k8 * 8);
    }
    __syncthreads();
    int mr = lane & 15, quad = lane >> 4;
    f32x4 acc[4] = {{0.f,0.f,0.f,0.f},{0.f,0.f,0.f,0.f},
                    {0.f,0.f,0.f,0.f},{0.f,0.f,0.f,0.f}};
#pragma unroll
    for (int kc = 0; kc < F; kc += 32) {
        bf16x8 a = *reinterpret_cast<const bf16x8*>(As + (wv*16 + mr) * AST + kc + quad*8);
#pragma unroll
        for (int t = 0; t < 4; ++t) {
            bf16x8 b = *reinterpret_cast<const bf16x8*>(Bs + (t*16 + mr) * AST + kc + quad*8);
            acc[t] = __builtin_amdgcn_mfma_f32_16x16x32_bf16(a, b, acc[t], 0, 0, 0);
        }
    }
    // C layout: col = lane&15, row = quad*4 + reg
#pragma unroll
    for (int t = 0; t < 4; ++t) {
#pragma unroll
        for (int r = 0; r < 4; ++r) {
            int gm = m0 + wv*16 + quad*4 + r;
            if (gm < M)
                G[(size_t)gm * NO + no0 + t*16 + mr] = (unsigned short)bf16rne(acc[t][r]);
        }
    }
}

// ---- G-gather (spatially-sorted query order via `order`) --------------------
__global__ __launch_bounds__(256) void gatherG_kernel(
    const int* __restrict__ order,
    const int* __restrict__ cnt, const int* __restrict__ nidx,
    const int* __restrict__ ncell, const float* __restrict__ ncoef,
    const unsigned short* __restrict__ G,
    const float* __restrict__ cb, const float* __restrict__ db,
    const float* __restrict__ resid, float* __restrict__ out)
{
    int w = (blockIdx.x * blockDim.x + threadIdx.x) >> 6;
    int lane = threadIdx.x & 63;
    if (w >= NQ) return;
    int n = order[w];
    int cn = cnt[n];
    int kk2 = 64 + lane;
    int cb1 = (lane < cn) ? ncell[n*K + lane] : 0;
    int j1  = (lane < cn) ? nidx [n*K + lane] : 0;
    int cb2 = (kk2 < cn) ? ncell[n*K + kk2] : 0;
    int j2  = (kk2 < cn) ? nidx [n*K + kk2] : 0;
    float acc = cb[lane] + db[lane];
    const float* cfp = ncoef + (size_t)n * K * 8;
#pragma unroll 2
    for (int k = 0; k < cn; ++k) {
        int j    = (k < 64) ? __shfl(j1, k)  : __shfl(j2, k - 64);
        int cbse = (k < 64) ? __shfl(cb1, k) : __shfl(cb2, k - 64);
        float4 cA = *reinterpret_cast<const float4*>(cfp + k*8);      // c=0..3 (dx=0)
        float4 cB = *reinterpret_cast<const float4*>(cfp + k*8 + 4);  // c=4..7 (dx=1)
        const unsigned short* Gj = G + (size_t)j * NO + lane;
        // c = dx*4+dy*2+dz ; cell = cbse + dz*16 + dy*4 + dx
        acc += cA.x * bf16f(Gj[(cbse     ) * 64]);
        acc += cA.y * bf16f(Gj[(cbse + 16) * 64]);
        acc += cA.z * bf16f(Gj[(cbse +  4) * 64]);
        acc += cA.w * bf16f(Gj[(cbse + 20) * 64]);
        acc += cB.x * bf16f(Gj[(cbse +  1) * 64]);
        acc += cB.y * bf16f(Gj[(cbse + 17) * 64]);
        acc += cB.z * bf16f(Gj[(cbse +  5) * 64]);
        acc += cB.w * bf16f(Gj[(cbse + 21) * 64]);
    }
    acc += bf16f(G[(size_t)n * NO + 64*64 + lane]);   // dense skip
    if (resid) acc += resid[(size_t)n * 64 + lane];
    out[(size_t)n * 64 + lane] = acc;
}

// --- prep: Bt1/Bt2 (bf16 G-GEMM filters), W3p, ff, dense-0, grid counts ------
__global__ __launch_bounds__(256) void prep_kernel(
    const float* __restrict__ c1w, const float* __restrict__ d1w,
    const float* __restrict__ c2w, const float* __restrict__ d2w,
    const float* __restrict__ c3w, const float* __restrict__ d3w,
    const float* __restrict__ pos, const float* __restrict__ box,
    const float* __restrict__ vel,
    const float* __restrict__ d0w, const float* __restrict__ d0b,
    unsigned short* __restrict__ Bt1, unsigned short* __restrict__ Bt2,
    float* __restrict__ W3p, float* __restrict__ ff, float* __restrict__ x1,
    int* __restrict__ gcnt)
{
    int stride = gridDim.x * blockDim.x;
    int gid = blockIdx.x * blockDim.x + threadIdx.x;
    for (int i = gid; i < NQ + NB; i += stride) {   // grid occupancy counts
        const float* p = (i < NQ) ? pos + (size_t)i*3 : box + (size_t)(i-NQ)*3;
        atomicAdd(&gcnt[((i < NQ) ? 0 : NC) + cell_of(p[0], p[1], p[2])], 1);
    }
    for (int i = gid; i < NO * 96; i += stride) {   // Bt1[n,f]; n = c*64+o
        int n = i / 96, f = i % 96, c = n >> 6, o = n & 63;
        float v = (c < 64) ? c1w[((size_t)c*96 + f)*64 + o] : d1w[f*64 + o];
        Bt1[i] = (unsigned short)bf16rne(v);
    }
    for (int i = gid; i < NO * 64; i += stride) {
        int n = i / 64, f = i % 64, c = n >> 6, o = n & 63;
        float v = (c < 64) ? c2w[((size_t)c*64 + f)*64 + o] : d2w[f*64 + o];
        Bt2[i] = (unsigned short)bf16rne(v);
    }
    for (int i = gid; i < 64 * 195; i += stride) {   // W3p[f][c*3+o]
        int f = i / 195, r = i % 195, c = r / 3, o = r % 3;
        W3p[i] = (c < 64) ? c3w[(c*64 + f)*3 + o] : d3w[f*3 + o];
    }
    for (int i = gid; i < NQ; i += stride) {
        ff[i*4+0] = 1.f;
        ff[i*4+1] = vel[i*3+0];
        ff[i*4+2] = vel[i*3+1];
        ff[i*4+3] = vel[i*3+2];
    }
    for (int i = gid; i < NQ * 32; i += stride) {    // dense-0 skip -> x1[:,64:96]
        int n = i >> 5, o = i & 31;
        float acc = d0b[o] + d0w[o]
                  + vel[n*3+0] * d0w[32 + o]
                  + vel[n*3+1] * d0w[64 + o]
                  + vel[n*3+2] * d0w[96 + o];
        x1[n*96 + 64 + o] = acc;
    }
}

// epilogue for layer 0: x1[:,0:32] = sum(Pco)+co_b ; x1[:,32:64] = sum(Pcf)+cf_b
__global__ __launch_bounds__(256) void e0_kernel(
    const float* __restrict__ Pco, const float* __restrict__ Pcf, int kc,
    const float* __restrict__ cob, const float* __restrict__ cfb,
    float* __restrict__ x1)
{
    int t = blockIdx.x * blockDim.x + threadIdx.x;
    if (t >= NQ * 64) return;
    int n = t >> 6, c = t & 63;
    float v;
    if (c < 32) {
        v = cob[c];
        for (int ky = 0; ky < kc; ++ky) v += Pco[(size_t)ky * NQ * 32 + n*32 + c];
    } else {
        int cc = c - 32;
        v = cfb[cc];
        for (int ky = 0; ky < kc; ++ky) v += Pcf[(size_t)ky * NQ * 32 + n*32 + cc];
    }
    x1[n*96 + c] = v;
}

// ---- final layer via transform+gather: Y[j, c<=64, 3] = relu(x3[j])*W3' -----
__global__ __launch_bounds__(256) void y3t_kernel(
    const float* __restrict__ x3, const float* __restrict__ W3p,
    float* __restrict__ Y)
{
    __shared__ float xr[64];
    int n = blockIdx.x, tid = threadIdx.x;
    if (tid < 64) xr[tid] = fmaxf(x3[n*64 + tid], 0.f);
    __syncthreads();
    if (tid < 195) {
        float acc = 0.f;
#pragma unroll 8
        for (int f = 0; f < 64; ++f) acc += xr[f] * W3p[f*195 + tid];
        Y[(size_t)n * 195 + tid] = acc;
    }
}

__global__ __launch_bounds__(256) void gather3_kernel(
    const int* __restrict__ order,
    const int* __restrict__ cnt, const int* __restrict__ nidx,
    const int* __restrict__ ncell, const float* __restrict__ ncoef,
    const float* __restrict__ Y,
    const float* __restrict__ cb3, const float* __restrict__ db3,
    float* __restrict__ out)
{
    int gw = (blockIdx.x * blockDim.x + threadIdx.x) >> 6;
    int lane = threadIdx.x & 63;
    if (gw >= NQ) return;
    int n = order[gw];
    int cn = cnt[n];
    float a0 = 0.f, a1 = 0.f, a2 = 0.f;
#pragma unroll
    for (int seg = 0; seg < 2; ++seg) {
        int kidx = seg * 64 + lane;
        if (kidx < cn) {
            int j  = nidx [n*K + kidx];
            int cb = ncell[n*K + kidx];
            const float* cf = ncoef + (size_t)(n*K + kidx) * 8;
            const float* Yj = Y + (size_t)j * 195;
#pragma unroll
            for (int c = 0; c < 8; ++c) {
                int cell = cb + (c & 1)*16 + ((c >> 1) & 1)*4 + (c >> 2);
                float wgt = cf[c];
                const float* Tp = Yj + cell*3;
                a0 += wgt * Tp[0];
                a1 += wgt * Tp[1];
                a2 += wgt * Tp[2];
            }
        }
    }
#pragma unroll
    for (int s = 32; s > 0; s >>= 1) {
        a0 += __shfl_down(a0, s);
        a1 += __shfl_down(a1, s);
        a2 += __shfl_down(a2, s);
    }
    if (lane == 0) {
        const float* Yn = Y + (size_t)n * 195 + 192;   // dense skip (c=64)
        out[n*3+0] = (a0 + Yn[0] + cb3[0] + db3[0]) * (1.f/128.f);
        out[n*3+1] = (a1 + Yn[1] + cb3[1] + db3[1]) * (1.f/128.f);
        out[n*3+2] = (a2 + Yn[2] + cb3[2] + db3[2]) * (1.f/128.f);
    }
}

} // namespace

extern "C" void kernel_launch(void* const* d_in, const int* in_sizes, int n_in,
                              void* d_out, int out_size, void* d_ws, size_t ws_size,
                              hipStream_t stream)
{
    const float* pos       = (const float*)d_in[0];
    const float* vel       = (const float*)d_in[1];
    const float* box       = (const float*)d_in[2];
    const float* box_feats = (const float*)d_in[3];
    const float* cf_w = (const float*)d_in[4];  const float* cf_b = (const float*)d_in[5];
    const float* co_w = (const float*)d_in[6];  const float* co_b = (const float*)d_in[7];
    const float* d0_w = (const float*)d_in[8];  const float* d0_b = (const float*)d_in[9];
    const float* c1_w = (const float*)d_in[10]; const float* c1_b = (const float*)d_in[11];
    const float* d1_w = (const float*)d_in[12]; const float* d1_b = (const float*)d_in[13];
    const float* c2_w = (const float*)d_in[14]; const float* c2_b = (const float*)d_in[15];
    const float* d2_w = (const float*)d_in[16]; const float* d2_b = (const float*)d_in[17];
    const float* c3_w = (const float*)d_in[18]; const float* c3_b = (const float*)d_in[19];
    const float* d3_w = (const float*)d_in[20]; const float* d3_b = (const float*)d_in[21];

    char* wsb = (char*)d_ws;
    size_t off = 0;
    auto alloc = [&](size_t bytes) {
        void* p = wsb + off;
        off = (off + bytes + 255) & ~(size_t)255;
        return p;
    };
    // Big region time-shared: {f_d2,b_d2} during nn -> {S_cf,S_co} (layer 0)
    // -> bf16 G rows for layers 1/2.
    char*  Graw = (char*)alloc((size_t)NQ * NO * 2 + 4096);   // 50 MB
    unsigned short* G = (unsigned short*)Graw;
    float* f_d2 = (float*)Graw;
    float* b_d2 = (float*)Graw + (size_t)NQ * K;
    float* S_cf = (float*)Graw;                      // [NQ,256] fp32
    float* S_co = (float*)Graw + (size_t)NQ * 256;   // [NQ,192] fp32
    int*   f_cnt  = (int*)  alloc((size_t)NQ * 4);
    int*   f_idx  = (int*)  alloc((size_t)NQ * K * 4);
    int*   f_cell = (int*)  alloc((size_t)NQ * K * 4);
    float* f_coef = (float*)alloc((size_t)NQ * K * 8 * 4);
    int*   b_cnt  = (int*)  alloc((size_t)NQ * 4);
    int*   b_idx  = (int*)  alloc((size_t)NQ * K * 4);
    int*   b_cell = (int*)  alloc((size_t)NQ * K * 4);
    float* b_coef = (float*)alloc((size_t)NQ * K * 8 * 4);
    float* ff     = (float*)alloc((size_t)NQ * 4 * 4);
    float* x1     = (float*)alloc((size_t)NQ * 96 * 4);
    float* x2     = (float*)alloc((size_t)NQ * 64 * 4);
    float* x3     = (float*)alloc((size_t)NQ * 64 * 4);
    unsigned short* Bt1 = (unsigned short*)alloc((size_t)NO * 96 * 2);  // 0.8 MB
    unsigned short* Bt2 = (unsigned short*)alloc((size_t)NO * 64 * 2);  // 0.5 MB
    float* W3p    = (float*)alloc((size_t)64 * 195 * 4);
    float* P      = (float*)alloc((size_t)KCS * NQ * 64 * 4);  // layer-0 partials / Y
    float* Pco    = P;
    float* Pcf    = P + (size_t)KCS * NQ * 32;
    float* Y      = P;
    // grid structures
    int*   gcnt   = (int*)  alloc((size_t)2 * NC * 4);
    int*   gs_f   = (int*)  alloc((size_t)(NC + 1) * 4);
    int*   gs_b   = (int*)  alloc((size_t)(NC + 1) * 4);
    int*   cur_f  = (int*)  alloc((size_t)NC * 4);
    int*   cur_b  = (int*)  alloc((size_t)NC * 4);
    float* spf    = (float*)alloc((size_t)NQ * 3 * 4);
    int*   sif    = (int*)  alloc((size_t)NQ * 4);
    float* spb    = (float*)alloc((size_t)NB * 3 * 4);
    int*   sib    = (int*)  alloc((size_t)NB * 4);

    dim3 b256(256);
    hipMemsetAsync(gcnt, 0, (size_t)2 * NC * 4, stream);
    prep_kernel<<<512, b256, 0, stream>>>(c1_w, d1_w, c2_w, d2_w, c3_w, d3_w,
                                          pos, box, vel, d0_w, d0_b,
                                          Bt1, Bt2, W3p, ff, x1, gcnt);
    scan_kernel<<<1, 512, 0, stream>>>(gcnt, gs_f, gs_b, cur_f, cur_b);
    scatter_pts_kernel<<<(NQ + NB + 255)/256, b256, 0, stream>>>(
        pos, box, cur_f, cur_b, spf, sif, spb, sib);
    nn2g_kernel<<<(2*NQ*64 + 255)/256, b256, 0, stream>>>(
        pos, spf, sif, gs_f, spb, sib, gs_b,
        f_cnt, f_idx, f_d2, b_cnt, b_idx, b_d2);
    coef2_kernel<<<(2*NQ*K + 255)/256, b256, 0, stream>>>(
        pos, box, f_cnt, f_idx, f_cell, f_coef, b_cnt, b_idx, b_cell, b_coef);
    // ---- layer 0 ----
    scatter_small_kernel<4><<<(NQ+3)/4, b256, 0, stream>>>(ff, f_cnt, f_idx,
        f_cell, f_coef, S_cf, NQ);
    scatter_small_kernel<3><<<(NQ+3)/4, b256, 0, stream>>>(box_feats, b_cnt, b_idx,
        b_cell, b_coef, S_co, NQ);
    gemm_kernel<32><<<dim3((NQ+127)/128, KCS), b256, 0, stream>>>(S_co, 192, co_w, Pco, NQ);
    gemm_kernel<32><<<dim3((NQ+127)/128, KCS), b256, 0, stream>>>(S_cf, 256, cf_w, Pcf, NQ);
    e0_kernel<<<(NQ*64 + 255)/256, b256, 0, stream>>>(Pco, Pcf, KCS, co_b, cf_b, x1);
    // ---- layer 1: G1 = relu(x1) x [c1;d1] (MFMA) ; x2 = gather(G1) + biases --
    gemmGm_kernel<96><<<dim3((NQ+63)/64, NO/64), b256, 0, stream>>>(x1, Bt1, G, NQ);
    gatherG_kernel<<<(NQ+3)/4, b256, 0, stream>>>(sif, f_cnt, f_idx, f_cell, f_coef,
        G, c1_b, d1_b, nullptr, x2);
    // ---- layer 2: G2 = relu(x2) x [c2;d2] (MFMA) ; x3 = gather + biases + x2 -
    gemmGm_kernel<64><<<dim3((NQ+63)/64, NO/64), b256, 0, stream>>>(x2, Bt2, G, NQ);
    gatherG_kernel<<<(NQ+3)/4, b256, 0, stream>>>(sif, f_cnt, f_idx, f_cell, f_coef,
        G, c2_b, d2_b, x2, x3);
    // ---- layer 3 (O=3): transform Y = relu(x3)*[c3;d3], then gather ----
    y3t_kernel<<<NQ, b256, 0, stream>>>(x3, W3p, Y);
    gather3_kernel<<<(NQ+3)/4, b256, 0, stream>>>(sif, f_cnt, f_idx, f_cell, f_coef,
        Y, c3_b, d3_b, (float*)d_out);

    (void)in_sizes; (void)n_in; (void)out_size; (void)ws_size;
    (void)f_d2; (void)b_d2;
}